// Round 7
// baseline (296.861 us; speedup 1.0000x reference)
//
#include <hip/hip_runtime.h>
#include <cstdint>
#include <cstddef>

#define NN 50000
#define EE 800000
#define TOT_E (NN + EE)
#define NBK 391      // buckets of 128 dst nodes
#define BCAP 2560    // bucket capacity (mean 2048 -> 11 sigma headroom)

typedef __attribute__((ext_vector_type(8))) short short8;
typedef __attribute__((ext_vector_type(4))) float f32x4;

static __device__ __forceinline__ unsigned short f2bf(float f) {
  union { float f; unsigned u; } v;
  v.f = f;
  unsigned r = v.u + 0x7FFFu + ((v.u >> 16) & 1u);  // RNE
  return (unsigned short)(r >> 16);
}
static __device__ __forceinline__ float bf2f(unsigned short u) {
  union { unsigned u; float f; } v;
  v.u = ((unsigned)u) << 16;
  return v.f;
}
static __device__ __forceinline__ float bf2f_lo(unsigned u) {
  union { unsigned u; float f; } v;
  v.u = u << 16;
  return v.f;
}
static __device__ __forceinline__ float bf2f_hi(unsigned u) {
  union { unsigned u; float f; } v;
  v.u = u & 0xFFFF0000u;
  return v.f;
}

// ============================ CSR build: bucket binning ============================
__global__ __launch_bounds__(512) void k_bin(const int* __restrict__ ei,
                                             int* __restrict__ gpos,
                                             unsigned* __restrict__ binned) {
  __shared__ int cnt[512];
  __shared__ int base[512];
  int tx = threadIdx.x;
  cnt[tx] = 0;
  __syncthreads();
  int e0 = blockIdx.x * 3125;
  int e1 = e0 + 3125;
  if (e1 > EE) e1 = EE;
  for (int i = e0 + tx; i < e1; i += 512) {
    int d = ei[EE + i];
    atomicAdd(&cnt[d >> 7], 1);
  }
  __syncthreads();
  if (tx < NBK) {
    int c = cnt[tx];
    base[tx] = c ? atomicAdd(&gpos[tx], c) : 0;
    cnt[tx] = 0;
  }
  __syncthreads();
  for (int i = e0 + tx; i < e1; i += 512) {
    int s = ei[i];
    int d = ei[EE + i];
    int b = d >> 7;
    int slot = base[b] + atomicAdd(&cnt[b], 1);
    if (slot < BCAP) binned[(size_t)b * BCAP + slot] = (unsigned)s | ((unsigned)(d & 127) << 16);
  }
}
__global__ __launch_bounds__(512) void k_bscan(const int* __restrict__ gpos,
                                               int* __restrict__ ebase,
                                               int* __restrict__ rowp) {
  __shared__ int sh[512];
  int tx = threadIdx.x;
  int v = 0;
  if (tx < NBK) {
    int nodes = NN - (tx << 7);
    if (nodes > 128) nodes = 128;
    int g = gpos[tx];
    if (g > BCAP) g = BCAP;
    v = g + nodes;
  }
  sh[tx] = v;
  __syncthreads();
  for (int off = 1; off < 512; off <<= 1) {
    int t = (tx >= off) ? sh[tx - off] : 0;
    __syncthreads();
    sh[tx] += t;
    __syncthreads();
  }
  if (tx < NBK) ebase[tx] = sh[tx] - v;
  if (tx == NBK - 1) rowp[NN] = sh[tx];
}
__global__ __launch_bounds__(256) void k_bucket(const unsigned* __restrict__ binned,
                                                const int* __restrict__ gpos,
                                                const int* __restrict__ ebase,
                                                int* __restrict__ rowp,
                                                int* __restrict__ srcl) {
  __shared__ int cnt[128], offs[128], cur[128];
  int b = blockIdx.x, tid = threadIdx.x;
  int n0 = b << 7;
  int nodes = NN - n0;
  if (nodes > 128) nodes = 128;
  int ne = gpos[b];
  if (ne > BCAP) ne = BCAP;
  int eb = ebase[b];
  if (tid < 128) cnt[tid] = (tid < nodes) ? 1 : 0;  // 1 = self-loop
  __syncthreads();
  const unsigned* bb = binned + (size_t)b * BCAP;
  for (int i = tid; i < ne; i += 256) atomicAdd(&cnt[bb[i] >> 16], 1);
  __syncthreads();
  if (tid < 128) offs[tid] = cnt[tid];
  __syncthreads();
  for (int o = 1; o < 128; o <<= 1) {
    int t = (tid < 128 && tid >= o) ? offs[tid - o] : 0;
    __syncthreads();
    if (tid < 128) offs[tid] += t;
    __syncthreads();
  }
  if (tid < 128 && tid < nodes) {
    int ex = offs[tid] - cnt[tid];
    rowp[n0 + tid] = eb + ex;
    srcl[eb + ex] = n0 + tid;  // self-loop first (segment order irrelevant)
    cur[tid] = ex + 1;
  }
  __syncthreads();
  for (int i = tid; i < ne; i += 256) {
    unsigned e = bb[i];
    int r = atomicAdd(&cur[e >> 16], 1);
    srcl[eb + r] = (int)(e & 0xFFFFu);
  }
}

// ============================ BN stats for x (f32, C=64) ============================
__global__ __launch_bounds__(256) void k_bn_stats64(const float* __restrict__ x,
                                                    float* __restrict__ sums) {
  int col = threadIdx.x & 63;
  int rsub = threadIdx.x >> 6;
  float s = 0.f, q = 0.f;
  for (int r = blockIdx.x * 4 + rsub; r < NN; r += gridDim.x * 4) {
    float v = x[(size_t)r * 64 + col];
    s += v;
    q += v * v;
  }
  __shared__ float bs[256], bq[256];
  bs[threadIdx.x] = s;
  bq[threadIdx.x] = q;
  __syncthreads();
  if (threadIdx.x < 64) {
#pragma unroll
    for (int i = 1; i < 4; ++i) {
      s += bs[threadIdx.x + i * 64];
      q += bq[threadIdx.x + i * 64];
    }
    atomicAdd(&sums[col], s);
    atomicAdd(&sums[64 + col], q);
  }
}

// ============================ fused weight reorder ============================
__global__ void k_reorder_all(const float* __restrict__ projW, const float* __restrict__ skipW,
                              const float* __restrict__ c1W, const float* __restrict__ c2W,
                              const float* __restrict__ c3W, const float* __restrict__ W1,
                              const float* __restrict__ cw, unsigned short* __restrict__ wr) {
  int o = blockIdx.x * 256 + threadIdx.x;
  if (o < 8192) {  // proj: K=64, NT=8
    int off = o;
    int j = off & 7, t = off >> 3;
    int q = t & 3; t >>= 2;
    int c = t & 15; t >>= 4;
    int kb = t & 1, ct = t >> 1;
    int k = kb * 32 + q * 8 + j, col = ct * 16 + c;
    wr[o] = f2bf(projW[(size_t)k * 128 + col]);
  } else if (o < 73728) {  // skip/c1/c2/c3: K=128, NT=8
    int region = (o - 8192) >> 14;
    int off = (o - 8192) & 16383;
    const float* W = region == 0 ? skipW : region == 1 ? c1W : region == 2 ? c2W : c3W;
    int j = off & 7, t = off >> 3;
    int q = t & 3; t >>= 2;
    int c = t & 15; t >>= 4;
    int kb = t & 3, ct = t >> 2;
    int k = kb * 32 + q * 8 + j, col = ct * 16 + c;
    wr[o] = f2bf(W[(size_t)k * 128 + col]);
  } else if (o < 83968) {  // cls: K=128, NT=5 (cols 0..63 W1, 64 confW, rest 0)
    int off = o - 73728;
    int j = off & 7, t = off >> 3;
    int q = t & 3; t >>= 2;
    int c = t & 15; t >>= 4;
    int kb = t & 3, ct = t >> 2;
    int k = kb * 32 + q * 8 + j, col = ct * 16 + c;
    float v = 0.f;
    if (col < 64) v = W1[(size_t)k * 64 + col];
    else if (col == 64) v = cw[k];
    wr[o] = f2bf(v);
  }
}

// ============================ shared device helpers ============================
template <int NH, int NT, int F>
static __device__ __forceinline__ void write_scores(const f32x4 (&acc)[F][NT],
                                                    const float* __restrict__ a_s,
                                                    const float* __restrict__ a_d,
                                                    int r0, int lane, int wv,
                                                    float* __restrict__ scs,
                                                    float* __restrict__ scd) {
  const int lr = lane & 15, lg = lane >> 4;
  float asv[NT], adv[NT];
#pragma unroll
  for (int ct = 0; ct < NT; ++ct) {
    asv[ct] = a_s[ct * 16 + lr];
    adv[ct] = a_d[ct * 16 + lr];
  }
  float ps[F][4][NH], pd[F][4][NH];
#pragma unroll
  for (int f = 0; f < F; ++f)
#pragma unroll
    for (int r = 0; r < 4; ++r)
#pragma unroll
      for (int h = 0; h < NH; ++h) { ps[f][r][h] = 0.f; pd[f][r][h] = 0.f; }
#pragma unroll
  for (int f = 0; f < F; ++f)
#pragma unroll
    for (int ct = 0; ct < NT; ++ct) {
      int h = (NH == 1) ? 0 : (ct >> 1);
#pragma unroll
      for (int r = 0; r < 4; ++r) {
        ps[f][r][h] = fmaf(acc[f][ct][r], asv[ct], ps[f][r][h]);
        pd[f][r][h] = fmaf(acc[f][ct][r], adv[ct], pd[f][r][h]);
      }
    }
#pragma unroll
  for (int off = 1; off < 16; off <<= 1)
#pragma unroll
    for (int f = 0; f < F; ++f)
#pragma unroll
      for (int r = 0; r < 4; ++r)
#pragma unroll
        for (int h = 0; h < NH; ++h) {
          ps[f][r][h] += __shfl_xor(ps[f][r][h], off);
          pd[f][r][h] += __shfl_xor(pd[f][r][h], off);
        }
  if (lr == 0) {
#pragma unroll
    for (int f = 0; f < F; ++f) {
      int rowb = r0 + (wv * F + f) * 16 + lg * 4;
#pragma unroll
      for (int r = 0; r < 4; ++r) {
        int gr = rowb + r;
        if (gr < NN) {
          if (NH == 4) {
            float4 vs = make_float4(ps[f][r][0], ps[f][r][1], ps[f][r][2], ps[f][r][3]);
            float4 vd = make_float4(pd[f][r][0], pd[f][r][1], pd[f][r][2], pd[f][r][3]);
            *(float4*)(scs + (size_t)gr * 4) = vs;
            *(float4*)(scd + (size_t)gr * 4) = vd;
          } else {
            scs[gr] = ps[f][r][0];
            scd[gr] = pd[f][r][0];
          }
        }
      }
    }
  }
}

template <int BIAS, int RELU, int NT, int F>
static __device__ __forceinline__ void write_out_bf(const f32x4 (&acc)[F][NT],
                                                    const float* __restrict__ bias,
                                                    int r0, int lane, int wv,
                                                    unsigned short* __restrict__ out) {
  const int lr = lane & 15, lg = lane >> 4;
#pragma unroll
  for (int f = 0; f < F; ++f) {
    int rowb = r0 + (wv * F + f) * 16 + lg * 4;
#pragma unroll
    for (int ct = 0; ct < NT; ++ct) {
      int col = ct * 16 + lr;
      float bb = BIAS ? bias[col] : 0.f;
#pragma unroll
      for (int r = 0; r < 4; ++r) {
        int gr = rowb + r;
        if (gr < NN) {
          float o = acc[f][ct][r] + bb;
          if (RELU) o = fmaxf(o, 0.f);
          out[(size_t)gr * 128 + col] = f2bf(o);
        }
      }
    }
  }
}

// ============================ MFMA GEMM ============================
// BM rows per block (64 or 128). BN: 0 none, 1 sc/sh, 2 +relu, 3 +skip+relu.
// BNP: 1 = 64 partial stat buffers. OUTM: 1 bf16 out; 2 classifier tail (BM must be 128).
// SCH: 0 off, 1/4 GAT scores.
template <int BM, int K, int NT, int ABF, int BN, int BNP, int BIAS, int RELU, int OUTM, int SCH>
__global__ __launch_bounds__(256) void k_mgemm(
    const void* __restrict__ Ain, const unsigned short* __restrict__ Bw,
    const float* __restrict__ bias,
    const float* __restrict__ bnsums, const float* __restrict__ bng,
    const float* __restrict__ bnb,
    const unsigned short* __restrict__ skip,
    const float* __restrict__ a_s, const float* __restrict__ a_d,
    const float* __restrict__ confb,
    void* __restrict__ Cout, float* __restrict__ conf,
    float* __restrict__ scs, float* __restrict__ scd,
    const float* __restrict__ W2, const float* __restrict__ b2,
    const float* __restrict__ W3, const float* __restrict__ b3,
    float* __restrict__ logits) {
  constexpr int KB = K / 32;
  constexpr int RT = BM / 16;       // row tiles
  constexpr int F = BM / 64;        // row tiles per wave
  __shared__ __align__(16) unsigned short sm[(RT + NT) * KB * 512];
  __shared__ float bnsc[128], bnsh[128];
  const int tid = threadIdx.x;
  const int r0 = blockIdx.x * BM;

  if constexpr (BN) {
    if (tid < K) {
      float s, q;
      if constexpr (BNP) {
        s = 0.f; q = 0.f;
#pragma unroll 8
        for (int pp = 0; pp < 64; ++pp) {
          s += bnsums[pp * 256 + tid];
          q += bnsums[pp * 256 + 128 + tid];
        }
      } else {
        s = bnsums[tid];
        q = bnsums[K + tid];
      }
      float invM = 1.f / (float)NN;
      float mu = s * invM;
      float var = q * invM - mu * mu;
      float sc = bng[tid] * rsqrtf(var + 1e-5f);
      bnsc[tid] = sc;
      bnsh[tid] = bnb[tid] - mu * sc;
    }
    __syncthreads();
  }

  // ---- stage A ----
  if constexpr (ABF) {
    const unsigned short* A = (const unsigned short*)Ain;
    constexpr int IT = BM * (K / 8) / 256;
#pragma unroll
    for (int it = 0; it < IT; ++it) {
      int idx = it * 256 + tid;
      int r = idx / (K / 8);
      int k = (idx % (K / 8)) * 8;
      int gr = r0 + r;
      union { uint4 u4; unsigned short us[8]; } v;
      v.u4 = make_uint4(0, 0, 0, 0);
      if (gr < NN) v.u4 = *(const uint4*)(A + (size_t)gr * K + k);
      if constexpr (BN) {
        union { uint4 u4; unsigned short us[8]; } sv;
        if (BN == 3) {
          sv.u4 = make_uint4(0, 0, 0, 0);
          if (gr < NN) sv.u4 = *(const uint4*)(skip + (size_t)gr * 128 + k);
        }
#pragma unroll
        for (int j = 0; j < 8; ++j) {
          float f = bf2f(v.us[j]) * bnsc[k + j] + bnsh[k + j];
          if (BN == 3) f += bf2f(sv.us[j]);
          if (BN >= 2) f = fmaxf(f, 0.f);
          v.us[j] = f2bf(f);
        }
      }
      *(uint4*)&sm[((r >> 4) * KB + (k >> 5)) * 512 + (r & 15) * 32 + (k & 31)] = v.u4;
    }
  } else {
    const float* A = (const float*)Ain;
    constexpr int IT = BM * (K / 4) / 256;
#pragma unroll
    for (int it = 0; it < IT; ++it) {
      int idx = it * 256 + tid;
      int r = idx / (K / 4);
      int k = (idx % (K / 4)) * 4;
      int gr = r0 + r;
      float4 av = make_float4(0.f, 0.f, 0.f, 0.f);
      if (gr < NN) av = *(const float4*)(A + (size_t)gr * K + k);
      if constexpr (BN) {
        av.x = av.x * bnsc[k + 0] + bnsh[k + 0];
        av.y = av.y * bnsc[k + 1] + bnsh[k + 1];
        av.z = av.z * bnsc[k + 2] + bnsh[k + 2];
        av.w = av.w * bnsc[k + 3] + bnsh[k + 3];
        if (BN >= 2) {
          av.x = fmaxf(av.x, 0.f); av.y = fmaxf(av.y, 0.f);
          av.z = fmaxf(av.z, 0.f); av.w = fmaxf(av.w, 0.f);
        }
      }
      ushort4 o;
      o.x = f2bf(av.x); o.y = f2bf(av.y); o.z = f2bf(av.z); o.w = f2bf(av.w);
      *(ushort4*)&sm[((r >> 4) * KB + (k >> 5)) * 512 + (r & 15) * 32 + (k & 31)] = o;
    }
  }
  // ---- stage B ----
  {
    constexpr int BW = NT * KB * 512;
#pragma unroll
    for (int it = 0; it < BW / 2048; ++it) {
      int idx = it * 256 + tid;
      *(uint4*)&sm[RT * KB * 512 + idx * 8] = *(const uint4*)(Bw + idx * 8);
    }
  }
  __syncthreads();

  // ---- MFMA ----
  const int lane = tid & 63, wv = tid >> 6;
  const int lr = lane & 15, lg = lane >> 4;
  const int fidx = lr * 32 + lg * 8;
  f32x4 acc[F][NT];
#pragma unroll
  for (int f = 0; f < F; ++f)
#pragma unroll
    for (int ct = 0; ct < NT; ++ct) acc[f][ct] = (f32x4){0.f, 0.f, 0.f, 0.f};
#pragma unroll
  for (int kb = 0; kb < KB; ++kb) {
    short8 afr[F];
#pragma unroll
    for (int f = 0; f < F; ++f)
      afr[f] = *(const short8*)&sm[((wv * F + f) * KB + kb) * 512 + fidx];
#pragma unroll
    for (int ct = 0; ct < NT; ++ct) {
      short8 b = *(const short8*)&sm[((RT + ct) * KB + kb) * 512 + fidx];
#pragma unroll
      for (int f = 0; f < F; ++f)
        acc[f][ct] = __builtin_amdgcn_mfma_f32_16x16x32_bf16(afr[f], b, acc[f][ct], 0, 0, 0);
    }
  }

  if constexpr (SCH > 0) {
    write_scores<(SCH == 1) ? 1 : 4>(acc, a_s, a_d, r0, lane, wv, scs, scd);
  }

  if constexpr (OUTM == 2) {
    // -------- classifier tail in-kernel (reuse sm; BM must be 128) --------
    __syncthreads();
    unsigned short* c1s = sm;                 // [128][65] bf16
    float* W2s = (float*)(sm + 8320);         // 64*32
    float* c2s = (float*)(sm + 12416);        // [128][33]
    float* W3s = (float*)(sm + 20864);        // 64
    float* b2s = (float*)(sm + 20992);        // 32
    float* b3s = (float*)(sm + 21056);        // 2
    for (int i = tid; i < 2048; i += 256) W2s[i] = W2[i];
    if (tid < 64) W3s[tid] = W3[tid];
    if (tid < 32) b2s[tid] = b2[tid];
    if (tid < 2) b3s[tid] = b3[tid];
#pragma unroll
    for (int f = 0; f < F; ++f) {
      int lrow = (wv * F + f) * 16 + lg * 4;
#pragma unroll
      for (int ct = 0; ct < NT; ++ct) {
        int col = ct * 16 + lr;
        if (col < 64) {
          float bb = bias[col];
#pragma unroll
          for (int r = 0; r < 4; ++r)
            c1s[(lrow + r) * 65 + col] = f2bf(fmaxf(acc[f][ct][r] + bb, 0.f));
        } else if (col == 64) {
          float cb = confb[0];
#pragma unroll
          for (int r = 0; r < 4; ++r) {
            int gr = r0 + lrow + r;
            if (gr < NN) conf[gr] = 1.f / (1.f + __expf(-(acc[f][ct][r] + cb)));
          }
        }
      }
    }
    __syncthreads();
    {
      int node = tid & 127;
      int cb = (tid >> 7) * 16;
      float a2[16];
#pragma unroll
      for (int i = 0; i < 16; ++i) a2[i] = b2s[cb + i];
      for (int k = 0; k < 64; ++k) {
        float v = bf2f(c1s[node * 65 + k]);
#pragma unroll
        for (int i = 0; i < 16; ++i) a2[i] = fmaf(v, W2s[k * 32 + cb + i], a2[i]);
      }
#pragma unroll
      for (int i = 0; i < 16; ++i) c2s[node * 33 + cb + i] = fmaxf(a2[i], 0.f);
    }
    __syncthreads();
    {
      int node = tid >> 1, j = tid & 1;
      float s3 = b3s[j];
#pragma unroll 8
      for (int k = 0; k < 32; ++k) s3 = fmaf(c2s[node * 33 + k], W3s[k * 2 + j], s3);
      int gr = r0 + node;
      if (gr < NN) logits[(size_t)gr * 2 + j] = s3;
    }
  } else {
    write_out_bf<BIAS, RELU>(acc, bias, r0, lane, wv, (unsigned short*)Cout);
  }
}

// ============================ dual-B MFMA GEMM (skip + conv1) ============================
__global__ __launch_bounds__(256) void k_mgemm_dual(
    const unsigned short* __restrict__ A, const unsigned short* __restrict__ Bw1,
    const float* __restrict__ bias1, const unsigned short* __restrict__ Bw2,
    const float* __restrict__ a_s, const float* __restrict__ a_d,
    unsigned short* __restrict__ Out1, unsigned short* __restrict__ Out2,
    float* __restrict__ scs, float* __restrict__ scd) {
  constexpr int KB = 4;  // K=128
  __shared__ __align__(16) unsigned short sm[16 * KB * 512];
  const int tid = threadIdx.x;
  const int r0 = blockIdx.x * 128;
#pragma unroll
  for (int it = 0; it < 8; ++it) {
    int idx = it * 256 + tid;
    int r = idx >> 4;
    int k = (idx & 15) * 8;
    int gr = r0 + r;
    uint4 v = make_uint4(0, 0, 0, 0);
    if (gr < NN) v = *(const uint4*)(A + (size_t)gr * 128 + k);
    *(uint4*)&sm[((r >> 4) * KB + (k >> 5)) * 512 + (r & 15) * 32 + (k & 31)] = v;
  }
#pragma unroll
  for (int it = 0; it < 8; ++it) {
    int idx = it * 256 + tid;
    *(uint4*)&sm[8 * KB * 512 + idx * 8] = *(const uint4*)(Bw1 + idx * 8);
  }
  __syncthreads();
  const int lane = tid & 63, wv = tid >> 6;
  const int lr = lane & 15, lg = lane >> 4;
  const int fidx = lr * 32 + lg * 8;
  f32x4 acc[2][8];
#pragma unroll
  for (int f = 0; f < 2; ++f)
#pragma unroll
    for (int ct = 0; ct < 8; ++ct) acc[f][ct] = (f32x4){0.f, 0.f, 0.f, 0.f};
#pragma unroll
  for (int kb = 0; kb < KB; ++kb) {
    short8 a0 = *(const short8*)&sm[((wv * 2 + 0) * KB + kb) * 512 + fidx];
    short8 a1 = *(const short8*)&sm[((wv * 2 + 1) * KB + kb) * 512 + fidx];
#pragma unroll
    for (int ct = 0; ct < 8; ++ct) {
      short8 b = *(const short8*)&sm[((8 + ct) * KB + kb) * 512 + fidx];
      acc[0][ct] = __builtin_amdgcn_mfma_f32_16x16x32_bf16(a0, b, acc[0][ct], 0, 0, 0);
      acc[1][ct] = __builtin_amdgcn_mfma_f32_16x16x32_bf16(a1, b, acc[1][ct], 0, 0, 0);
    }
  }
  write_out_bf<1, 0>(acc, bias1, r0, lane, wv, Out1);
  __syncthreads();
#pragma unroll
  for (int it = 0; it < 8; ++it) {
    int idx = it * 256 + tid;
    *(uint4*)&sm[8 * KB * 512 + idx * 8] = *(const uint4*)(Bw2 + idx * 8);
  }
  __syncthreads();
#pragma unroll
  for (int f = 0; f < 2; ++f)
#pragma unroll
    for (int ct = 0; ct < 8; ++ct) acc[f][ct] = (f32x4){0.f, 0.f, 0.f, 0.f};
#pragma unroll
  for (int kb = 0; kb < KB; ++kb) {
    short8 a0 = *(const short8*)&sm[((wv * 2 + 0) * KB + kb) * 512 + fidx];
    short8 a1 = *(const short8*)&sm[((wv * 2 + 1) * KB + kb) * 512 + fidx];
#pragma unroll
    for (int ct = 0; ct < 8; ++ct) {
      short8 b = *(const short8*)&sm[((8 + ct) * KB + kb) * 512 + fidx];
      acc[0][ct] = __builtin_amdgcn_mfma_f32_16x16x32_bf16(a0, b, acc[0][ct], 0, 0, 0);
      acc[1][ct] = __builtin_amdgcn_mfma_f32_16x16x32_bf16(a1, b, acc[1][ct], 0, 0, 0);
    }
  }
  write_scores<4>(acc, a_s, a_d, r0, lane, wv, scs, scd);
  write_out_bf<0, 0>(acc, nullptr, r0, lane, wv, Out2);
}

// ============================ GAT aggregation (+ fused BN stats) ============================
// TWO waves per dst node (64 channels each): 8 edge-groups x 8 lanes x 8 bf16 ch,
// 2-edge unroll = 16 edges in flight, srcl prefetched. Stats -> 64 partial buffers.
template <int H>
__global__ __launch_bounds__(256) void k_agg(const unsigned short* __restrict__ hp,
                                             const float* __restrict__ scs,
                                             const float* __restrict__ scd,
                                             const int* __restrict__ rowp,
                                             const int* __restrict__ srcl,
                                             const float* __restrict__ bias,
                                             unsigned short* __restrict__ out,
                                             float* __restrict__ part) {
  __shared__ float ssum[4][64], ssq[4][64];
  int tid = threadIdx.x;
  int lane = tid & 63, wv = tid >> 6;
  int gw = blockIdx.x * 4 + wv;   // global wave; grid exact: gw < 2*NN
  int n = gw >> 1;
  int half = gw & 1;
  int g = lane >> 3;              // edge group 0..7
  int l8 = lane & 7;
  int c0 = half * 64 + l8 * 8;    // 8 channels per lane
  int hid = (H == 1) ? 0 : (c0 >> 5);
  float sd = scd[(size_t)n * H + hid];
  int beg = rowp[n], end = rowp[n + 1];
  float a[8];
#pragma unroll
  for (int i = 0; i < 8; ++i) a[i] = 0.f;
  float sw = 0.f;
  int k = beg + g;
  int sA = (k < end) ? srcl[k] : 0;
  int sB = (k + 8 < end) ? srcl[k + 8] : 0;
  for (; k + 8 < end; k += 16) {
    int s0 = sA, s1 = sB;
    int kn = k + 16;
    sA = (kn < end) ? srcl[kn] : 0;
    sB = (kn + 8 < end) ? srcl[kn + 8] : 0;
    float e0 = scs[(size_t)s0 * H + hid] + sd;
    float e1 = scs[(size_t)s1 * H + hid] + sd;
    uint4 u = *(const uint4*)(hp + (size_t)s0 * 128 + c0);
    uint4 v = *(const uint4*)(hp + (size_t)s1 * 128 + c0);
    e0 = fmaxf(e0, 0.f) + 0.2f * fminf(e0, 0.f);
    e1 = fmaxf(e1, 0.f) + 0.2f * fminf(e1, 0.f);
    float w0 = __expf(e0), w1 = __expf(e1);
    a[0] = fmaf(w0, bf2f_lo(u.x), a[0]); a[1] = fmaf(w0, bf2f_hi(u.x), a[1]);
    a[2] = fmaf(w0, bf2f_lo(u.y), a[2]); a[3] = fmaf(w0, bf2f_hi(u.y), a[3]);
    a[4] = fmaf(w0, bf2f_lo(u.z), a[4]); a[5] = fmaf(w0, bf2f_hi(u.z), a[5]);
    a[6] = fmaf(w0, bf2f_lo(u.w), a[6]); a[7] = fmaf(w0, bf2f_hi(u.w), a[7]);
    a[0] = fmaf(w1, bf2f_lo(v.x), a[0]); a[1] = fmaf(w1, bf2f_hi(v.x), a[1]);
    a[2] = fmaf(w1, bf2f_lo(v.y), a[2]); a[3] = fmaf(w1, bf2f_hi(v.y), a[3]);
    a[4] = fmaf(w1, bf2f_lo(v.z), a[4]); a[5] = fmaf(w1, bf2f_hi(v.z), a[5]);
    a[6] = fmaf(w1, bf2f_lo(v.w), a[6]); a[7] = fmaf(w1, bf2f_hi(v.w), a[7]);
    sw += w0 + w1;
  }
  if (k < end) {
    int s0 = sA;
    float e0 = scs[(size_t)s0 * H + hid] + sd;
    uint4 u = *(const uint4*)(hp + (size_t)s0 * 128 + c0);
    e0 = fmaxf(e0, 0.f) + 0.2f * fminf(e0, 0.f);
    float w0 = __expf(e0);
    a[0] = fmaf(w0, bf2f_lo(u.x), a[0]); a[1] = fmaf(w0, bf2f_hi(u.x), a[1]);
    a[2] = fmaf(w0, bf2f_lo(u.y), a[2]); a[3] = fmaf(w0, bf2f_hi(u.y), a[3]);
    a[4] = fmaf(w0, bf2f_lo(u.z), a[4]); a[5] = fmaf(w0, bf2f_hi(u.z), a[5]);
    a[6] = fmaf(w0, bf2f_lo(u.w), a[6]); a[7] = fmaf(w0, bf2f_hi(u.w), a[7]);
    sw += w0;
  }
#pragma unroll
  for (int i = 0; i < 8; ++i) {
    a[i] += __shfl_xor(a[i], 8);
    a[i] += __shfl_xor(a[i], 16);
    a[i] += __shfl_xor(a[i], 32);
  }
  sw += __shfl_xor(sw, 8);
  sw += __shfl_xor(sw, 16);
  sw += __shfl_xor(sw, 32);
  if (g == 0) {
    float inv = 1.f / (sw + 1e-16f);
    unsigned wb[4];
#pragma unroll
    for (int j = 0; j < 4; ++j) {
      float o0 = a[2 * j] * inv + bias[c0 + 2 * j];
      float o1 = a[2 * j + 1] * inv + bias[c0 + 2 * j + 1];
      ssum[wv][l8 * 8 + 2 * j] = o0;
      ssum[wv][l8 * 8 + 2 * j + 1] = o1;
      ssq[wv][l8 * 8 + 2 * j] = o0 * o0;
      ssq[wv][l8 * 8 + 2 * j + 1] = o1 * o1;
      wb[j] = (unsigned)f2bf(o0) | ((unsigned)f2bf(o1) << 16);
    }
    *(uint4*)(out + (size_t)n * 128 + c0) = make_uint4(wb[0], wb[1], wb[2], wb[3]);
  }
  __syncthreads();
  if (tid < 128) {
    int hi = tid >> 6, c = tid & 63;
    float s = ssum[hi][c] + ssum[2 + hi][c];
    float q = ssq[hi][c] + ssq[2 + hi][c];
    int pb = (blockIdx.x & 63) * 256;
    atomicAdd(&part[pb + tid], s);
    atomicAdd(&part[pb + 128 + tid], q);
  }
}

// ============================ launch ============================
extern "C" void kernel_launch(void* const* d_in, const int* in_sizes, int n_in,
                              void* d_out, int out_size, void* d_ws, size_t ws_size,
                              hipStream_t stream) {
  (void)in_sizes; (void)n_in; (void)out_size; (void)ws_size;
  const float* x       = (const float*)d_in[0];
  const int*   ei      = (const int*)d_in[1];
  const float* in_g    = (const float*)d_in[2];
  const float* in_b    = (const float*)d_in[3];
  const float* projW   = (const float*)d_in[4];
  const float* projb   = (const float*)d_in[5];
  const float* skipW   = (const float*)d_in[6];
  const float* skipb   = (const float*)d_in[7];
  const float* c1W     = (const float*)d_in[8];
  const float* c1as    = (const float*)d_in[9];
  const float* c1ad    = (const float*)d_in[10];
  const float* c1b     = (const float*)d_in[11];
  const float* bn1g    = (const float*)d_in[12];
  const float* bn1b    = (const float*)d_in[13];
  const float* c2W     = (const float*)d_in[14];
  const float* c2as    = (const float*)d_in[15];
  const float* c2ad    = (const float*)d_in[16];
  const float* c2b     = (const float*)d_in[17];
  const float* bn2g    = (const float*)d_in[18];
  const float* bn2b    = (const float*)d_in[19];
  const float* c3W     = (const float*)d_in[20];
  const float* c3as    = (const float*)d_in[21];
  const float* c3ad    = (const float*)d_in[22];
  const float* c3b     = (const float*)d_in[23];
  const float* bn3g    = (const float*)d_in[24];
  const float* bn3b    = (const float*)d_in[25];
  const float* clsW1   = (const float*)d_in[26];
  const float* clsb1   = (const float*)d_in[27];
  const float* clsW2   = (const float*)d_in[28];
  const float* clsb2   = (const float*)d_in[29];
  const float* clsW3   = (const float*)d_in[30];
  const float* clsb3   = (const float*)d_in[31];
  const float* confW   = (const float*)d_in[32];
  const float* confb   = (const float*)d_in[33];

  float* out_logits = (float*)d_out;
  float* out_conf   = (float*)d_out + (size_t)NN * 2;

  char* p = (char*)d_ws;
  auto alloc = [&](size_t bytes) -> char* {
    char* r = p;
    p += (bytes + 255) & ~(size_t)255;
    return r;
  };
  unsigned short* hr  = (unsigned short*)alloc((size_t)NN * 128 * 2);  // relu(proj)
  unsigned short* hsk = (unsigned short*)alloc((size_t)NN * 128 * 2);  // h_skip
  unsigned short* hb  = (unsigned short*)alloc((size_t)NN * 128 * 2);  // conv h
  unsigned short* agA = (unsigned short*)alloc((size_t)NN * 128 * 2);  // agg out (L1, L3)
  unsigned short* agB = (unsigned short*)alloc((size_t)NN * 128 * 2);  // agg out (L2)
  float* scs   = (float*)alloc((size_t)NN * 4 * 4);
  float* scd   = (float*)alloc((size_t)NN * 4 * 4);
  // zero region: gpos | stats(x) | part1 | part2 | part3
  char*  zr    = alloc(2048 + 1024 + 3 * 65536);
  int*   gpos  = (int*)zr;
  float* stats = (float*)(zr + 2048);
  float* part1 = stats + 256;
  float* part2 = part1 + 16384;
  float* part3 = part2 + 16384;
  int*   rowp  = (int*)alloc((size_t)(NN + 1) * 4);
  int*   ebase = (int*)alloc((size_t)NBK * 4);
  unsigned* binned = (unsigned*)alloc((size_t)NBK * BCAP * 4);
  int*   srcl  = (int*)alloc((size_t)TOT_E * 4);
  unsigned short* wr = (unsigned short*)alloc(83968 * 2);
  unsigned short* wr_proj = wr;
  unsigned short* wr_skip = wr + 8192;
  unsigned short* wr_c1   = wr + 24576;
  unsigned short* wr_c2   = wr + 40960;
  unsigned short* wr_c3   = wr + 57344;
  unsigned short* wr_cls  = wr + 73728;

  const int GB64  = (NN + 63) / 64;    // 782
  const int GB128 = (NN + 127) / 128;  // 391
  const int AB    = (NN * 2) / 4;      // 25000 agg blocks (exact)

  k_reorder_all<<<328, 256, 0, stream>>>(projW, skipW, c1W, c2W, c3W, clsW1, confW, wr);
  hipMemsetAsync(zr, 0, 2048 + 1024 + 3 * 65536, stream);

  // ---- CSR build ----
  k_bin<<<256, 512, 0, stream>>>(ei, gpos, binned);
  k_bscan<<<1, 512, 0, stream>>>(gpos, ebase, rowp);
  k_bucket<<<NBK, 256, 0, stream>>>(binned, gpos, ebase, rowp, srcl);

  // ---- input BN stats ----
  k_bn_stats64<<<256, 256, 0, stream>>>(x, stats);

  // ---- proj: hr = relu(bn(x) @ projW + b) ----
  k_mgemm<64, 64, 8, 0, 1, 0, 1, 1, 1, 0><<<GB64, 256, 0, stream>>>(
      x, wr_proj, projb, stats, in_g, in_b, nullptr, nullptr, nullptr, nullptr,
      hr, nullptr, nullptr, nullptr, nullptr, nullptr, nullptr, nullptr, nullptr);

  // ---- dual: hsk = hr@skipW+b ; h1 = hr@c1W (+scores) ----
  k_mgemm_dual<<<GB128, 256, 0, stream>>>(hr, wr_skip, skipb, wr_c1, c1as, c1ad,
                                          hsk, hb, scs, scd);
  k_agg<4><<<AB, 256, 0, stream>>>(hb, scs, scd, rowp, srcl, c1b, agA, part1);

  // ---- GAT layer 2 (bn1+relu fused into A staging) ----
  k_mgemm<64, 128, 8, 1, 2, 1, 0, 0, 1, 4><<<GB64, 256, 0, stream>>>(
      agA, wr_c2, nullptr, part1, bn1g, bn1b, nullptr, c2as, c2ad, nullptr,
      hb, nullptr, scs, scd, nullptr, nullptr, nullptr, nullptr, nullptr);
  k_agg<4><<<AB, 256, 0, stream>>>(hb, scs, scd, rowp, srcl, c2b, agB, part2);

  // ---- GAT layer 3 (H=1; bn2+relu fused) ----
  k_mgemm<64, 128, 8, 1, 2, 1, 0, 0, 1, 1><<<GB64, 256, 0, stream>>>(
      agB, wr_c3, nullptr, part2, bn2g, bn2b, nullptr, c3as, c3ad, nullptr,
      hb, nullptr, scs, scd, nullptr, nullptr, nullptr, nullptr, nullptr);
  k_agg<1><<<AB, 256, 0, stream>>>(hb, scs, scd, rowp, srcl, c3b, agA, part3);

  // ---- classifier: relu(bn3(agA)+hsk) @ [W1|confW] -> C1(LDS) -> c2 -> logits/conf ----
  k_mgemm<128, 128, 5, 1, 3, 1, 1, 0, 2, 0><<<GB128, 256, 0, stream>>>(
      agA, wr_cls, clsb1, part3, bn3g, bn3b, hsk, nullptr, nullptr, confb,
      nullptr, out_conf, nullptr, nullptr, clsW2, clsb2, clsW3, clsb3, out_logits);
}

// Round 8
// 280.698 us; speedup vs baseline: 1.0576x; 1.0576x over previous
//
#include <hip/hip_runtime.h>
#include <cstdint>
#include <cstddef>

#define NN 50000
#define EE 800000
#define TOT_E (NN + EE)
#define NBK 391      // buckets of 128 dst nodes
#define BCAP 2560    // bucket capacity (mean 2048 -> 11 sigma headroom)

typedef __attribute__((ext_vector_type(8))) short short8;
typedef __attribute__((ext_vector_type(4))) float f32x4;

static __device__ __forceinline__ unsigned short f2bf(float f) {
  union { float f; unsigned u; } v;
  v.f = f;
  unsigned r = v.u + 0x7FFFu + ((v.u >> 16) & 1u);  // RNE
  return (unsigned short)(r >> 16);
}
static __device__ __forceinline__ float bf2f(unsigned short u) {
  union { unsigned u; float f; } v;
  v.u = ((unsigned)u) << 16;
  return v.f;
}
static __device__ __forceinline__ float bf2f_lo(unsigned u) {
  union { unsigned u; float f; } v;
  v.u = u << 16;
  return v.f;
}
static __device__ __forceinline__ float bf2f_hi(unsigned u) {
  union { unsigned u; float f; } v;
  v.u = u & 0xFFFF0000u;
  return v.f;
}

// ============================ CSR build: bucket binning ============================
__global__ __launch_bounds__(512) void k_bin(const int* __restrict__ ei,
                                             int* __restrict__ gpos,
                                             unsigned* __restrict__ binned) {
  __shared__ int cnt[512];
  __shared__ int base[512];
  int tx = threadIdx.x;
  cnt[tx] = 0;
  __syncthreads();
  int e0 = blockIdx.x * 3125;
  int e1 = e0 + 3125;
  if (e1 > EE) e1 = EE;
  for (int i = e0 + tx; i < e1; i += 512) {
    int d = ei[EE + i];
    atomicAdd(&cnt[d >> 7], 1);
  }
  __syncthreads();
  if (tx < NBK) {
    int c = cnt[tx];
    base[tx] = c ? atomicAdd(&gpos[tx], c) : 0;
    cnt[tx] = 0;
  }
  __syncthreads();
  for (int i = e0 + tx; i < e1; i += 512) {
    int s = ei[i];
    int d = ei[EE + i];
    int b = d >> 7;
    int slot = base[b] + atomicAdd(&cnt[b], 1);
    if (slot < BCAP) binned[(size_t)b * BCAP + slot] = (unsigned)s | ((unsigned)(d & 127) << 16);
  }
}
__global__ __launch_bounds__(512) void k_bscan(const int* __restrict__ gpos,
                                               int* __restrict__ ebase,
                                               int* __restrict__ rowp) {
  __shared__ int sh[512];
  int tx = threadIdx.x;
  int v = 0;
  if (tx < NBK) {
    int nodes = NN - (tx << 7);
    if (nodes > 128) nodes = 128;
    int g = gpos[tx];
    if (g > BCAP) g = BCAP;
    v = g + nodes;
  }
  sh[tx] = v;
  __syncthreads();
  for (int off = 1; off < 512; off <<= 1) {
    int t = (tx >= off) ? sh[tx - off] : 0;
    __syncthreads();
    sh[tx] += t;
    __syncthreads();
  }
  if (tx < NBK) ebase[tx] = sh[tx] - v;
  if (tx == NBK - 1) rowp[NN] = sh[tx];
}
__global__ __launch_bounds__(256) void k_bucket(const unsigned* __restrict__ binned,
                                                const int* __restrict__ gpos,
                                                const int* __restrict__ ebase,
                                                int* __restrict__ rowp,
                                                int* __restrict__ srcl) {
  __shared__ int cnt[128], offs[128], cur[128];
  int b = blockIdx.x, tid = threadIdx.x;
  int n0 = b << 7;
  int nodes = NN - n0;
  if (nodes > 128) nodes = 128;
  int ne = gpos[b];
  if (ne > BCAP) ne = BCAP;
  int eb = ebase[b];
  if (tid < 128) cnt[tid] = (tid < nodes) ? 1 : 0;  // 1 = self-loop
  __syncthreads();
  const unsigned* bb = binned + (size_t)b * BCAP;
  for (int i = tid; i < ne; i += 256) atomicAdd(&cnt[bb[i] >> 16], 1);
  __syncthreads();
  if (tid < 128) offs[tid] = cnt[tid];
  __syncthreads();
  for (int o = 1; o < 128; o <<= 1) {
    int t = (tid < 128 && tid >= o) ? offs[tid - o] : 0;
    __syncthreads();
    if (tid < 128) offs[tid] += t;
    __syncthreads();
  }
  if (tid < 128 && tid < nodes) {
    int ex = offs[tid] - cnt[tid];
    rowp[n0 + tid] = eb + ex;
    srcl[eb + ex] = n0 + tid;  // self-loop first (segment order irrelevant)
    cur[tid] = ex + 1;
  }
  __syncthreads();
  for (int i = tid; i < ne; i += 256) {
    unsigned e = bb[i];
    int r = atomicAdd(&cur[e >> 16], 1);
    srcl[eb + r] = (int)(e & 0xFFFFu);
  }
}

// ============================ BN stats for x (f32, C=64) ============================
__global__ __launch_bounds__(256) void k_bn_stats64(const float* __restrict__ x,
                                                    float* __restrict__ sums) {
  int col = threadIdx.x & 63;
  int rsub = threadIdx.x >> 6;
  float s = 0.f, q = 0.f;
  for (int r = blockIdx.x * 4 + rsub; r < NN; r += gridDim.x * 4) {
    float v = x[(size_t)r * 64 + col];
    s += v;
    q += v * v;
  }
  __shared__ float bs[256], bq[256];
  bs[threadIdx.x] = s;
  bq[threadIdx.x] = q;
  __syncthreads();
  if (threadIdx.x < 64) {
#pragma unroll
    for (int i = 1; i < 4; ++i) {
      s += bs[threadIdx.x + i * 64];
      q += bq[threadIdx.x + i * 64];
    }
    atomicAdd(&sums[col], s);
    atomicAdd(&sums[64 + col], q);
  }
}

// ============================ fused weight reorder ============================
__global__ void k_reorder_all(const float* __restrict__ projW, const float* __restrict__ skipW,
                              const float* __restrict__ c1W, const float* __restrict__ c2W,
                              const float* __restrict__ c3W, const float* __restrict__ W1,
                              const float* __restrict__ cw, unsigned short* __restrict__ wr) {
  int o = blockIdx.x * 256 + threadIdx.x;
  if (o < 8192) {  // proj: K=64, NT=8
    int off = o;
    int j = off & 7, t = off >> 3;
    int q = t & 3; t >>= 2;
    int c = t & 15; t >>= 4;
    int kb = t & 1, ct = t >> 1;
    int k = kb * 32 + q * 8 + j, col = ct * 16 + c;
    wr[o] = f2bf(projW[(size_t)k * 128 + col]);
  } else if (o < 73728) {  // skip/c1/c2/c3: K=128, NT=8
    int region = (o - 8192) >> 14;
    int off = (o - 8192) & 16383;
    const float* W = region == 0 ? skipW : region == 1 ? c1W : region == 2 ? c2W : c3W;
    int j = off & 7, t = off >> 3;
    int q = t & 3; t >>= 2;
    int c = t & 15; t >>= 4;
    int kb = t & 3, ct = t >> 2;
    int k = kb * 32 + q * 8 + j, col = ct * 16 + c;
    wr[o] = f2bf(W[(size_t)k * 128 + col]);
  } else if (o < 83968) {  // cls: K=128, NT=5 (cols 0..63 W1, 64 confW, rest 0)
    int off = o - 73728;
    int j = off & 7, t = off >> 3;
    int q = t & 3; t >>= 2;
    int c = t & 15; t >>= 4;
    int kb = t & 3, ct = t >> 2;
    int k = kb * 32 + q * 8 + j, col = ct * 16 + c;
    float v = 0.f;
    if (col < 64) v = W1[(size_t)k * 64 + col];
    else if (col == 64) v = cw[k];
    wr[o] = f2bf(v);
  }
}

// ============================ shared device helpers ============================
template <int NH, int NT, int F>
static __device__ __forceinline__ void write_scores(const f32x4 (&acc)[F][NT],
                                                    const float* __restrict__ a_s,
                                                    const float* __restrict__ a_d,
                                                    int r0, int lane, int wv,
                                                    float* __restrict__ scs,
                                                    float* __restrict__ scd) {
  const int lr = lane & 15, lg = lane >> 4;
  float asv[NT], adv[NT];
#pragma unroll
  for (int ct = 0; ct < NT; ++ct) {
    asv[ct] = a_s[ct * 16 + lr];
    adv[ct] = a_d[ct * 16 + lr];
  }
  float ps[F][4][NH], pd[F][4][NH];
#pragma unroll
  for (int f = 0; f < F; ++f)
#pragma unroll
    for (int r = 0; r < 4; ++r)
#pragma unroll
      for (int h = 0; h < NH; ++h) { ps[f][r][h] = 0.f; pd[f][r][h] = 0.f; }
#pragma unroll
  for (int f = 0; f < F; ++f)
#pragma unroll
    for (int ct = 0; ct < NT; ++ct) {
      int h = (NH == 1) ? 0 : (ct >> 1);
#pragma unroll
      for (int r = 0; r < 4; ++r) {
        ps[f][r][h] = fmaf(acc[f][ct][r], asv[ct], ps[f][r][h]);
        pd[f][r][h] = fmaf(acc[f][ct][r], adv[ct], pd[f][r][h]);
      }
    }
#pragma unroll
  for (int off = 1; off < 16; off <<= 1)
#pragma unroll
    for (int f = 0; f < F; ++f)
#pragma unroll
      for (int r = 0; r < 4; ++r)
#pragma unroll
        for (int h = 0; h < NH; ++h) {
          ps[f][r][h] += __shfl_xor(ps[f][r][h], off);
          pd[f][r][h] += __shfl_xor(pd[f][r][h], off);
        }
  if (lr == 0) {
#pragma unroll
    for (int f = 0; f < F; ++f) {
      int rowb = r0 + (wv * F + f) * 16 + lg * 4;
#pragma unroll
      for (int r = 0; r < 4; ++r) {
        int gr = rowb + r;
        if (gr < NN) {
          if (NH == 4) {
            float4 vs = make_float4(ps[f][r][0], ps[f][r][1], ps[f][r][2], ps[f][r][3]);
            float4 vd = make_float4(pd[f][r][0], pd[f][r][1], pd[f][r][2], pd[f][r][3]);
            *(float4*)(scs + (size_t)gr * 4) = vs;
            *(float4*)(scd + (size_t)gr * 4) = vd;
          } else {
            scs[gr] = ps[f][r][0];
            scd[gr] = pd[f][r][0];
          }
        }
      }
    }
  }
}

template <int BIAS, int RELU, int NT, int F>
static __device__ __forceinline__ void write_out_bf(const f32x4 (&acc)[F][NT],
                                                    const float* __restrict__ bias,
                                                    int r0, int lane, int wv,
                                                    unsigned short* __restrict__ out) {
  const int lr = lane & 15, lg = lane >> 4;
#pragma unroll
  for (int f = 0; f < F; ++f) {
    int rowb = r0 + (wv * F + f) * 16 + lg * 4;
#pragma unroll
    for (int ct = 0; ct < NT; ++ct) {
      int col = ct * 16 + lr;
      float bb = BIAS ? bias[col] : 0.f;
#pragma unroll
      for (int r = 0; r < 4; ++r) {
        int gr = rowb + r;
        if (gr < NN) {
          float o = acc[f][ct][r] + bb;
          if (RELU) o = fmaxf(o, 0.f);
          out[(size_t)gr * 128 + col] = f2bf(o);
        }
      }
    }
  }
}

// ============================ MFMA GEMM ============================
// BM rows per block (64 or 128). BN: 0 none, 1 sc/sh, 2 +relu, 3 +skip+relu.
// BNP: 1 = 64 partial stat buffers. OUTM: 1 bf16 out; 2 classifier tail (BM must be 128).
// SCH: 0 off, 1/4 GAT scores.
template <int BM, int K, int NT, int ABF, int BN, int BNP, int BIAS, int RELU, int OUTM, int SCH>
__global__ __launch_bounds__(256) void k_mgemm(
    const void* __restrict__ Ain, const unsigned short* __restrict__ Bw,
    const float* __restrict__ bias,
    const float* __restrict__ bnsums, const float* __restrict__ bng,
    const float* __restrict__ bnb,
    const unsigned short* __restrict__ skip,
    const float* __restrict__ a_s, const float* __restrict__ a_d,
    const float* __restrict__ confb,
    void* __restrict__ Cout, float* __restrict__ conf,
    float* __restrict__ scs, float* __restrict__ scd,
    const float* __restrict__ W2, const float* __restrict__ b2,
    const float* __restrict__ W3, const float* __restrict__ b3,
    float* __restrict__ logits) {
  constexpr int KB = K / 32;
  constexpr int RT = BM / 16;       // row tiles
  constexpr int F = BM / 64;        // row tiles per wave
  __shared__ __align__(16) unsigned short sm[(RT + NT) * KB * 512];
  __shared__ float bnsc[128], bnsh[128];
  const int tid = threadIdx.x;
  const int r0 = blockIdx.x * BM;

  if constexpr (BN) {
    if (tid < K) {
      float s, q;
      if constexpr (BNP) {
        s = 0.f; q = 0.f;
#pragma unroll 8
        for (int pp = 0; pp < 64; ++pp) {
          s += bnsums[pp * 256 + tid];
          q += bnsums[pp * 256 + 128 + tid];
        }
      } else {
        s = bnsums[tid];
        q = bnsums[K + tid];
      }
      float invM = 1.f / (float)NN;
      float mu = s * invM;
      float var = q * invM - mu * mu;
      float sc = bng[tid] * rsqrtf(var + 1e-5f);
      bnsc[tid] = sc;
      bnsh[tid] = bnb[tid] - mu * sc;
    }
    __syncthreads();
  }

  // ---- stage A ----
  if constexpr (ABF) {
    const unsigned short* A = (const unsigned short*)Ain;
    constexpr int IT = BM * (K / 8) / 256;
#pragma unroll
    for (int it = 0; it < IT; ++it) {
      int idx = it * 256 + tid;
      int r = idx / (K / 8);
      int k = (idx % (K / 8)) * 8;
      int gr = r0 + r;
      union { uint4 u4; unsigned short us[8]; } v;
      v.u4 = make_uint4(0, 0, 0, 0);
      if (gr < NN) v.u4 = *(const uint4*)(A + (size_t)gr * K + k);
      if constexpr (BN) {
        union { uint4 u4; unsigned short us[8]; } sv;
        if (BN == 3) {
          sv.u4 = make_uint4(0, 0, 0, 0);
          if (gr < NN) sv.u4 = *(const uint4*)(skip + (size_t)gr * 128 + k);
        }
#pragma unroll
        for (int j = 0; j < 8; ++j) {
          float f = bf2f(v.us[j]) * bnsc[k + j] + bnsh[k + j];
          if (BN == 3) f += bf2f(sv.us[j]);
          if (BN >= 2) f = fmaxf(f, 0.f);
          v.us[j] = f2bf(f);
        }
      }
      *(uint4*)&sm[((r >> 4) * KB + (k >> 5)) * 512 + (r & 15) * 32 + (k & 31)] = v.u4;
    }
  } else {
    const float* A = (const float*)Ain;
    constexpr int IT = BM * (K / 4) / 256;
#pragma unroll
    for (int it = 0; it < IT; ++it) {
      int idx = it * 256 + tid;
      int r = idx / (K / 4);
      int k = (idx % (K / 4)) * 4;
      int gr = r0 + r;
      float4 av = make_float4(0.f, 0.f, 0.f, 0.f);
      if (gr < NN) av = *(const float4*)(A + (size_t)gr * K + k);
      if constexpr (BN) {
        av.x = av.x * bnsc[k + 0] + bnsh[k + 0];
        av.y = av.y * bnsc[k + 1] + bnsh[k + 1];
        av.z = av.z * bnsc[k + 2] + bnsh[k + 2];
        av.w = av.w * bnsc[k + 3] + bnsh[k + 3];
        if (BN >= 2) {
          av.x = fmaxf(av.x, 0.f); av.y = fmaxf(av.y, 0.f);
          av.z = fmaxf(av.z, 0.f); av.w = fmaxf(av.w, 0.f);
        }
      }
      ushort4 o;
      o.x = f2bf(av.x); o.y = f2bf(av.y); o.z = f2bf(av.z); o.w = f2bf(av.w);
      *(ushort4*)&sm[((r >> 4) * KB + (k >> 5)) * 512 + (r & 15) * 32 + (k & 31)] = o;
    }
  }
  // ---- stage B ----
  {
    constexpr int BW = NT * KB * 512;
#pragma unroll
    for (int it = 0; it < BW / 2048; ++it) {
      int idx = it * 256 + tid;
      *(uint4*)&sm[RT * KB * 512 + idx * 8] = *(const uint4*)(Bw + idx * 8);
    }
  }
  __syncthreads();

  // ---- MFMA ----
  const int lane = tid & 63, wv = tid >> 6;
  const int lr = lane & 15, lg = lane >> 4;
  const int fidx = lr * 32 + lg * 8;
  f32x4 acc[F][NT];
#pragma unroll
  for (int f = 0; f < F; ++f)
#pragma unroll
    for (int ct = 0; ct < NT; ++ct) acc[f][ct] = (f32x4){0.f, 0.f, 0.f, 0.f};
#pragma unroll
  for (int kb = 0; kb < KB; ++kb) {
    short8 afr[F];
#pragma unroll
    for (int f = 0; f < F; ++f)
      afr[f] = *(const short8*)&sm[((wv * F + f) * KB + kb) * 512 + fidx];
#pragma unroll
    for (int ct = 0; ct < NT; ++ct) {
      short8 b = *(const short8*)&sm[((RT + ct) * KB + kb) * 512 + fidx];
#pragma unroll
      for (int f = 0; f < F; ++f)
        acc[f][ct] = __builtin_amdgcn_mfma_f32_16x16x32_bf16(afr[f], b, acc[f][ct], 0, 0, 0);
    }
  }

  if constexpr (SCH > 0) {
    write_scores<(SCH == 1) ? 1 : 4>(acc, a_s, a_d, r0, lane, wv, scs, scd);
  }

  if constexpr (OUTM == 2) {
    // -------- classifier tail in-kernel (reuse sm; BM must be 128) --------
    __syncthreads();
    unsigned short* c1s = sm;                 // [128][65] bf16
    float* W2s = (float*)(sm + 8320);         // 64*32
    float* c2s = (float*)(sm + 12416);        // [128][33]
    float* W3s = (float*)(sm + 20864);        // 64
    float* b2s = (float*)(sm + 20992);        // 32
    float* b3s = (float*)(sm + 21056);        // 2
    for (int i = tid; i < 2048; i += 256) W2s[i] = W2[i];
    if (tid < 64) W3s[tid] = W3[tid];
    if (tid < 32) b2s[tid] = b2[tid];
    if (tid < 2) b3s[tid] = b3[tid];
#pragma unroll
    for (int f = 0; f < F; ++f) {
      int lrow = (wv * F + f) * 16 + lg * 4;
#pragma unroll
      for (int ct = 0; ct < NT; ++ct) {
        int col = ct * 16 + lr;
        if (col < 64) {
          float bb = bias[col];
#pragma unroll
          for (int r = 0; r < 4; ++r)
            c1s[(lrow + r) * 65 + col] = f2bf(fmaxf(acc[f][ct][r] + bb, 0.f));
        } else if (col == 64) {
          float cb = confb[0];
#pragma unroll
          for (int r = 0; r < 4; ++r) {
            int gr = r0 + lrow + r;
            if (gr < NN) conf[gr] = 1.f / (1.f + __expf(-(acc[f][ct][r] + cb)));
          }
        }
      }
    }
    __syncthreads();
    {
      int node = tid & 127;
      int cb = (tid >> 7) * 16;
      float a2[16];
#pragma unroll
      for (int i = 0; i < 16; ++i) a2[i] = b2s[cb + i];
      for (int k = 0; k < 64; ++k) {
        float v = bf2f(c1s[node * 65 + k]);
#pragma unroll
        for (int i = 0; i < 16; ++i) a2[i] = fmaf(v, W2s[k * 32 + cb + i], a2[i]);
      }
#pragma unroll
      for (int i = 0; i < 16; ++i) c2s[node * 33 + cb + i] = fmaxf(a2[i], 0.f);
    }
    __syncthreads();
    {
      int node = tid >> 1, j = tid & 1;
      float s3 = b3s[j];
#pragma unroll 8
      for (int k = 0; k < 32; ++k) s3 = fmaf(c2s[node * 33 + k], W3s[k * 2 + j], s3);
      int gr = r0 + node;
      if (gr < NN) logits[(size_t)gr * 2 + j] = s3;
    }
  } else {
    write_out_bf<BIAS, RELU>(acc, bias, r0, lane, wv, (unsigned short*)Cout);
  }
}

// ============================ dual-B MFMA GEMM (skip + conv1) ============================
__global__ __launch_bounds__(256) void k_mgemm_dual(
    const unsigned short* __restrict__ A, const unsigned short* __restrict__ Bw1,
    const float* __restrict__ bias1, const unsigned short* __restrict__ Bw2,
    const float* __restrict__ a_s, const float* __restrict__ a_d,
    unsigned short* __restrict__ Out1, unsigned short* __restrict__ Out2,
    float* __restrict__ scs, float* __restrict__ scd) {
  constexpr int KB = 4;  // K=128
  __shared__ __align__(16) unsigned short sm[16 * KB * 512];
  const int tid = threadIdx.x;
  const int r0 = blockIdx.x * 128;
#pragma unroll
  for (int it = 0; it < 8; ++it) {
    int idx = it * 256 + tid;
    int r = idx >> 4;
    int k = (idx & 15) * 8;
    int gr = r0 + r;
    uint4 v = make_uint4(0, 0, 0, 0);
    if (gr < NN) v = *(const uint4*)(A + (size_t)gr * 128 + k);
    *(uint4*)&sm[((r >> 4) * KB + (k >> 5)) * 512 + (r & 15) * 32 + (k & 31)] = v;
  }
#pragma unroll
  for (int it = 0; it < 8; ++it) {
    int idx = it * 256 + tid;
    *(uint4*)&sm[8 * KB * 512 + idx * 8] = *(const uint4*)(Bw1 + idx * 8);
  }
  __syncthreads();
  const int lane = tid & 63, wv = tid >> 6;
  const int lr = lane & 15, lg = lane >> 4;
  const int fidx = lr * 32 + lg * 8;
  f32x4 acc[2][8];
#pragma unroll
  for (int f = 0; f < 2; ++f)
#pragma unroll
    for (int ct = 0; ct < 8; ++ct) acc[f][ct] = (f32x4){0.f, 0.f, 0.f, 0.f};
#pragma unroll
  for (int kb = 0; kb < KB; ++kb) {
    short8 a0 = *(const short8*)&sm[((wv * 2 + 0) * KB + kb) * 512 + fidx];
    short8 a1 = *(const short8*)&sm[((wv * 2 + 1) * KB + kb) * 512 + fidx];
#pragma unroll
    for (int ct = 0; ct < 8; ++ct) {
      short8 b = *(const short8*)&sm[((8 + ct) * KB + kb) * 512 + fidx];
      acc[0][ct] = __builtin_amdgcn_mfma_f32_16x16x32_bf16(a0, b, acc[0][ct], 0, 0, 0);
      acc[1][ct] = __builtin_amdgcn_mfma_f32_16x16x32_bf16(a1, b, acc[1][ct], 0, 0, 0);
    }
  }
  write_out_bf<1, 0>(acc, bias1, r0, lane, wv, Out1);
  __syncthreads();
#pragma unroll
  for (int it = 0; it < 8; ++it) {
    int idx = it * 256 + tid;
    *(uint4*)&sm[8 * KB * 512 + idx * 8] = *(const uint4*)(Bw2 + idx * 8);
  }
  __syncthreads();
#pragma unroll
  for (int f = 0; f < 2; ++f)
#pragma unroll
    for (int ct = 0; ct < 8; ++ct) acc[f][ct] = (f32x4){0.f, 0.f, 0.f, 0.f};
#pragma unroll
  for (int kb = 0; kb < KB; ++kb) {
    short8 a0 = *(const short8*)&sm[((wv * 2 + 0) * KB + kb) * 512 + fidx];
    short8 a1 = *(const short8*)&sm[((wv * 2 + 1) * KB + kb) * 512 + fidx];
#pragma unroll
    for (int ct = 0; ct < 8; ++ct) {
      short8 b = *(const short8*)&sm[((8 + ct) * KB + kb) * 512 + fidx];
      acc[0][ct] = __builtin_amdgcn_mfma_f32_16x16x32_bf16(a0, b, acc[0][ct], 0, 0, 0);
      acc[1][ct] = __builtin_amdgcn_mfma_f32_16x16x32_bf16(a1, b, acc[1][ct], 0, 0, 0);
    }
  }
  write_scores<4>(acc, a_s, a_d, r0, lane, wv, scs, scd);
  write_out_bf<0, 0>(acc, nullptr, r0, lane, wv, Out2);
}

// ============================ GAT aggregation (+ fused BN stats) ============================
// ONE wave per dst node: 8 edge-groups x 8 ch-lanes x 16 bf16 channels,
// 2-edge unroll = 16 edges in flight, srcl prefetched one iter ahead.
// Stats go through padded LDS (idx = c + (c>>4): lane bases stride 17 -> conflict-free)
// then 64-way partial buffers via atomicAdd.
template <int H>
__global__ __launch_bounds__(256) void k_agg(const unsigned short* __restrict__ hp,
                                             const float* __restrict__ scs,
                                             const float* __restrict__ scd,
                                             const int* __restrict__ rowp,
                                             const int* __restrict__ srcl,
                                             const float* __restrict__ bias,
                                             unsigned short* __restrict__ out,
                                             float* __restrict__ part) {
  __shared__ float ssum[4][136], ssq[4][136];
  int tid = threadIdx.x;
  int lane = tid & 63, wv = tid >> 6;
  int n = blockIdx.x * 4 + wv;   // grid exact: n < NN
  int g = lane >> 3;             // edge group 0..7
  int l8 = lane & 7;             // channel lane
  int c0 = l8 * 16;
  int hid = (H == 1) ? 0 : (l8 >> 1);
  float sd = scd[(size_t)n * H + hid];
  int beg = rowp[n], end = rowp[n + 1];
  float a[16];
#pragma unroll
  for (int i = 0; i < 16; ++i) a[i] = 0.f;
  float sw = 0.f;
  int k = beg + g;
  int sA = (k < end) ? srcl[k] : 0;
  int sB = (k + 8 < end) ? srcl[k + 8] : 0;
  for (; k + 8 < end; k += 16) {
    int s0 = sA, s1 = sB;
    int kn = k + 16;
    sA = (kn < end) ? srcl[kn] : 0;
    sB = (kn + 8 < end) ? srcl[kn + 8] : 0;
    float e0 = scs[(size_t)s0 * H + hid] + sd;
    float e1 = scs[(size_t)s1 * H + hid] + sd;
    const uint4* p0 = (const uint4*)(hp + (size_t)s0 * 128 + c0);
    const uint4* p1 = (const uint4*)(hp + (size_t)s1 * 128 + c0);
    uint4 u0 = p0[0], u1 = p0[1];
    uint4 v0 = p1[0], v1 = p1[1];
    e0 = fmaxf(e0, 0.f) + 0.2f * fminf(e0, 0.f);
    e1 = fmaxf(e1, 0.f) + 0.2f * fminf(e1, 0.f);
    float w0 = __expf(e0), w1 = __expf(e1);
    a[0] = fmaf(w0, bf2f_lo(u0.x), a[0]); a[1] = fmaf(w0, bf2f_hi(u0.x), a[1]);
    a[2] = fmaf(w0, bf2f_lo(u0.y), a[2]); a[3] = fmaf(w0, bf2f_hi(u0.y), a[3]);
    a[4] = fmaf(w0, bf2f_lo(u0.z), a[4]); a[5] = fmaf(w0, bf2f_hi(u0.z), a[5]);
    a[6] = fmaf(w0, bf2f_lo(u0.w), a[6]); a[7] = fmaf(w0, bf2f_hi(u0.w), a[7]);
    a[8] = fmaf(w0, bf2f_lo(u1.x), a[8]); a[9] = fmaf(w0, bf2f_hi(u1.x), a[9]);
    a[10] = fmaf(w0, bf2f_lo(u1.y), a[10]); a[11] = fmaf(w0, bf2f_hi(u1.y), a[11]);
    a[12] = fmaf(w0, bf2f_lo(u1.z), a[12]); a[13] = fmaf(w0, bf2f_hi(u1.z), a[13]);
    a[14] = fmaf(w0, bf2f_lo(u1.w), a[14]); a[15] = fmaf(w0, bf2f_hi(u1.w), a[15]);
    a[0] = fmaf(w1, bf2f_lo(v0.x), a[0]); a[1] = fmaf(w1, bf2f_hi(v0.x), a[1]);
    a[2] = fmaf(w1, bf2f_lo(v0.y), a[2]); a[3] = fmaf(w1, bf2f_hi(v0.y), a[3]);
    a[4] = fmaf(w1, bf2f_lo(v0.z), a[4]); a[5] = fmaf(w1, bf2f_hi(v0.z), a[5]);
    a[6] = fmaf(w1, bf2f_lo(v0.w), a[6]); a[7] = fmaf(w1, bf2f_hi(v0.w), a[7]);
    a[8] = fmaf(w1, bf2f_lo(v1.x), a[8]); a[9] = fmaf(w1, bf2f_hi(v1.x), a[9]);
    a[10] = fmaf(w1, bf2f_lo(v1.y), a[10]); a[11] = fmaf(w1, bf2f_hi(v1.y), a[11]);
    a[12] = fmaf(w1, bf2f_lo(v1.z), a[12]); a[13] = fmaf(w1, bf2f_hi(v1.z), a[13]);
    a[14] = fmaf(w1, bf2f_lo(v1.w), a[14]); a[15] = fmaf(w1, bf2f_hi(v1.w), a[15]);
    sw += w0 + w1;
  }
  if (k < end) {
    int s0 = sA;
    float e0 = scs[(size_t)s0 * H + hid] + sd;
    const uint4* p0 = (const uint4*)(hp + (size_t)s0 * 128 + c0);
    uint4 u0 = p0[0], u1 = p0[1];
    e0 = fmaxf(e0, 0.f) + 0.2f * fminf(e0, 0.f);
    float w0 = __expf(e0);
    a[0] = fmaf(w0, bf2f_lo(u0.x), a[0]); a[1] = fmaf(w0, bf2f_hi(u0.x), a[1]);
    a[2] = fmaf(w0, bf2f_lo(u0.y), a[2]); a[3] = fmaf(w0, bf2f_hi(u0.y), a[3]);
    a[4] = fmaf(w0, bf2f_lo(u0.z), a[4]); a[5] = fmaf(w0, bf2f_hi(u0.z), a[5]);
    a[6] = fmaf(w0, bf2f_lo(u0.w), a[6]); a[7] = fmaf(w0, bf2f_hi(u0.w), a[7]);
    a[8] = fmaf(w0, bf2f_lo(u1.x), a[8]); a[9] = fmaf(w0, bf2f_hi(u1.x), a[9]);
    a[10] = fmaf(w0, bf2f_lo(u1.y), a[10]); a[11] = fmaf(w0, bf2f_hi(u1.y), a[11]);
    a[12] = fmaf(w0, bf2f_lo(u1.z), a[12]); a[13] = fmaf(w0, bf2f_hi(u1.z), a[13]);
    a[14] = fmaf(w0, bf2f_lo(u1.w), a[14]); a[15] = fmaf(w0, bf2f_hi(u1.w), a[15]);
    sw += w0;
  }
#pragma unroll
  for (int i = 0; i < 16; ++i) {
    a[i] += __shfl_xor(a[i], 8);
    a[i] += __shfl_xor(a[i], 16);
    a[i] += __shfl_xor(a[i], 32);
  }
  sw += __shfl_xor(sw, 8);
  sw += __shfl_xor(sw, 16);
  sw += __shfl_xor(sw, 32);
  if (g == 0) {
    float inv = 1.f / (sw + 1e-16f);
    unsigned wb[8];
#pragma unroll
    for (int j = 0; j < 8; ++j) {
      float o0 = a[2 * j] * inv + bias[c0 + 2 * j];
      float o1 = a[2 * j + 1] * inv + bias[c0 + 2 * j + 1];
      int i0 = c0 + 2 * j + l8;      // padded: c + (c>>4), c>>4 == l8 for this lane
      ssum[wv][i0] = o0;
      ssum[wv][i0 + 1] = o1;
      ssq[wv][i0] = o0 * o0;
      ssq[wv][i0 + 1] = o1 * o1;
      wb[j] = (unsigned)f2bf(o0) | ((unsigned)f2bf(o1) << 16);
    }
    *(uint4*)(out + (size_t)n * 128 + c0) = make_uint4(wb[0], wb[1], wb[2], wb[3]);
    *(uint4*)(out + (size_t)n * 128 + c0 + 8) = make_uint4(wb[4], wb[5], wb[6], wb[7]);
  }
  __syncthreads();
  if (tid < 128) {
    int idx = tid + (tid >> 4);
    float s = ssum[0][idx] + ssum[1][idx] + ssum[2][idx] + ssum[3][idx];
    float q = ssq[0][idx] + ssq[1][idx] + ssq[2][idx] + ssq[3][idx];
    int pb = (blockIdx.x & 63) * 256;
    atomicAdd(&part[pb + tid], s);
    atomicAdd(&part[pb + 128 + tid], q);
  }
}

// ============================ launch ============================
extern "C" void kernel_launch(void* const* d_in, const int* in_sizes, int n_in,
                              void* d_out, int out_size, void* d_ws, size_t ws_size,
                              hipStream_t stream) {
  (void)in_sizes; (void)n_in; (void)out_size; (void)ws_size;
  const float* x       = (const float*)d_in[0];
  const int*   ei      = (const int*)d_in[1];
  const float* in_g    = (const float*)d_in[2];
  const float* in_b    = (const float*)d_in[3];
  const float* projW   = (const float*)d_in[4];
  const float* projb   = (const float*)d_in[5];
  const float* skipW   = (const float*)d_in[6];
  const float* skipb   = (const float*)d_in[7];
  const float* c1W     = (const float*)d_in[8];
  const float* c1as    = (const float*)d_in[9];
  const float* c1ad    = (const float*)d_in[10];
  const float* c1b     = (const float*)d_in[11];
  const float* bn1g    = (const float*)d_in[12];
  const float* bn1b    = (const float*)d_in[13];
  const float* c2W     = (const float*)d_in[14];
  const float* c2as    = (const float*)d_in[15];
  const float* c2ad    = (const float*)d_in[16];
  const float* c2b     = (const float*)d_in[17];
  const float* bn2g    = (const float*)d_in[18];
  const float* bn2b    = (const float*)d_in[19];
  const float* c3W     = (const float*)d_in[20];
  const float* c3as    = (const float*)d_in[21];
  const float* c3ad    = (const float*)d_in[22];
  const float* c3b     = (const float*)d_in[23];
  const float* bn3g    = (const float*)d_in[24];
  const float* bn3b    = (const float*)d_in[25];
  const float* clsW1   = (const float*)d_in[26];
  const float* clsb1   = (const float*)d_in[27];
  const float* clsW2   = (const float*)d_in[28];
  const float* clsb2   = (const float*)d_in[29];
  const float* clsW3   = (const float*)d_in[30];
  const float* clsb3   = (const float*)d_in[31];
  const float* confW   = (const float*)d_in[32];
  const float* confb   = (const float*)d_in[33];

  float* out_logits = (float*)d_out;
  float* out_conf   = (float*)d_out + (size_t)NN * 2;

  char* p = (char*)d_ws;
  auto alloc = [&](size_t bytes) -> char* {
    char* r = p;
    p += (bytes + 255) & ~(size_t)255;
    return r;
  };
  unsigned short* hr  = (unsigned short*)alloc((size_t)NN * 128 * 2);  // relu(proj)
  unsigned short* hsk = (unsigned short*)alloc((size_t)NN * 128 * 2);  // h_skip
  unsigned short* hb  = (unsigned short*)alloc((size_t)NN * 128 * 2);  // conv h
  unsigned short* agA = (unsigned short*)alloc((size_t)NN * 128 * 2);  // agg out (L1, L3)
  unsigned short* agB = (unsigned short*)alloc((size_t)NN * 128 * 2);  // agg out (L2)
  float* scs   = (float*)alloc((size_t)NN * 4 * 4);
  float* scd   = (float*)alloc((size_t)NN * 4 * 4);
  // zero region: gpos | stats(x) | part1 | part2 | part3
  char*  zr    = alloc(2048 + 1024 + 3 * 65536);
  int*   gpos  = (int*)zr;
  float* stats = (float*)(zr + 2048);
  float* part1 = stats + 256;
  float* part2 = part1 + 16384;
  float* part3 = part2 + 16384;
  int*   rowp  = (int*)alloc((size_t)(NN + 1) * 4);
  int*   ebase = (int*)alloc((size_t)NBK * 4);
  unsigned* binned = (unsigned*)alloc((size_t)NBK * BCAP * 4);
  int*   srcl  = (int*)alloc((size_t)TOT_E * 4);
  unsigned short* wr = (unsigned short*)alloc(83968 * 2);
  unsigned short* wr_proj = wr;
  unsigned short* wr_skip = wr + 8192;
  unsigned short* wr_c1   = wr + 24576;
  unsigned short* wr_c2   = wr + 40960;
  unsigned short* wr_c3   = wr + 57344;
  unsigned short* wr_cls  = wr + 73728;

  const int GB64  = (NN + 63) / 64;    // 782
  const int GB128 = (NN + 127) / 128;  // 391
  const int AB    = NN / 4;            // 12500 agg blocks (exact, 1 wave/node)

  k_reorder_all<<<328, 256, 0, stream>>>(projW, skipW, c1W, c2W, c3W, clsW1, confW, wr);
  hipMemsetAsync(zr, 0, 2048 + 1024 + 3 * 65536, stream);

  // ---- CSR build ----
  k_bin<<<256, 512, 0, stream>>>(ei, gpos, binned);
  k_bscan<<<1, 512, 0, stream>>>(gpos, ebase, rowp);
  k_bucket<<<NBK, 256, 0, stream>>>(binned, gpos, ebase, rowp, srcl);

  // ---- input BN stats ----
  k_bn_stats64<<<256, 256, 0, stream>>>(x, stats);

  // ---- proj: hr = relu(bn(x) @ projW + b) ----
  k_mgemm<64, 64, 8, 0, 1, 0, 1, 1, 1, 0><<<GB64, 256, 0, stream>>>(
      x, wr_proj, projb, stats, in_g, in_b, nullptr, nullptr, nullptr, nullptr,
      hr, nullptr, nullptr, nullptr, nullptr, nullptr, nullptr, nullptr, nullptr);

  // ---- dual: hsk = hr@skipW+b ; h1 = hr@c1W (+scores) ----
  k_mgemm_dual<<<GB128, 256, 0, stream>>>(hr, wr_skip, skipb, wr_c1, c1as, c1ad,
                                          hsk, hb, scs, scd);
  k_agg<4><<<AB, 256, 0, stream>>>(hb, scs, scd, rowp, srcl, c1b, agA, part1);

  // ---- GAT layer 2 (bn1+relu fused into A staging) ----
  k_mgemm<64, 128, 8, 1, 2, 1, 0, 0, 1, 4><<<GB64, 256, 0, stream>>>(
      agA, wr_c2, nullptr, part1, bn1g, bn1b, nullptr, c2as, c2ad, nullptr,
      hb, nullptr, scs, scd, nullptr, nullptr, nullptr, nullptr, nullptr);
  k_agg<4><<<AB, 256, 0, stream>>>(hb, scs, scd, rowp, srcl, c2b, agB, part2);

  // ---- GAT layer 3 (H=1; bn2+relu fused) ----
  k_mgemm<64, 128, 8, 1, 2, 1, 0, 0, 1, 1><<<GB64, 256, 0, stream>>>(
      agB, wr_c3, nullptr, part2, bn2g, bn2b, nullptr, c3as, c3ad, nullptr,
      hb, nullptr, scs, scd, nullptr, nullptr, nullptr, nullptr, nullptr);
  k_agg<1><<<AB, 256, 0, stream>>>(hb, scs, scd, rowp, srcl, c3b, agA, part3);

  // ---- classifier: relu(bn3(agA)+hsk) @ [W1|confW] -> C1(LDS) -> c2 -> logits/conf ----
  k_mgemm<128, 128, 5, 1, 3, 1, 1, 0, 2, 0><<<GB128, 256, 0, stream>>>(
      agA, wr_cls, clsb1, part3, bn3g, bn3b, hsk, nullptr, nullptr, confb,
      nullptr, out_conf, nullptr, nullptr, clsW2, clsb2, clsW3, clsb3, out_logits);
}

// Round 9
// 250.485 us; speedup vs baseline: 1.1851x; 1.1206x over previous
//
#include <hip/hip_runtime.h>
#include <cstdint>
#include <cstddef>

#define NN 50000
#define EE 800000
#define TOT_E (NN + EE)
#define NBK 391      // buckets of 128 dst nodes
#define BCAP 2560    // bucket capacity (mean 2048 -> 11 sigma headroom)

typedef __attribute__((ext_vector_type(8))) short short8;
typedef __attribute__((ext_vector_type(4))) float f32x4;

static __device__ __forceinline__ unsigned short f2bf(float f) {
  union { float f; unsigned u; } v;
  v.f = f;
  unsigned r = v.u + 0x7FFFu + ((v.u >> 16) & 1u);  // RNE
  return (unsigned short)(r >> 16);
}
static __device__ __forceinline__ float bf2f(unsigned short u) {
  union { unsigned u; float f; } v;
  v.u = ((unsigned)u) << 16;
  return v.f;
}
static __device__ __forceinline__ float bf2f_lo(unsigned u) {
  union { unsigned u; float f; } v;
  v.u = u << 16;
  return v.f;
}
static __device__ __forceinline__ float bf2f_hi(unsigned u) {
  union { unsigned u; float f; } v;
  v.u = u & 0xFFFF0000u;
  return v.f;
}

// ============================ CSR build: bucket binning ============================
__global__ __launch_bounds__(512) void k_bin(const int* __restrict__ ei,
                                             int* __restrict__ gpos,
                                             unsigned* __restrict__ binned) {
  __shared__ int cnt[512];
  __shared__ int base[512];
  int tx = threadIdx.x;
  cnt[tx] = 0;
  __syncthreads();
  int e0 = blockIdx.x * 3125;
  int e1 = e0 + 3125;
  if (e1 > EE) e1 = EE;
  for (int i = e0 + tx; i < e1; i += 512) {
    int d = ei[EE + i];
    atomicAdd(&cnt[d >> 7], 1);
  }
  __syncthreads();
  if (tx < NBK) {
    int c = cnt[tx];
    base[tx] = c ? atomicAdd(&gpos[tx], c) : 0;
    cnt[tx] = 0;
  }
  __syncthreads();
  for (int i = e0 + tx; i < e1; i += 512) {
    int s = ei[i];
    int d = ei[EE + i];
    int b = d >> 7;
    int slot = base[b] + atomicAdd(&cnt[b], 1);
    if (slot < BCAP) binned[(size_t)b * BCAP + slot] = (unsigned)s | ((unsigned)(d & 127) << 16);
  }
}
__global__ __launch_bounds__(512) void k_bscan(const int* __restrict__ gpos,
                                               int* __restrict__ ebase,
                                               int* __restrict__ rowp) {
  __shared__ int sh[512];
  int tx = threadIdx.x;
  int v = 0;
  if (tx < NBK) {
    int nodes = NN - (tx << 7);
    if (nodes > 128) nodes = 128;
    int g = gpos[tx];
    if (g > BCAP) g = BCAP;
    v = g + nodes;
  }
  sh[tx] = v;
  __syncthreads();
  for (int off = 1; off < 512; off <<= 1) {
    int t = (tx >= off) ? sh[tx - off] : 0;
    __syncthreads();
    sh[tx] += t;
    __syncthreads();
  }
  if (tx < NBK) ebase[tx] = sh[tx] - v;
  if (tx == NBK - 1) rowp[NN] = sh[tx];
}
__global__ __launch_bounds__(256) void k_bucket(const unsigned* __restrict__ binned,
                                                const int* __restrict__ gpos,
                                                const int* __restrict__ ebase,
                                                int* __restrict__ rowp,
                                                int* __restrict__ srcl) {
  __shared__ int cnt[128], offs[128], cur[128];
  int b = blockIdx.x, tid = threadIdx.x;
  int n0 = b << 7;
  int nodes = NN - n0;
  if (nodes > 128) nodes = 128;
  int ne = gpos[b];
  if (ne > BCAP) ne = BCAP;
  int eb = ebase[b];
  if (tid < 128) cnt[tid] = (tid < nodes) ? 1 : 0;  // 1 = self-loop
  __syncthreads();
  const unsigned* bb = binned + (size_t)b * BCAP;
  for (int i = tid; i < ne; i += 256) atomicAdd(&cnt[bb[i] >> 16], 1);
  __syncthreads();
  if (tid < 128) offs[tid] = cnt[tid];
  __syncthreads();
  for (int o = 1; o < 128; o <<= 1) {
    int t = (tid < 128 && tid >= o) ? offs[tid - o] : 0;
    __syncthreads();
    if (tid < 128) offs[tid] += t;
    __syncthreads();
  }
  if (tid < 128 && tid < nodes) {
    int ex = offs[tid] - cnt[tid];
    rowp[n0 + tid] = eb + ex;
    srcl[eb + ex] = n0 + tid;  // self-loop first (segment order irrelevant)
    cur[tid] = ex + 1;
  }
  __syncthreads();
  for (int i = tid; i < ne; i += 256) {
    unsigned e = bb[i];
    int r = atomicAdd(&cur[e >> 16], 1);
    srcl[eb + r] = (int)(e & 0xFFFFu);
  }
}

// ============================ BN stats for x (f32, C=64) ============================
__global__ __launch_bounds__(256) void k_bn_stats64(const float* __restrict__ x,
                                                    float* __restrict__ sums) {
  int col = threadIdx.x & 63;
  int rsub = threadIdx.x >> 6;
  float s = 0.f, q = 0.f;
  for (int r = blockIdx.x * 4 + rsub; r < NN; r += gridDim.x * 4) {
    float v = x[(size_t)r * 64 + col];
    s += v;
    q += v * v;
  }
  __shared__ float bs[256], bq[256];
  bs[threadIdx.x] = s;
  bq[threadIdx.x] = q;
  __syncthreads();
  if (threadIdx.x < 64) {
#pragma unroll
    for (int i = 1; i < 4; ++i) {
      s += bs[threadIdx.x + i * 64];
      q += bq[threadIdx.x + i * 64];
    }
    atomicAdd(&sums[col], s);
    atomicAdd(&sums[64 + col], q);
  }
}

// ============================ fused weight reorder ============================
__global__ void k_reorder_all(const float* __restrict__ projW, const float* __restrict__ skipW,
                              const float* __restrict__ c1W, const float* __restrict__ c2W,
                              const float* __restrict__ c3W, const float* __restrict__ W1,
                              const float* __restrict__ cw, unsigned short* __restrict__ wr) {
  int o = blockIdx.x * 256 + threadIdx.x;
  if (o < 8192) {  // proj: K=64, NT=8
    int off = o;
    int j = off & 7, t = off >> 3;
    int q = t & 3; t >>= 2;
    int c = t & 15; t >>= 4;
    int kb = t & 1, ct = t >> 1;
    int k = kb * 32 + q * 8 + j, col = ct * 16 + c;
    wr[o] = f2bf(projW[(size_t)k * 128 + col]);
  } else if (o < 73728) {  // skip/c1/c2/c3: K=128, NT=8
    int region = (o - 8192) >> 14;
    int off = (o - 8192) & 16383;
    const float* W = region == 0 ? skipW : region == 1 ? c1W : region == 2 ? c2W : c3W;
    int j = off & 7, t = off >> 3;
    int q = t & 3; t >>= 2;
    int c = t & 15; t >>= 4;
    int kb = t & 3, ct = t >> 2;
    int k = kb * 32 + q * 8 + j, col = ct * 16 + c;
    wr[o] = f2bf(W[(size_t)k * 128 + col]);
  } else if (o < 83968) {  // cls: K=128, NT=5 (cols 0..63 W1, 64 confW, rest 0)
    int off = o - 73728;
    int j = off & 7, t = off >> 3;
    int q = t & 3; t >>= 2;
    int c = t & 15; t >>= 4;
    int kb = t & 3, ct = t >> 2;
    int k = kb * 32 + q * 8 + j, col = ct * 16 + c;
    float v = 0.f;
    if (col < 64) v = W1[(size_t)k * 64 + col];
    else if (col == 64) v = cw[k];
    wr[o] = f2bf(v);
  }
}

// ============================ shared device helpers ============================
template <int NH, int NT, int F>
static __device__ __forceinline__ void write_scores(const f32x4 (&acc)[F][NT],
                                                    const float* __restrict__ a_s,
                                                    const float* __restrict__ a_d,
                                                    int r0, int lane, int wv,
                                                    float* __restrict__ scs,
                                                    float* __restrict__ scd) {
  const int lr = lane & 15, lg = lane >> 4;
  float asv[NT], adv[NT];
#pragma unroll
  for (int ct = 0; ct < NT; ++ct) {
    asv[ct] = a_s[ct * 16 + lr];
    adv[ct] = a_d[ct * 16 + lr];
  }
  float ps[F][4][NH], pd[F][4][NH];
#pragma unroll
  for (int f = 0; f < F; ++f)
#pragma unroll
    for (int r = 0; r < 4; ++r)
#pragma unroll
      for (int h = 0; h < NH; ++h) { ps[f][r][h] = 0.f; pd[f][r][h] = 0.f; }
#pragma unroll
  for (int f = 0; f < F; ++f)
#pragma unroll
    for (int ct = 0; ct < NT; ++ct) {
      int h = (NH == 1) ? 0 : (ct >> 1);
#pragma unroll
      for (int r = 0; r < 4; ++r) {
        ps[f][r][h] = fmaf(acc[f][ct][r], asv[ct], ps[f][r][h]);
        pd[f][r][h] = fmaf(acc[f][ct][r], adv[ct], pd[f][r][h]);
      }
    }
#pragma unroll
  for (int off = 1; off < 16; off <<= 1)
#pragma unroll
    for (int f = 0; f < F; ++f)
#pragma unroll
      for (int r = 0; r < 4; ++r)
#pragma unroll
        for (int h = 0; h < NH; ++h) {
          ps[f][r][h] += __shfl_xor(ps[f][r][h], off);
          pd[f][r][h] += __shfl_xor(pd[f][r][h], off);
        }
  if (lr == 0) {
#pragma unroll
    for (int f = 0; f < F; ++f) {
      int rowb = r0 + (wv * F + f) * 16 + lg * 4;
#pragma unroll
      for (int r = 0; r < 4; ++r) {
        int gr = rowb + r;
        if (gr < NN) {
          if (NH == 4) {
            float4 vs = make_float4(ps[f][r][0], ps[f][r][1], ps[f][r][2], ps[f][r][3]);
            float4 vd = make_float4(pd[f][r][0], pd[f][r][1], pd[f][r][2], pd[f][r][3]);
            *(float4*)(scs + (size_t)gr * 4) = vs;
            *(float4*)(scd + (size_t)gr * 4) = vd;
          } else {
            scs[gr] = ps[f][r][0];
            scd[gr] = pd[f][r][0];
          }
        }
      }
    }
  }
}

template <int BIAS, int RELU, int NT, int F>
static __device__ __forceinline__ void write_out_bf(const f32x4 (&acc)[F][NT],
                                                    const float* __restrict__ bias,
                                                    int r0, int lane, int wv,
                                                    unsigned short* __restrict__ out) {
  const int lr = lane & 15, lg = lane >> 4;
#pragma unroll
  for (int f = 0; f < F; ++f) {
    int rowb = r0 + (wv * F + f) * 16 + lg * 4;
#pragma unroll
    for (int ct = 0; ct < NT; ++ct) {
      int col = ct * 16 + lr;
      float bb = BIAS ? bias[col] : 0.f;
#pragma unroll
      for (int r = 0; r < 4; ++r) {
        int gr = rowb + r;
        if (gr < NN) {
          float o = acc[f][ct][r] + bb;
          if (RELU) o = fmaxf(o, 0.f);
          out[(size_t)gr * 128 + col] = f2bf(o);
        }
      }
    }
  }
}

// ============================ MFMA GEMM ============================
// BM rows per block (64 or 128). BN: 0 none, 1 sc/sh, 2 +relu, 3 +skip+relu.
// BNP: 1 = 64 partial stat buffers. OUTM: 1 bf16 out; 2 classifier tail (BM must be 128).
// SCH: 0 off, 1/4 GAT scores.
template <int BM, int K, int NT, int ABF, int BN, int BNP, int BIAS, int RELU, int OUTM, int SCH>
__global__ __launch_bounds__(256) void k_mgemm(
    const void* __restrict__ Ain, const unsigned short* __restrict__ Bw,
    const float* __restrict__ bias,
    const float* __restrict__ bnsums, const float* __restrict__ bng,
    const float* __restrict__ bnb,
    const unsigned short* __restrict__ skip,
    const float* __restrict__ a_s, const float* __restrict__ a_d,
    const float* __restrict__ confb,
    void* __restrict__ Cout, float* __restrict__ conf,
    float* __restrict__ scs, float* __restrict__ scd,
    const float* __restrict__ W2, const float* __restrict__ b2,
    const float* __restrict__ W3, const float* __restrict__ b3,
    float* __restrict__ logits) {
  constexpr int KB = K / 32;
  constexpr int RT = BM / 16;       // row tiles
  constexpr int F = BM / 64;        // row tiles per wave
  __shared__ __align__(16) unsigned short sm[(RT + NT) * KB * 512];
  __shared__ float bnsc[128], bnsh[128];
  const int tid = threadIdx.x;
  const int r0 = blockIdx.x * BM;

  if constexpr (BN) {
    if (tid < K) {
      float s, q;
      if constexpr (BNP) {
        s = 0.f; q = 0.f;
#pragma unroll 8
        for (int pp = 0; pp < 64; ++pp) {
          s += bnsums[pp * 256 + tid];
          q += bnsums[pp * 256 + 128 + tid];
        }
      } else {
        s = bnsums[tid];
        q = bnsums[K + tid];
      }
      float invM = 1.f / (float)NN;
      float mu = s * invM;
      float var = q * invM - mu * mu;
      float sc = bng[tid] * rsqrtf(var + 1e-5f);
      bnsc[tid] = sc;
      bnsh[tid] = bnb[tid] - mu * sc;
    }
    __syncthreads();
  }

  // ---- stage A ----
  if constexpr (ABF) {
    const unsigned short* A = (const unsigned short*)Ain;
    constexpr int IT = BM * (K / 8) / 256;
#pragma unroll
    for (int it = 0; it < IT; ++it) {
      int idx = it * 256 + tid;
      int r = idx / (K / 8);
      int k = (idx % (K / 8)) * 8;
      int gr = r0 + r;
      union { uint4 u4; unsigned short us[8]; } v;
      v.u4 = make_uint4(0, 0, 0, 0);
      if (gr < NN) v.u4 = *(const uint4*)(A + (size_t)gr * K + k);
      if constexpr (BN) {
        union { uint4 u4; unsigned short us[8]; } sv;
        if (BN == 3) {
          sv.u4 = make_uint4(0, 0, 0, 0);
          if (gr < NN) sv.u4 = *(const uint4*)(skip + (size_t)gr * 128 + k);
        }
#pragma unroll
        for (int j = 0; j < 8; ++j) {
          float f = bf2f(v.us[j]) * bnsc[k + j] + bnsh[k + j];
          if (BN == 3) f += bf2f(sv.us[j]);
          if (BN >= 2) f = fmaxf(f, 0.f);
          v.us[j] = f2bf(f);
        }
      }
      *(uint4*)&sm[((r >> 4) * KB + (k >> 5)) * 512 + (r & 15) * 32 + (k & 31)] = v.u4;
    }
  } else {
    const float* A = (const float*)Ain;
    constexpr int IT = BM * (K / 4) / 256;
#pragma unroll
    for (int it = 0; it < IT; ++it) {
      int idx = it * 256 + tid;
      int r = idx / (K / 4);
      int k = (idx % (K / 4)) * 4;
      int gr = r0 + r;
      float4 av = make_float4(0.f, 0.f, 0.f, 0.f);
      if (gr < NN) av = *(const float4*)(A + (size_t)gr * K + k);
      if constexpr (BN) {
        av.x = av.x * bnsc[k + 0] + bnsh[k + 0];
        av.y = av.y * bnsc[k + 1] + bnsh[k + 1];
        av.z = av.z * bnsc[k + 2] + bnsh[k + 2];
        av.w = av.w * bnsc[k + 3] + bnsh[k + 3];
        if (BN >= 2) {
          av.x = fmaxf(av.x, 0.f); av.y = fmaxf(av.y, 0.f);
          av.z = fmaxf(av.z, 0.f); av.w = fmaxf(av.w, 0.f);
        }
      }
      ushort4 o;
      o.x = f2bf(av.x); o.y = f2bf(av.y); o.z = f2bf(av.z); o.w = f2bf(av.w);
      *(ushort4*)&sm[((r >> 4) * KB + (k >> 5)) * 512 + (r & 15) * 32 + (k & 31)] = o;
    }
  }
  // ---- stage B ----
  {
    constexpr int BW = NT * KB * 512;
#pragma unroll
    for (int it = 0; it < BW / 2048; ++it) {
      int idx = it * 256 + tid;
      *(uint4*)&sm[RT * KB * 512 + idx * 8] = *(const uint4*)(Bw + idx * 8);
    }
  }
  __syncthreads();

  // ---- MFMA ----
  const int lane = tid & 63, wv = tid >> 6;
  const int lr = lane & 15, lg = lane >> 4;
  const int fidx = lr * 32 + lg * 8;
  f32x4 acc[F][NT];
#pragma unroll
  for (int f = 0; f < F; ++f)
#pragma unroll
    for (int ct = 0; ct < NT; ++ct) acc[f][ct] = (f32x4){0.f, 0.f, 0.f, 0.f};
#pragma unroll
  for (int kb = 0; kb < KB; ++kb) {
    short8 afr[F];
#pragma unroll
    for (int f = 0; f < F; ++f)
      afr[f] = *(const short8*)&sm[((wv * F + f) * KB + kb) * 512 + fidx];
#pragma unroll
    for (int ct = 0; ct < NT; ++ct) {
      short8 b = *(const short8*)&sm[((RT + ct) * KB + kb) * 512 + fidx];
#pragma unroll
      for (int f = 0; f < F; ++f)
        acc[f][ct] = __builtin_amdgcn_mfma_f32_16x16x32_bf16(afr[f], b, acc[f][ct], 0, 0, 0);
    }
  }

  if constexpr (SCH > 0) {
    write_scores<(SCH == 1) ? 1 : 4>(acc, a_s, a_d, r0, lane, wv, scs, scd);
  }

  if constexpr (OUTM == 2) {
    // -------- classifier tail in-kernel (reuse sm; BM must be 128) --------
    __syncthreads();
    unsigned short* c1s = sm;                 // [128][65] bf16
    float* W2s = (float*)(sm + 8320);         // 64*32
    float* c2s = (float*)(sm + 12416);        // [128][33]
    float* W3s = (float*)(sm + 20864);        // 64
    float* b2s = (float*)(sm + 20992);        // 32
    float* b3s = (float*)(sm + 21056);        // 2
    for (int i = tid; i < 2048; i += 256) W2s[i] = W2[i];
    if (tid < 64) W3s[tid] = W3[tid];
    if (tid < 32) b2s[tid] = b2[tid];
    if (tid < 2) b3s[tid] = b3[tid];
#pragma unroll
    for (int f = 0; f < F; ++f) {
      int lrow = (wv * F + f) * 16 + lg * 4;
#pragma unroll
      for (int ct = 0; ct < NT; ++ct) {
        int col = ct * 16 + lr;
        if (col < 64) {
          float bb = bias[col];
#pragma unroll
          for (int r = 0; r < 4; ++r)
            c1s[(lrow + r) * 65 + col] = f2bf(fmaxf(acc[f][ct][r] + bb, 0.f));
        } else if (col == 64) {
          float cb = confb[0];
#pragma unroll
          for (int r = 0; r < 4; ++r) {
            int gr = r0 + lrow + r;
            if (gr < NN) conf[gr] = 1.f / (1.f + __expf(-(acc[f][ct][r] + cb)));
          }
        }
      }
    }
    __syncthreads();
    {
      int node = tid & 127;
      int cb = (tid >> 7) * 16;
      float a2[16];
#pragma unroll
      for (int i = 0; i < 16; ++i) a2[i] = b2s[cb + i];
      for (int k = 0; k < 64; ++k) {
        float v = bf2f(c1s[node * 65 + k]);
#pragma unroll
        for (int i = 0; i < 16; ++i) a2[i] = fmaf(v, W2s[k * 32 + cb + i], a2[i]);
      }
#pragma unroll
      for (int i = 0; i < 16; ++i) c2s[node * 33 + cb + i] = fmaxf(a2[i], 0.f);
    }
    __syncthreads();
    {
      int node = tid >> 1, j = tid & 1;
      float s3 = b3s[j];
#pragma unroll 8
      for (int k = 0; k < 32; ++k) s3 = fmaf(c2s[node * 33 + k], W3s[k * 2 + j], s3);
      int gr = r0 + node;
      if (gr < NN) logits[(size_t)gr * 2 + j] = s3;
    }
  } else {
    write_out_bf<BIAS, RELU>(acc, bias, r0, lane, wv, (unsigned short*)Cout);
  }
}

// ============================ dual-B MFMA GEMM (skip + conv1) ============================
__global__ __launch_bounds__(256) void k_mgemm_dual(
    const unsigned short* __restrict__ A, const unsigned short* __restrict__ Bw1,
    const float* __restrict__ bias1, const unsigned short* __restrict__ Bw2,
    const float* __restrict__ a_s, const float* __restrict__ a_d,
    unsigned short* __restrict__ Out1, unsigned short* __restrict__ Out2,
    float* __restrict__ scs, float* __restrict__ scd) {
  constexpr int KB = 4;  // K=128
  __shared__ __align__(16) unsigned short sm[16 * KB * 512];
  const int tid = threadIdx.x;
  const int r0 = blockIdx.x * 128;
#pragma unroll
  for (int it = 0; it < 8; ++it) {
    int idx = it * 256 + tid;
    int r = idx >> 4;
    int k = (idx & 15) * 8;
    int gr = r0 + r;
    uint4 v = make_uint4(0, 0, 0, 0);
    if (gr < NN) v = *(const uint4*)(A + (size_t)gr * 128 + k);
    *(uint4*)&sm[((r >> 4) * KB + (k >> 5)) * 512 + (r & 15) * 32 + (k & 31)] = v;
  }
#pragma unroll
  for (int it = 0; it < 8; ++it) {
    int idx = it * 256 + tid;
    *(uint4*)&sm[8 * KB * 512 + idx * 8] = *(const uint4*)(Bw1 + idx * 8);
  }
  __syncthreads();
  const int lane = tid & 63, wv = tid >> 6;
  const int lr = lane & 15, lg = lane >> 4;
  const int fidx = lr * 32 + lg * 8;
  f32x4 acc[2][8];
#pragma unroll
  for (int f = 0; f < 2; ++f)
#pragma unroll
    for (int ct = 0; ct < 8; ++ct) acc[f][ct] = (f32x4){0.f, 0.f, 0.f, 0.f};
#pragma unroll
  for (int kb = 0; kb < KB; ++kb) {
    short8 a0 = *(const short8*)&sm[((wv * 2 + 0) * KB + kb) * 512 + fidx];
    short8 a1 = *(const short8*)&sm[((wv * 2 + 1) * KB + kb) * 512 + fidx];
#pragma unroll
    for (int ct = 0; ct < 8; ++ct) {
      short8 b = *(const short8*)&sm[((8 + ct) * KB + kb) * 512 + fidx];
      acc[0][ct] = __builtin_amdgcn_mfma_f32_16x16x32_bf16(a0, b, acc[0][ct], 0, 0, 0);
      acc[1][ct] = __builtin_amdgcn_mfma_f32_16x16x32_bf16(a1, b, acc[1][ct], 0, 0, 0);
    }
  }
  write_out_bf<1, 0>(acc, bias1, r0, lane, wv, Out1);
  __syncthreads();
#pragma unroll
  for (int it = 0; it < 8; ++it) {
    int idx = it * 256 + tid;
    *(uint4*)&sm[8 * KB * 512 + idx * 8] = *(const uint4*)(Bw2 + idx * 8);
  }
  __syncthreads();
#pragma unroll
  for (int f = 0; f < 2; ++f)
#pragma unroll
    for (int ct = 0; ct < 8; ++ct) acc[f][ct] = (f32x4){0.f, 0.f, 0.f, 0.f};
#pragma unroll
  for (int kb = 0; kb < KB; ++kb) {
    short8 a0 = *(const short8*)&sm[((wv * 2 + 0) * KB + kb) * 512 + fidx];
    short8 a1 = *(const short8*)&sm[((wv * 2 + 1) * KB + kb) * 512 + fidx];
#pragma unroll
    for (int ct = 0; ct < 8; ++ct) {
      short8 b = *(const short8*)&sm[((8 + ct) * KB + kb) * 512 + fidx];
      acc[0][ct] = __builtin_amdgcn_mfma_f32_16x16x32_bf16(a0, b, acc[0][ct], 0, 0, 0);
      acc[1][ct] = __builtin_amdgcn_mfma_f32_16x16x32_bf16(a1, b, acc[1][ct], 0, 0, 0);
    }
  }
  write_scores<4>(acc, a_s, a_d, r0, lane, wv, scs, scd);
  write_out_bf<0, 0>(acc, nullptr, r0, lane, wv, Out2);
}

// ============================ GAT aggregation (+ fused BN stats) ============================
// TWO nodes per wave (32 lanes each). Per node: 2 edge-groups x 16 ch-lanes x 8 bf16 ch,
// 4-edge unroll per group = 8 edges in flight per node. Single-level shfl_xor(16) reduce.
// Stats via padded LDS (idx = c + (c>>3), lane bases stride 9 -> conflict-free) then
// 64-way partial buffers. Block = 4 waves = 8 nodes.
template <int H>
__global__ __launch_bounds__(256) void k_agg(const unsigned short* __restrict__ hp,
                                             const float* __restrict__ scs,
                                             const float* __restrict__ scd,
                                             const int* __restrict__ rowp,
                                             const int* __restrict__ srcl,
                                             const float* __restrict__ bias,
                                             unsigned short* __restrict__ out,
                                             float* __restrict__ part) {
  __shared__ float ssum[8][144], ssq[8][144];
  int tid = threadIdx.x;
  int lane = tid & 63, wv = tid >> 6;
  int half = lane >> 5;            // node within wave
  int l32 = lane & 31;
  int g = l32 >> 4;                // edge group 0/1
  int l16 = lane & 15;             // channel lane
  int n = (blockIdx.x * 4 + wv) * 2 + half;  // grid exact: NN/8 blocks
  int c0 = l16 * 8;                // 8 channels per lane
  int hid = (H == 1) ? 0 : (l16 >> 2);
  float sd = scd[(size_t)n * H + hid];
  int beg = rowp[n], end = rowp[n + 1];
  int last = end - 1;
  float a[8];
#pragma unroll
  for (int i = 0; i < 8; ++i) a[i] = 0.f;
  float sw = 0.f;
  for (int k0 = beg + g * 4; k0 < end; k0 += 8) {
    int k1 = k0 + 1, k2 = k0 + 2, k3 = k0 + 3;
    int s0 = srcl[k0];
    int s1 = srcl[k1 <= last ? k1 : last];
    int s2 = srcl[k2 <= last ? k2 : last];
    int s3 = srcl[k3 <= last ? k3 : last];
    float e0 = scs[(size_t)s0 * H + hid] + sd;
    float e1 = scs[(size_t)s1 * H + hid] + sd;
    float e2 = scs[(size_t)s2 * H + hid] + sd;
    float e3 = scs[(size_t)s3 * H + hid] + sd;
    uint4 u0 = *(const uint4*)(hp + (size_t)s0 * 128 + c0);
    uint4 u1 = *(const uint4*)(hp + (size_t)s1 * 128 + c0);
    uint4 u2 = *(const uint4*)(hp + (size_t)s2 * 128 + c0);
    uint4 u3 = *(const uint4*)(hp + (size_t)s3 * 128 + c0);
    e0 = fmaxf(e0, 0.f) + 0.2f * fminf(e0, 0.f);
    e1 = fmaxf(e1, 0.f) + 0.2f * fminf(e1, 0.f);
    e2 = fmaxf(e2, 0.f) + 0.2f * fminf(e2, 0.f);
    e3 = fmaxf(e3, 0.f) + 0.2f * fminf(e3, 0.f);
    float w0 = __expf(e0);
    float w1 = (k1 <= last) ? __expf(e1) : 0.f;
    float w2 = (k2 <= last) ? __expf(e2) : 0.f;
    float w3 = (k3 <= last) ? __expf(e3) : 0.f;
    a[0] = fmaf(w0, bf2f_lo(u0.x), a[0]); a[1] = fmaf(w0, bf2f_hi(u0.x), a[1]);
    a[2] = fmaf(w0, bf2f_lo(u0.y), a[2]); a[3] = fmaf(w0, bf2f_hi(u0.y), a[3]);
    a[4] = fmaf(w0, bf2f_lo(u0.z), a[4]); a[5] = fmaf(w0, bf2f_hi(u0.z), a[5]);
    a[6] = fmaf(w0, bf2f_lo(u0.w), a[6]); a[7] = fmaf(w0, bf2f_hi(u0.w), a[7]);
    a[0] = fmaf(w1, bf2f_lo(u1.x), a[0]); a[1] = fmaf(w1, bf2f_hi(u1.x), a[1]);
    a[2] = fmaf(w1, bf2f_lo(u1.y), a[2]); a[3] = fmaf(w1, bf2f_hi(u1.y), a[3]);
    a[4] = fmaf(w1, bf2f_lo(u1.z), a[4]); a[5] = fmaf(w1, bf2f_hi(u1.z), a[5]);
    a[6] = fmaf(w1, bf2f_lo(u1.w), a[6]); a[7] = fmaf(w1, bf2f_hi(u1.w), a[7]);
    a[0] = fmaf(w2, bf2f_lo(u2.x), a[0]); a[1] = fmaf(w2, bf2f_hi(u2.x), a[1]);
    a[2] = fmaf(w2, bf2f_lo(u2.y), a[2]); a[3] = fmaf(w2, bf2f_hi(u2.y), a[3]);
    a[4] = fmaf(w2, bf2f_lo(u2.z), a[4]); a[5] = fmaf(w2, bf2f_hi(u2.z), a[5]);
    a[6] = fmaf(w2, bf2f_lo(u2.w), a[6]); a[7] = fmaf(w2, bf2f_hi(u2.w), a[7]);
    a[0] = fmaf(w3, bf2f_lo(u3.x), a[0]); a[1] = fmaf(w3, bf2f_hi(u3.x), a[1]);
    a[2] = fmaf(w3, bf2f_lo(u3.y), a[2]); a[3] = fmaf(w3, bf2f_hi(u3.y), a[3]);
    a[4] = fmaf(w3, bf2f_lo(u3.z), a[4]); a[5] = fmaf(w3, bf2f_hi(u3.z), a[5]);
    a[6] = fmaf(w3, bf2f_lo(u3.w), a[6]); a[7] = fmaf(w3, bf2f_hi(u3.w), a[7]);
    sw += (w0 + w1) + (w2 + w3);
  }
  // single-level cross-group reduce (stays within the 32-lane half)
#pragma unroll
  for (int i = 0; i < 8; ++i) a[i] += __shfl_xor(a[i], 16);
  sw += __shfl_xor(sw, 16);
  int slice = wv * 2 + half;
  if (g == 0) {
    float inv = 1.f / (sw + 1e-16f);
    unsigned wb[4];
    int ib = c0 + l16;  // padded base: c + (c>>3) with c = c0 = 8*l16
#pragma unroll
    for (int j = 0; j < 4; ++j) {
      float o0 = a[2 * j] * inv + bias[c0 + 2 * j];
      float o1 = a[2 * j + 1] * inv + bias[c0 + 2 * j + 1];
      ssum[slice][ib + 2 * j] = o0;
      ssum[slice][ib + 2 * j + 1] = o1;
      ssq[slice][ib + 2 * j] = o0 * o0;
      ssq[slice][ib + 2 * j + 1] = o1 * o1;
      wb[j] = (unsigned)f2bf(o0) | ((unsigned)f2bf(o1) << 16);
    }
    *(uint4*)(out + (size_t)n * 128 + c0) = make_uint4(wb[0], wb[1], wb[2], wb[3]);
  }
  __syncthreads();
  if (tid < 128) {
    int idx = tid + (tid >> 3);
    float s = 0.f, q = 0.f;
#pragma unroll
    for (int sl = 0; sl < 8; ++sl) {
      s += ssum[sl][idx];
      q += ssq[sl][idx];
    }
    int pb = (blockIdx.x & 63) * 256;
    atomicAdd(&part[pb + tid], s);
    atomicAdd(&part[pb + 128 + tid], q);
  }
}

// ============================ launch ============================
extern "C" void kernel_launch(void* const* d_in, const int* in_sizes, int n_in,
                              void* d_out, int out_size, void* d_ws, size_t ws_size,
                              hipStream_t stream) {
  (void)in_sizes; (void)n_in; (void)out_size; (void)ws_size;
  const float* x       = (const float*)d_in[0];
  const int*   ei      = (const int*)d_in[1];
  const float* in_g    = (const float*)d_in[2];
  const float* in_b    = (const float*)d_in[3];
  const float* projW   = (const float*)d_in[4];
  const float* projb   = (const float*)d_in[5];
  const float* skipW   = (const float*)d_in[6];
  const float* skipb   = (const float*)d_in[7];
  const float* c1W     = (const float*)d_in[8];
  const float* c1as    = (const float*)d_in[9];
  const float* c1ad    = (const float*)d_in[10];
  const float* c1b     = (const float*)d_in[11];
  const float* bn1g    = (const float*)d_in[12];
  const float* bn1b    = (const float*)d_in[13];
  const float* c2W     = (const float*)d_in[14];
  const float* c2as    = (const float*)d_in[15];
  const float* c2ad    = (const float*)d_in[16];
  const float* c2b     = (const float*)d_in[17];
  const float* bn2g    = (const float*)d_in[18];
  const float* bn2b    = (const float*)d_in[19];
  const float* c3W     = (const float*)d_in[20];
  const float* c3as    = (const float*)d_in[21];
  const float* c3ad    = (const float*)d_in[22];
  const float* c3b     = (const float*)d_in[23];
  const float* bn3g    = (const float*)d_in[24];
  const float* bn3b    = (const float*)d_in[25];
  const float* clsW1   = (const float*)d_in[26];
  const float* clsb1   = (const float*)d_in[27];
  const float* clsW2   = (const float*)d_in[28];
  const float* clsb2   = (const float*)d_in[29];
  const float* clsW3   = (const float*)d_in[30];
  const float* clsb3   = (const float*)d_in[31];
  const float* confW   = (const float*)d_in[32];
  const float* confb   = (const float*)d_in[33];

  float* out_logits = (float*)d_out;
  float* out_conf   = (float*)d_out + (size_t)NN * 2;

  char* p = (char*)d_ws;
  auto alloc = [&](size_t bytes) -> char* {
    char* r = p;
    p += (bytes + 255) & ~(size_t)255;
    return r;
  };
  unsigned short* hr  = (unsigned short*)alloc((size_t)NN * 128 * 2);  // relu(proj)
  unsigned short* hsk = (unsigned short*)alloc((size_t)NN * 128 * 2);  // h_skip
  unsigned short* hb  = (unsigned short*)alloc((size_t)NN * 128 * 2);  // conv h
  unsigned short* agA = (unsigned short*)alloc((size_t)NN * 128 * 2);  // agg out (L1, L3)
  unsigned short* agB = (unsigned short*)alloc((size_t)NN * 128 * 2);  // agg out (L2)
  float* scs   = (float*)alloc((size_t)NN * 4 * 4);
  float* scd   = (float*)alloc((size_t)NN * 4 * 4);
  // zero region: gpos | stats(x) | part1 | part2 | part3
  char*  zr    = alloc(2048 + 1024 + 3 * 65536);
  int*   gpos  = (int*)zr;
  float* stats = (float*)(zr + 2048);
  float* part1 = stats + 256;
  float* part2 = part1 + 16384;
  float* part3 = part2 + 16384;
  int*   rowp  = (int*)alloc((size_t)(NN + 1) * 4);
  int*   ebase = (int*)alloc((size_t)NBK * 4);
  unsigned* binned = (unsigned*)alloc((size_t)NBK * BCAP * 4);
  int*   srcl  = (int*)alloc((size_t)TOT_E * 4);
  unsigned short* wr = (unsigned short*)alloc(83968 * 2);
  unsigned short* wr_proj = wr;
  unsigned short* wr_skip = wr + 8192;
  unsigned short* wr_c1   = wr + 24576;
  unsigned short* wr_c2   = wr + 40960;
  unsigned short* wr_c3   = wr + 57344;
  unsigned short* wr_cls  = wr + 73728;

  const int GB64  = (NN + 63) / 64;    // 782
  const int GB128 = (NN + 127) / 128;  // 391
  const int AB    = NN / 8;            // 6250 agg blocks (exact, 8 nodes/block)

  k_reorder_all<<<328, 256, 0, stream>>>(projW, skipW, c1W, c2W, c3W, clsW1, confW, wr);
  hipMemsetAsync(zr, 0, 2048 + 1024 + 3 * 65536, stream);

  // ---- CSR build ----
  k_bin<<<256, 512, 0, stream>>>(ei, gpos, binned);
  k_bscan<<<1, 512, 0, stream>>>(gpos, ebase, rowp);
  k_bucket<<<NBK, 256, 0, stream>>>(binned, gpos, ebase, rowp, srcl);

  // ---- input BN stats ----
  k_bn_stats64<<<256, 256, 0, stream>>>(x, stats);

  // ---- proj: hr = relu(bn(x) @ projW + b) ----
  k_mgemm<64, 64, 8, 0, 1, 0, 1, 1, 1, 0><<<GB64, 256, 0, stream>>>(
      x, wr_proj, projb, stats, in_g, in_b, nullptr, nullptr, nullptr, nullptr,
      hr, nullptr, nullptr, nullptr, nullptr, nullptr, nullptr, nullptr, nullptr);

  // ---- dual: hsk = hr@skipW+b ; h1 = hr@c1W (+scores) ----
  k_mgemm_dual<<<GB128, 256, 0, stream>>>(hr, wr_skip, skipb, wr_c1, c1as, c1ad,
                                          hsk, hb, scs, scd);
  k_agg<4><<<AB, 256, 0, stream>>>(hb, scs, scd, rowp, srcl, c1b, agA, part1);

  // ---- GAT layer 2 (bn1+relu fused into A staging) ----
  k_mgemm<64, 128, 8, 1, 2, 1, 0, 0, 1, 4><<<GB64, 256, 0, stream>>>(
      agA, wr_c2, nullptr, part1, bn1g, bn1b, nullptr, c2as, c2ad, nullptr,
      hb, nullptr, scs, scd, nullptr, nullptr, nullptr, nullptr, nullptr);
  k_agg<4><<<AB, 256, 0, stream>>>(hb, scs, scd, rowp, srcl, c2b, agB, part2);

  // ---- GAT layer 3 (H=1; bn2+relu fused) ----
  k_mgemm<64, 128, 8, 1, 2, 1, 0, 0, 1, 1><<<GB64, 256, 0, stream>>>(
      agB, wr_c3, nullptr, part2, bn2g, bn2b, nullptr, c3as, c3ad, nullptr,
      hb, nullptr, scs, scd, nullptr, nullptr, nullptr, nullptr, nullptr);
  k_agg<1><<<AB, 256, 0, stream>>>(hb, scs, scd, rowp, srcl, c3b, agA, part3);

  // ---- classifier: relu(bn3(agA)+hsk) @ [W1|confW] -> C1(LDS) -> c2 -> logits/conf ----
  k_mgemm<128, 128, 5, 1, 3, 1, 1, 0, 2, 0><<<GB128, 256, 0, stream>>>(
      agA, wr_cls, clsb1, part3, bn3g, bn3b, hsk, nullptr, nullptr, confb,
      nullptr, out_conf, nullptr, nullptr, clsW2, clsb2, clsW3, clsb3, out_logits);
}

// Round 10
// 246.524 us; speedup vs baseline: 1.2042x; 1.0161x over previous
//
#include <hip/hip_runtime.h>
#include <cstdint>
#include <cstddef>

#define NN 50000
#define EE 800000
#define TOT_E (NN + EE)
#define NBK 391      // buckets of 128 dst nodes
#define BCAP 2560    // bucket capacity (mean 2048 -> 11 sigma headroom)

typedef __attribute__((ext_vector_type(8))) short short8;
typedef __attribute__((ext_vector_type(4))) float f32x4;

static __device__ __forceinline__ unsigned short f2bf(float f) {
  union { float f; unsigned u; } v;
  v.f = f;
  unsigned r = v.u + 0x7FFFu + ((v.u >> 16) & 1u);  // RNE
  return (unsigned short)(r >> 16);
}
static __device__ __forceinline__ float bf2f(unsigned short u) {
  union { unsigned u; float f; } v;
  v.u = ((unsigned)u) << 16;
  return v.f;
}
static __device__ __forceinline__ float bf2f_lo(unsigned u) {
  union { unsigned u; float f; } v;
  v.u = u << 16;
  return v.f;
}
static __device__ __forceinline__ float bf2f_hi(unsigned u) {
  union { unsigned u; float f; } v;
  v.u = u & 0xFFFF0000u;
  return v.f;
}

// ============================ mega-prep: reorder | x-BN-stats | edge binning ==========
// blocks [0,164): weight reorder (83968 items, 512/block)
// blocks [164,228): input BN stats, 64 blocks each writing its own xpart slot (no atomics)
// blocks [228,484): bin edges by dst>>7 (gpos must be pre-zeroed)
__global__ __launch_bounds__(512) void k_prep(
    const float* __restrict__ projW, const float* __restrict__ skipW,
    const float* __restrict__ c1W, const float* __restrict__ c2W,
    const float* __restrict__ c3W, const float* __restrict__ W1,
    const float* __restrict__ cw, unsigned short* __restrict__ wr,
    const float* __restrict__ x, float* __restrict__ xpart,
    const int* __restrict__ ei, int* __restrict__ gpos,
    unsigned* __restrict__ binned) {
  __shared__ float smf[1024];
  int tx = threadIdx.x;
  int b = blockIdx.x;
  if (b < 164) {
    // ---- weight reorder ----
    int o = b * 512 + tx;
    if (o < 8192) {  // proj: K=64, NT=8
      int off = o;
      int j = off & 7, t = off >> 3;
      int q = t & 3; t >>= 2;
      int c = t & 15; t >>= 4;
      int kb = t & 1, ct = t >> 1;
      int k = kb * 32 + q * 8 + j, col = ct * 16 + c;
      wr[o] = f2bf(projW[(size_t)k * 128 + col]);
    } else if (o < 73728) {  // skip/c1/c2/c3: K=128, NT=8
      int region = (o - 8192) >> 14;
      int off = (o - 8192) & 16383;
      const float* W = region == 0 ? skipW : region == 1 ? c1W : region == 2 ? c2W : c3W;
      int j = off & 7, t = off >> 3;
      int q = t & 3; t >>= 2;
      int c = t & 15; t >>= 4;
      int kb = t & 3, ct = t >> 2;
      int k = kb * 32 + q * 8 + j, col = ct * 16 + c;
      wr[o] = f2bf(W[(size_t)k * 128 + col]);
    } else if (o < 83968) {  // cls: K=128, NT=5
      int off = o - 73728;
      int j = off & 7, t = off >> 3;
      int q = t & 3; t >>= 2;
      int c = t & 15; t >>= 4;
      int kb = t & 3, ct = t >> 2;
      int k = kb * 32 + q * 8 + j, col = ct * 16 + c;
      float v = 0.f;
      if (col < 64) v = W1[(size_t)k * 64 + col];
      else if (col == 64) v = cw[k];
      wr[o] = f2bf(v);
    }
  } else if (b < 228) {
    // ---- input BN stats: block owns xpart slot (b-164), 512 thr = 64 cols x 8 rows ----
    int bi = b - 164;
    int col = tx & 63;
    int rsub = tx >> 6;
    float s = 0.f, q = 0.f;
    for (int r = bi * 8 + rsub; r < NN; r += 64 * 8) {
      float v = x[(size_t)r * 64 + col];
      s += v;
      q += v * v;
    }
    smf[tx] = s;
    smf[512 + tx] = q;
    __syncthreads();
    if (tx < 64) {
#pragma unroll
      for (int i = 1; i < 8; ++i) {
        s += smf[tx + i * 64];
        q += smf[512 + tx + i * 64];
      }
      xpart[bi * 128 + tx] = s;
      xpart[bi * 128 + 64 + tx] = q;
    }
  } else {
    // ---- bin edges ----
    int* cnt = (int*)smf;
    int* base = (int*)smf + 512;
    cnt[tx] = 0;
    __syncthreads();
    int e0 = (b - 228) * 3125;
    int e1 = e0 + 3125;
    if (e1 > EE) e1 = EE;
    for (int i = e0 + tx; i < e1; i += 512) {
      int d = ei[EE + i];
      atomicAdd(&cnt[d >> 7], 1);
    }
    __syncthreads();
    if (tx < NBK) {
      int c = cnt[tx];
      base[tx] = c ? atomicAdd(&gpos[tx], c) : 0;
      cnt[tx] = 0;
    }
    __syncthreads();
    for (int i = e0 + tx; i < e1; i += 512) {
      int s = ei[i];
      int d = ei[EE + i];
      int bk = d >> 7;
      int slot = base[bk] + atomicAdd(&cnt[bk], 1);
      if (slot < BCAP)
        binned[(size_t)bk * BCAP + slot] = (unsigned)s | ((unsigned)(d & 127) << 16);
    }
  }
}

// ============================ bucket: CSR segment build (inline ebase scan) ============
__global__ __launch_bounds__(256) void k_bucket(const unsigned* __restrict__ binned,
                                                const int* __restrict__ gpos,
                                                int* __restrict__ rowp,
                                                int* __restrict__ srcl) {
  __shared__ int cnt[128], offs[128], cur[128];
  __shared__ int red[256], red2[256];
  int b = blockIdx.x, tid = threadIdx.x;
  // ---- inline exclusive scan of bucket sizes -> eb ----
  int accp = 0, acct = 0;
  for (int i = tid; i < NBK; i += 256) {
    int gv = gpos[i];
    if (gv > BCAP) gv = BCAP;
    if (i < b) accp += gv;
    acct += gv;
  }
  red[tid] = accp;
  red2[tid] = acct;
  __syncthreads();
  for (int o = 128; o; o >>= 1) {
    if (tid < o) {
      red[tid] += red[tid + o];
      red2[tid] += red2[tid + o];
    }
    __syncthreads();
  }
  int eb = (b << 7) + red[0];
  if (b == NBK - 1 && tid == 0) rowp[NN] = red2[0] + NN;

  int n0 = b << 7;
  int nodes = NN - n0;
  if (nodes > 128) nodes = 128;
  int ne = gpos[b];
  if (ne > BCAP) ne = BCAP;
  if (tid < 128) cnt[tid] = (tid < nodes) ? 1 : 0;  // 1 = self-loop
  __syncthreads();
  const unsigned* bb = binned + (size_t)b * BCAP;
  for (int i = tid; i < ne; i += 256) atomicAdd(&cnt[bb[i] >> 16], 1);
  __syncthreads();
  if (tid < 128) offs[tid] = cnt[tid];
  __syncthreads();
  for (int o = 1; o < 128; o <<= 1) {
    int t = (tid < 128 && tid >= o) ? offs[tid - o] : 0;
    __syncthreads();
    if (tid < 128) offs[tid] += t;
    __syncthreads();
  }
  if (tid < 128 && tid < nodes) {
    int ex = offs[tid] - cnt[tid];
    rowp[n0 + tid] = eb + ex;
    srcl[eb + ex] = n0 + tid;  // self-loop first (segment order irrelevant)
    cur[tid] = ex + 1;
  }
  __syncthreads();
  for (int i = tid; i < ne; i += 256) {
    unsigned e = bb[i];
    int r = atomicAdd(&cur[e >> 16], 1);
    srcl[eb + r] = (int)(e & 0xFFFFu);
  }
}

// ============================ shared device helpers ============================
template <int NH, int NT, int F>
static __device__ __forceinline__ void write_scores(const f32x4 (&acc)[F][NT],
                                                    const float* __restrict__ a_s,
                                                    const float* __restrict__ a_d,
                                                    int r0, int lane, int wv,
                                                    float* __restrict__ scs,
                                                    float* __restrict__ scd) {
  const int lr = lane & 15, lg = lane >> 4;
  float asv[NT], adv[NT];
#pragma unroll
  for (int ct = 0; ct < NT; ++ct) {
    asv[ct] = a_s[ct * 16 + lr];
    adv[ct] = a_d[ct * 16 + lr];
  }
  float ps[F][4][NH], pd[F][4][NH];
#pragma unroll
  for (int f = 0; f < F; ++f)
#pragma unroll
    for (int r = 0; r < 4; ++r)
#pragma unroll
      for (int h = 0; h < NH; ++h) { ps[f][r][h] = 0.f; pd[f][r][h] = 0.f; }
#pragma unroll
  for (int f = 0; f < F; ++f)
#pragma unroll
    for (int ct = 0; ct < NT; ++ct) {
      int h = (NH == 1) ? 0 : (ct >> 1);
#pragma unroll
      for (int r = 0; r < 4; ++r) {
        ps[f][r][h] = fmaf(acc[f][ct][r], asv[ct], ps[f][r][h]);
        pd[f][r][h] = fmaf(acc[f][ct][r], adv[ct], pd[f][r][h]);
      }
    }
#pragma unroll
  for (int off = 1; off < 16; off <<= 1)
#pragma unroll
    for (int f = 0; f < F; ++f)
#pragma unroll
      for (int r = 0; r < 4; ++r)
#pragma unroll
        for (int h = 0; h < NH; ++h) {
          ps[f][r][h] += __shfl_xor(ps[f][r][h], off);
          pd[f][r][h] += __shfl_xor(pd[f][r][h], off);
        }
  if (lr == 0) {
#pragma unroll
    for (int f = 0; f < F; ++f) {
      int rowb = r0 + (wv * F + f) * 16 + lg * 4;
#pragma unroll
      for (int r = 0; r < 4; ++r) {
        int gr = rowb + r;
        if (gr < NN) {
          if (NH == 4) {
            float4 vs = make_float4(ps[f][r][0], ps[f][r][1], ps[f][r][2], ps[f][r][3]);
            float4 vd = make_float4(pd[f][r][0], pd[f][r][1], pd[f][r][2], pd[f][r][3]);
            *(float4*)(scs + (size_t)gr * 4) = vs;
            *(float4*)(scd + (size_t)gr * 4) = vd;
          } else {
            scs[gr] = ps[f][r][0];
            scd[gr] = pd[f][r][0];
          }
        }
      }
    }
  }
}

template <int BIAS, int RELU, int NT, int F>
static __device__ __forceinline__ void write_out_bf(const f32x4 (&acc)[F][NT],
                                                    const float* __restrict__ bias,
                                                    int r0, int lane, int wv,
                                                    unsigned short* __restrict__ out) {
  const int lr = lane & 15, lg = lane >> 4;
#pragma unroll
  for (int f = 0; f < F; ++f) {
    int rowb = r0 + (wv * F + f) * 16 + lg * 4;
#pragma unroll
    for (int ct = 0; ct < NT; ++ct) {
      int col = ct * 16 + lr;
      float bb = BIAS ? bias[col] : 0.f;
#pragma unroll
      for (int r = 0; r < 4; ++r) {
        int gr = rowb + r;
        if (gr < NN) {
          float o = acc[f][ct][r] + bb;
          if (RELU) o = fmaxf(o, 0.f);
          out[(size_t)gr * 128 + col] = f2bf(o);
        }
      }
    }
  }
}

// ============================ MFMA GEMM ============================
// BM rows per block (64/128). BN: 0 none, 1 sc/sh, 2 +relu, 3 +skip+relu.
// BNP: 0 single sums buffer; 1 = 32 agg partials (stride 256); 2 = 64 xpart (stride 128).
// OUTM: 1 bf16 out; 2 classifier tail (BM must be 128). SCH: 0 off, 1/4 GAT scores.
template <int BM, int K, int NT, int ABF, int BN, int BNP, int BIAS, int RELU, int OUTM, int SCH>
__global__ __launch_bounds__(256) void k_mgemm(
    const void* __restrict__ Ain, const unsigned short* __restrict__ Bw,
    const float* __restrict__ bias,
    const float* __restrict__ bnsums, const float* __restrict__ bng,
    const float* __restrict__ bnb,
    const unsigned short* __restrict__ skip,
    const float* __restrict__ a_s, const float* __restrict__ a_d,
    const float* __restrict__ confb,
    void* __restrict__ Cout, float* __restrict__ conf,
    float* __restrict__ scs, float* __restrict__ scd,
    const float* __restrict__ W2, const float* __restrict__ b2,
    const float* __restrict__ W3, const float* __restrict__ b3,
    float* __restrict__ logits) {
  constexpr int KB = K / 32;
  constexpr int RT = BM / 16;       // row tiles
  constexpr int F = BM / 64;        // row tiles per wave
  __shared__ __align__(16) unsigned short sm[(RT + NT) * KB * 512];
  __shared__ float bnsc[128], bnsh[128];
  const int tid = threadIdx.x;
  const int r0 = blockIdx.x * BM;

  if constexpr (BN) {
    if (tid < K) {
      float s, q;
      if constexpr (BNP == 1) {
        s = 0.f; q = 0.f;
#pragma unroll 8
        for (int pp = 0; pp < 32; ++pp) {
          s += bnsums[pp * 256 + tid];
          q += bnsums[pp * 256 + 128 + tid];
        }
      } else if constexpr (BNP == 2) {
        s = 0.f; q = 0.f;
#pragma unroll 8
        for (int pp = 0; pp < 64; ++pp) {
          s += bnsums[pp * 128 + tid];
          q += bnsums[pp * 128 + 64 + tid];
        }
      } else {
        s = bnsums[tid];
        q = bnsums[K + tid];
      }
      float invM = 1.f / (float)NN;
      float mu = s * invM;
      float var = q * invM - mu * mu;
      float sc = bng[tid] * rsqrtf(var + 1e-5f);
      bnsc[tid] = sc;
      bnsh[tid] = bnb[tid] - mu * sc;
    }
    __syncthreads();
  }

  // ---- stage A ----
  if constexpr (ABF) {
    const unsigned short* A = (const unsigned short*)Ain;
    constexpr int IT = BM * (K / 8) / 256;
#pragma unroll
    for (int it = 0; it < IT; ++it) {
      int idx = it * 256 + tid;
      int r = idx / (K / 8);
      int k = (idx % (K / 8)) * 8;
      int gr = r0 + r;
      union { uint4 u4; unsigned short us[8]; } v;
      v.u4 = make_uint4(0, 0, 0, 0);
      if (gr < NN) v.u4 = *(const uint4*)(A + (size_t)gr * K + k);
      if constexpr (BN) {
        union { uint4 u4; unsigned short us[8]; } sv;
        if (BN == 3) {
          sv.u4 = make_uint4(0, 0, 0, 0);
          if (gr < NN) sv.u4 = *(const uint4*)(skip + (size_t)gr * 128 + k);
        }
#pragma unroll
        for (int j = 0; j < 8; ++j) {
          float f = bf2f(v.us[j]) * bnsc[k + j] + bnsh[k + j];
          if (BN == 3) f += bf2f(sv.us[j]);
          if (BN >= 2) f = fmaxf(f, 0.f);
          v.us[j] = f2bf(f);
        }
      }
      *(uint4*)&sm[((r >> 4) * KB + (k >> 5)) * 512 + (r & 15) * 32 + (k & 31)] = v.u4;
    }
  } else {
    const float* A = (const float*)Ain;
    constexpr int IT = BM * (K / 4) / 256;
#pragma unroll
    for (int it = 0; it < IT; ++it) {
      int idx = it * 256 + tid;
      int r = idx / (K / 4);
      int k = (idx % (K / 4)) * 4;
      int gr = r0 + r;
      float4 av = make_float4(0.f, 0.f, 0.f, 0.f);
      if (gr < NN) av = *(const float4*)(A + (size_t)gr * K + k);
      if constexpr (BN) {
        av.x = av.x * bnsc[k + 0] + bnsh[k + 0];
        av.y = av.y * bnsc[k + 1] + bnsh[k + 1];
        av.z = av.z * bnsc[k + 2] + bnsh[k + 2];
        av.w = av.w * bnsc[k + 3] + bnsh[k + 3];
        if (BN >= 2) {
          av.x = fmaxf(av.x, 0.f); av.y = fmaxf(av.y, 0.f);
          av.z = fmaxf(av.z, 0.f); av.w = fmaxf(av.w, 0.f);
        }
      }
      ushort4 o;
      o.x = f2bf(av.x); o.y = f2bf(av.y); o.z = f2bf(av.z); o.w = f2bf(av.w);
      *(ushort4*)&sm[((r >> 4) * KB + (k >> 5)) * 512 + (r & 15) * 32 + (k & 31)] = o;
    }
  }
  // ---- stage B ----
  {
    constexpr int BW = NT * KB * 512;
#pragma unroll
    for (int it = 0; it < BW / 2048; ++it) {
      int idx = it * 256 + tid;
      *(uint4*)&sm[RT * KB * 512 + idx * 8] = *(const uint4*)(Bw + idx * 8);
    }
  }
  __syncthreads();

  // ---- MFMA ----
  const int lane = tid & 63, wv = tid >> 6;
  const int lr = lane & 15, lg = lane >> 4;
  const int fidx = lr * 32 + lg * 8;
  f32x4 acc[F][NT];
#pragma unroll
  for (int f = 0; f < F; ++f)
#pragma unroll
    for (int ct = 0; ct < NT; ++ct) acc[f][ct] = (f32x4){0.f, 0.f, 0.f, 0.f};
#pragma unroll
  for (int kb = 0; kb < KB; ++kb) {
    short8 afr[F];
#pragma unroll
    for (int f = 0; f < F; ++f)
      afr[f] = *(const short8*)&sm[((wv * F + f) * KB + kb) * 512 + fidx];
#pragma unroll
    for (int ct = 0; ct < NT; ++ct) {
      short8 b = *(const short8*)&sm[((RT + ct) * KB + kb) * 512 + fidx];
#pragma unroll
      for (int f = 0; f < F; ++f)
        acc[f][ct] = __builtin_amdgcn_mfma_f32_16x16x32_bf16(afr[f], b, acc[f][ct], 0, 0, 0);
    }
  }

  if constexpr (SCH > 0) {
    write_scores<(SCH == 1) ? 1 : 4>(acc, a_s, a_d, r0, lane, wv, scs, scd);
  }

  if constexpr (OUTM == 2) {
    // -------- classifier tail in-kernel (reuse sm; BM must be 128) --------
    __syncthreads();
    unsigned short* c1s = sm;                 // [128][65] bf16
    float* W2s = (float*)(sm + 8320);         // 64*32
    float* c2s = (float*)(sm + 12416);        // [128][33]
    float* W3s = (float*)(sm + 20864);        // 64
    float* b2s = (float*)(sm + 20992);        // 32
    float* b3s = (float*)(sm + 21056);        // 2
    for (int i = tid; i < 2048; i += 256) W2s[i] = W2[i];
    if (tid < 64) W3s[tid] = W3[tid];
    if (tid < 32) b2s[tid] = b2[tid];
    if (tid < 2) b3s[tid] = b3[tid];
#pragma unroll
    for (int f = 0; f < F; ++f) {
      int lrow = (wv * F + f) * 16 + lg * 4;
#pragma unroll
      for (int ct = 0; ct < NT; ++ct) {
        int col = ct * 16 + lr;
        if (col < 64) {
          float bb = bias[col];
#pragma unroll
          for (int r = 0; r < 4; ++r)
            c1s[(lrow + r) * 65 + col] = f2bf(fmaxf(acc[f][ct][r] + bb, 0.f));
        } else if (col == 64) {
          float cb = confb[0];
#pragma unroll
          for (int r = 0; r < 4; ++r) {
            int gr = r0 + lrow + r;
            if (gr < NN) conf[gr] = 1.f / (1.f + __expf(-(acc[f][ct][r] + cb)));
          }
        }
      }
    }
    __syncthreads();
    {
      int node = tid & 127;
      int cb = (tid >> 7) * 16;
      float a2[16];
#pragma unroll
      for (int i = 0; i < 16; ++i) a2[i] = b2s[cb + i];
      for (int k = 0; k < 64; ++k) {
        float v = bf2f(c1s[node * 65 + k]);
#pragma unroll
        for (int i = 0; i < 16; ++i) a2[i] = fmaf(v, W2s[k * 32 + cb + i], a2[i]);
      }
#pragma unroll
      for (int i = 0; i < 16; ++i) c2s[node * 33 + cb + i] = fmaxf(a2[i], 0.f);
    }
    __syncthreads();
    {
      int node = tid >> 1, j = tid & 1;
      float s3 = b3s[j];
#pragma unroll 8
      for (int k = 0; k < 32; ++k) s3 = fmaf(c2s[node * 33 + k], W3s[k * 2 + j], s3);
      int gr = r0 + node;
      if (gr < NN) logits[(size_t)gr * 2 + j] = s3;
    }
  } else {
    write_out_bf<BIAS, RELU>(acc, bias, r0, lane, wv, (unsigned short*)Cout);
  }
}

// ============================ dual-B MFMA GEMM (skip + conv1) ============================
__global__ __launch_bounds__(256) void k_mgemm_dual(
    const unsigned short* __restrict__ A, const unsigned short* __restrict__ Bw1,
    const float* __restrict__ bias1, const unsigned short* __restrict__ Bw2,
    const float* __restrict__ a_s, const float* __restrict__ a_d,
    unsigned short* __restrict__ Out1, unsigned short* __restrict__ Out2,
    float* __restrict__ scs, float* __restrict__ scd) {
  constexpr int KB = 4;  // K=128
  __shared__ __align__(16) unsigned short sm[16 * KB * 512];
  const int tid = threadIdx.x;
  const int r0 = blockIdx.x * 128;
#pragma unroll
  for (int it = 0; it < 8; ++it) {
    int idx = it * 256 + tid;
    int r = idx >> 4;
    int k = (idx & 15) * 8;
    int gr = r0 + r;
    uint4 v = make_uint4(0, 0, 0, 0);
    if (gr < NN) v = *(const uint4*)(A + (size_t)gr * 128 + k);
    *(uint4*)&sm[((r >> 4) * KB + (k >> 5)) * 512 + (r & 15) * 32 + (k & 31)] = v;
  }
#pragma unroll
  for (int it = 0; it < 8; ++it) {
    int idx = it * 256 + tid;
    *(uint4*)&sm[8 * KB * 512 + idx * 8] = *(const uint4*)(Bw1 + idx * 8);
  }
  __syncthreads();
  const int lane = tid & 63, wv = tid >> 6;
  const int lr = lane & 15, lg = lane >> 4;
  const int fidx = lr * 32 + lg * 8;
  f32x4 acc[2][8];
#pragma unroll
  for (int f = 0; f < 2; ++f)
#pragma unroll
    for (int ct = 0; ct < 8; ++ct) acc[f][ct] = (f32x4){0.f, 0.f, 0.f, 0.f};
#pragma unroll
  for (int kb = 0; kb < KB; ++kb) {
    short8 a0 = *(const short8*)&sm[((wv * 2 + 0) * KB + kb) * 512 + fidx];
    short8 a1 = *(const short8*)&sm[((wv * 2 + 1) * KB + kb) * 512 + fidx];
#pragma unroll
    for (int ct = 0; ct < 8; ++ct) {
      short8 b = *(const short8*)&sm[((8 + ct) * KB + kb) * 512 + fidx];
      acc[0][ct] = __builtin_amdgcn_mfma_f32_16x16x32_bf16(a0, b, acc[0][ct], 0, 0, 0);
      acc[1][ct] = __builtin_amdgcn_mfma_f32_16x16x32_bf16(a1, b, acc[1][ct], 0, 0, 0);
    }
  }
  write_out_bf<1, 0>(acc, bias1, r0, lane, wv, Out1);
  __syncthreads();
#pragma unroll
  for (int it = 0; it < 8; ++it) {
    int idx = it * 256 + tid;
    *(uint4*)&sm[8 * KB * 512 + idx * 8] = *(const uint4*)(Bw2 + idx * 8);
  }
  __syncthreads();
#pragma unroll
  for (int f = 0; f < 2; ++f)
#pragma unroll
    for (int ct = 0; ct < 8; ++ct) acc[f][ct] = (f32x4){0.f, 0.f, 0.f, 0.f};
#pragma unroll
  for (int kb = 0; kb < KB; ++kb) {
    short8 a0 = *(const short8*)&sm[((wv * 2 + 0) * KB + kb) * 512 + fidx];
    short8 a1 = *(const short8*)&sm[((wv * 2 + 1) * KB + kb) * 512 + fidx];
#pragma unroll
    for (int ct = 0; ct < 8; ++ct) {
      short8 b = *(const short8*)&sm[((8 + ct) * KB + kb) * 512 + fidx];
      acc[0][ct] = __builtin_amdgcn_mfma_f32_16x16x32_bf16(a0, b, acc[0][ct], 0, 0, 0);
      acc[1][ct] = __builtin_amdgcn_mfma_f32_16x16x32_bf16(a1, b, acc[1][ct], 0, 0, 0);
    }
  }
  write_scores<4>(acc, a_s, a_d, r0, lane, wv, scs, scd);
  write_out_bf<0, 0>(acc, nullptr, r0, lane, wv, Out2);
}

// ============================ GAT aggregation (+ fused BN stats) ============================
// TWO nodes per wave (32 lanes each). Per node: 2 edge-groups x 16 ch-lanes x 8 bf16 ch,
// 4-edge unroll per group, srcl prefetched one iteration ahead. Single shfl_xor(16) reduce.
// Stats via padded LDS then 32 partial buffers.
template <int H>
__global__ __launch_bounds__(256) void k_agg(const unsigned short* __restrict__ hp,
                                             const float* __restrict__ scs,
                                             const float* __restrict__ scd,
                                             const int* __restrict__ rowp,
                                             const int* __restrict__ srcl,
                                             const float* __restrict__ bias,
                                             unsigned short* __restrict__ out,
                                             float* __restrict__ part) {
  __shared__ float ssum[8][144], ssq[8][144];
  int tid = threadIdx.x;
  int lane = tid & 63, wv = tid >> 6;
  int half = lane >> 5;            // node within wave
  int l32 = lane & 31;
  int g = l32 >> 4;                // edge group 0/1
  int l16 = lane & 15;             // channel lane
  int n = (blockIdx.x * 4 + wv) * 2 + half;  // grid exact: NN/8 blocks
  int c0 = l16 * 8;                // 8 channels per lane
  int hid = (H == 1) ? 0 : (l16 >> 2);
  float sd = scd[(size_t)n * H + hid];
  int beg = rowp[n], end = rowp[n + 1];
  int last = end - 1;
  float a[8];
#pragma unroll
  for (int i = 0; i < 8; ++i) a[i] = 0.f;
  float sw = 0.f;
  int k0 = beg + g * 4;
  // prefetched current-quad source indices (clamped reads are always in-range)
  int s0 = srcl[(k0 + 0) <= last ? (k0 + 0) : last];
  int s1 = srcl[(k0 + 1) <= last ? (k0 + 1) : last];
  int s2 = srcl[(k0 + 2) <= last ? (k0 + 2) : last];
  int s3 = srcl[(k0 + 3) <= last ? (k0 + 3) : last];
  for (; k0 < end; k0 += 8) {
    int np = k0 + 8;
    int t0 = srcl[(np + 0) <= last ? (np + 0) : last];
    int t1 = srcl[(np + 1) <= last ? (np + 1) : last];
    int t2 = srcl[(np + 2) <= last ? (np + 2) : last];
    int t3 = srcl[(np + 3) <= last ? (np + 3) : last];
    float e0 = scs[(size_t)s0 * H + hid] + sd;
    float e1 = scs[(size_t)s1 * H + hid] + sd;
    float e2 = scs[(size_t)s2 * H + hid] + sd;
    float e3 = scs[(size_t)s3 * H + hid] + sd;
    uint4 u0 = *(const uint4*)(hp + (size_t)s0 * 128 + c0);
    uint4 u1 = *(const uint4*)(hp + (size_t)s1 * 128 + c0);
    uint4 u2 = *(const uint4*)(hp + (size_t)s2 * 128 + c0);
    uint4 u3 = *(const uint4*)(hp + (size_t)s3 * 128 + c0);
    e0 = fmaxf(e0, 0.f) + 0.2f * fminf(e0, 0.f);
    e1 = fmaxf(e1, 0.f) + 0.2f * fminf(e1, 0.f);
    e2 = fmaxf(e2, 0.f) + 0.2f * fminf(e2, 0.f);
    e3 = fmaxf(e3, 0.f) + 0.2f * fminf(e3, 0.f);
    float w0 = __expf(e0);
    float w1 = (k0 + 1 <= last) ? __expf(e1) : 0.f;
    float w2 = (k0 + 2 <= last) ? __expf(e2) : 0.f;
    float w3 = (k0 + 3 <= last) ? __expf(e3) : 0.f;
    a[0] = fmaf(w0, bf2f_lo(u0.x), a[0]); a[1] = fmaf(w0, bf2f_hi(u0.x), a[1]);
    a[2] = fmaf(w0, bf2f_lo(u0.y), a[2]); a[3] = fmaf(w0, bf2f_hi(u0.y), a[3]);
    a[4] = fmaf(w0, bf2f_lo(u0.z), a[4]); a[5] = fmaf(w0, bf2f_hi(u0.z), a[5]);
    a[6] = fmaf(w0, bf2f_lo(u0.w), a[6]); a[7] = fmaf(w0, bf2f_hi(u0.w), a[7]);
    a[0] = fmaf(w1, bf2f_lo(u1.x), a[0]); a[1] = fmaf(w1, bf2f_hi(u1.x), a[1]);
    a[2] = fmaf(w1, bf2f_lo(u1.y), a[2]); a[3] = fmaf(w1, bf2f_hi(u1.y), a[3]);
    a[4] = fmaf(w1, bf2f_lo(u1.z), a[4]); a[5] = fmaf(w1, bf2f_hi(u1.z), a[5]);
    a[6] = fmaf(w1, bf2f_lo(u1.w), a[6]); a[7] = fmaf(w1, bf2f_hi(u1.w), a[7]);
    a[0] = fmaf(w2, bf2f_lo(u2.x), a[0]); a[1] = fmaf(w2, bf2f_hi(u2.x), a[1]);
    a[2] = fmaf(w2, bf2f_lo(u2.y), a[2]); a[3] = fmaf(w2, bf2f_hi(u2.y), a[3]);
    a[4] = fmaf(w2, bf2f_lo(u2.z), a[4]); a[5] = fmaf(w2, bf2f_hi(u2.z), a[5]);
    a[6] = fmaf(w2, bf2f_lo(u2.w), a[6]); a[7] = fmaf(w2, bf2f_hi(u2.w), a[7]);
    a[0] = fmaf(w3, bf2f_lo(u3.x), a[0]); a[1] = fmaf(w3, bf2f_hi(u3.x), a[1]);
    a[2] = fmaf(w3, bf2f_lo(u3.y), a[2]); a[3] = fmaf(w3, bf2f_hi(u3.y), a[3]);
    a[4] = fmaf(w3, bf2f_lo(u3.z), a[4]); a[5] = fmaf(w3, bf2f_hi(u3.z), a[5]);
    a[6] = fmaf(w3, bf2f_lo(u3.w), a[6]); a[7] = fmaf(w3, bf2f_hi(u3.w), a[7]);
    sw += (w0 + w1) + (w2 + w3);
    s0 = t0; s1 = t1; s2 = t2; s3 = t3;
  }
  // single-level cross-group reduce (stays within the 32-lane half)
#pragma unroll
  for (int i = 0; i < 8; ++i) a[i] += __shfl_xor(a[i], 16);
  sw += __shfl_xor(sw, 16);
  int slice = wv * 2 + half;
  if (g == 0) {
    float inv = 1.f / (sw + 1e-16f);
    unsigned wb[4];
    int ib = c0 + l16;  // padded base: c + (c>>3) with c = c0 = 8*l16
#pragma unroll
    for (int j = 0; j < 4; ++j) {
      float o0 = a[2 * j] * inv + bias[c0 + 2 * j];
      float o1 = a[2 * j + 1] * inv + bias[c0 + 2 * j + 1];
      ssum[slice][ib + 2 * j] = o0;
      ssum[slice][ib + 2 * j + 1] = o1;
      ssq[slice][ib + 2 * j] = o0 * o0;
      ssq[slice][ib + 2 * j + 1] = o1 * o1;
      wb[j] = (unsigned)f2bf(o0) | ((unsigned)f2bf(o1) << 16);
    }
    *(uint4*)(out + (size_t)n * 128 + c0) = make_uint4(wb[0], wb[1], wb[2], wb[3]);
  }
  __syncthreads();
  if (tid < 128) {
    int idx = tid + (tid >> 3);
    float s = 0.f, q = 0.f;
#pragma unroll
    for (int sl = 0; sl < 8; ++sl) {
      s += ssum[sl][idx];
      q += ssq[sl][idx];
    }
    int pb = (blockIdx.x & 31) * 256;
    atomicAdd(&part[pb + tid], s);
    atomicAdd(&part[pb + 128 + tid], q);
  }
}

// ============================ launch ============================
extern "C" void kernel_launch(void* const* d_in, const int* in_sizes, int n_in,
                              void* d_out, int out_size, void* d_ws, size_t ws_size,
                              hipStream_t stream) {
  (void)in_sizes; (void)n_in; (void)out_size; (void)ws_size;
  const float* x       = (const float*)d_in[0];
  const int*   ei      = (const int*)d_in[1];
  const float* in_g    = (const float*)d_in[2];
  const float* in_b    = (const float*)d_in[3];
  const float* projW   = (const float*)d_in[4];
  const float* projb   = (const float*)d_in[5];
  const float* skipW   = (const float*)d_in[6];
  const float* skipb   = (const float*)d_in[7];
  const float* c1W     = (const float*)d_in[8];
  const float* c1as    = (const float*)d_in[9];
  const float* c1ad    = (const float*)d_in[10];
  const float* c1b     = (const float*)d_in[11];
  const float* bn1g    = (const float*)d_in[12];
  const float* bn1b    = (const float*)d_in[13];
  const float* c2W     = (const float*)d_in[14];
  const float* c2as    = (const float*)d_in[15];
  const float* c2ad    = (const float*)d_in[16];
  const float* c2b     = (const float*)d_in[17];
  const float* bn2g    = (const float*)d_in[18];
  const float* bn2b    = (const float*)d_in[19];
  const float* c3W     = (const float*)d_in[20];
  const float* c3as    = (const float*)d_in[21];
  const float* c3ad    = (const float*)d_in[22];
  const float* c3b     = (const float*)d_in[23];
  const float* bn3g    = (const float*)d_in[24];
  const float* bn3b    = (const float*)d_in[25];
  const float* clsW1   = (const float*)d_in[26];
  const float* clsb1   = (const float*)d_in[27];
  const float* clsW2   = (const float*)d_in[28];
  const float* clsb2   = (const float*)d_in[29];
  const float* clsW3   = (const float*)d_in[30];
  const float* clsb3   = (const float*)d_in[31];
  const float* confW   = (const float*)d_in[32];
  const float* confb   = (const float*)d_in[33];

  float* out_logits = (float*)d_out;
  float* out_conf   = (float*)d_out + (size_t)NN * 2;

  char* p = (char*)d_ws;
  auto alloc = [&](size_t bytes) -> char* {
    char* r = p;
    p += (bytes + 255) & ~(size_t)255;
    return r;
  };
  unsigned short* hr  = (unsigned short*)alloc((size_t)NN * 128 * 2);  // relu(proj)
  unsigned short* hsk = (unsigned short*)alloc((size_t)NN * 128 * 2);  // h_skip
  unsigned short* hb  = (unsigned short*)alloc((size_t)NN * 128 * 2);  // conv h
  unsigned short* agA = (unsigned short*)alloc((size_t)NN * 128 * 2);  // agg out (L1, L3)
  unsigned short* agB = (unsigned short*)alloc((size_t)NN * 128 * 2);  // agg out (L2)
  float* scs   = (float*)alloc((size_t)NN * 4 * 4);
  float* scd   = (float*)alloc((size_t)NN * 4 * 4);
  // zero region: gpos | part1 | part2 | part3 (32 slots x 256 floats each)
  char*  zr    = alloc(2048 + 3 * 32768);
  int*   gpos  = (int*)zr;
  float* part1 = (float*)(zr + 2048);
  float* part2 = part1 + 8192;
  float* part3 = part2 + 8192;
  float* xpart = (float*)alloc(64 * 128 * 4);  // input BN partials (no zeroing needed)
  int*   rowp  = (int*)alloc((size_t)(NN + 1) * 4);
  unsigned* binned = (unsigned*)alloc((size_t)NBK * BCAP * 4);
  int*   srcl  = (int*)alloc((size_t)TOT_E * 4);
  unsigned short* wr = (unsigned short*)alloc(83968 * 2);
  unsigned short* wr_proj = wr;
  unsigned short* wr_skip = wr + 8192;
  unsigned short* wr_c1   = wr + 24576;
  unsigned short* wr_c2   = wr + 40960;
  unsigned short* wr_c3   = wr + 57344;
  unsigned short* wr_cls  = wr + 73728;

  const int GB64  = (NN + 63) / 64;    // 782
  const int GB128 = (NN + 127) / 128;  // 391
  const int AB    = NN / 8;            // 6250 agg blocks (exact, 8 nodes/block)

  hipMemsetAsync(zr, 0, 2048 + 3 * 32768, stream);

  // ---- mega-prep: reorder | x-stats | bin ----
  k_prep<<<484, 512, 0, stream>>>(projW, skipW, c1W, c2W, c3W, clsW1, confW, wr,
                                  x, xpart, ei, gpos, binned);
  // ---- CSR segments ----
  k_bucket<<<NBK, 256, 0, stream>>>(binned, gpos, rowp, srcl);

  // ---- proj: hr = relu(bn(x) @ projW + b) ----
  k_mgemm<64, 64, 8, 0, 1, 2, 1, 1, 1, 0><<<GB64, 256, 0, stream>>>(
      x, wr_proj, projb, xpart, in_g, in_b, nullptr, nullptr, nullptr, nullptr,
      hr, nullptr, nullptr, nullptr, nullptr, nullptr, nullptr, nullptr, nullptr);

  // ---- dual: hsk = hr@skipW+b ; h1 = hr@c1W (+scores) ----
  k_mgemm_dual<<<GB128, 256, 0, stream>>>(hr, wr_skip, skipb, wr_c1, c1as, c1ad,
                                          hsk, hb, scs, scd);
  k_agg<4><<<AB, 256, 0, stream>>>(hb, scs, scd, rowp, srcl, c1b, agA, part1);

  // ---- GAT layer 2 (bn1+relu fused into A staging) ----
  k_mgemm<64, 128, 8, 1, 2, 1, 0, 0, 1, 4><<<GB64, 256, 0, stream>>>(
      agA, wr_c2, nullptr, part1, bn1g, bn1b, nullptr, c2as, c2ad, nullptr,
      hb, nullptr, scs, scd, nullptr, nullptr, nullptr, nullptr, nullptr);
  k_agg<4><<<AB, 256, 0, stream>>>(hb, scs, scd, rowp, srcl, c2b, agB, part2);

  // ---- GAT layer 3 (H=1; bn2+relu fused) ----
  k_mgemm<64, 128, 8, 1, 2, 1, 0, 0, 1, 1><<<GB64, 256, 0, stream>>>(
      agB, wr_c3, nullptr, part2, bn2g, bn2b, nullptr, c3as, c3ad, nullptr,
      hb, nullptr, scs, scd, nullptr, nullptr, nullptr, nullptr, nullptr);
  k_agg<1><<<AB, 256, 0, stream>>>(hb, scs, scd, rowp, srcl, c3b, agA, part3);

  // ---- classifier: relu(bn3(agA)+hsk) @ [W1|confW] -> C1(LDS) -> c2 -> logits/conf ----
  k_mgemm<128, 128, 5, 1, 3, 1, 1, 0, 2, 0><<<GB128, 256, 0, stream>>>(
      agA, wr_cls, clsb1, part3, bn3g, bn3b, hsk, nullptr, nullptr, confb,
      nullptr, out_conf, nullptr, nullptr, clsW2, clsb2, clsW3, clsb3, out_logits);
}

// Round 11
// 231.216 us; speedup vs baseline: 1.2839x; 1.0662x over previous
//
#include <hip/hip_runtime.h>
#include <cstdint>
#include <cstddef>

#define NN 50000
#define EE 800000
#define TOT_E (NN + EE)
#define NBK 391      // buckets of 128 dst nodes
#define BCAP 2560    // bucket capacity (mean 2048 -> 11 sigma headroom)

typedef __attribute__((ext_vector_type(8))) short short8;
typedef __attribute__((ext_vector_type(4))) float f32x4;

static __device__ __forceinline__ unsigned short f2bf(float f) {
  union { float f; unsigned u; } v;
  v.f = f;
  unsigned r = v.u + 0x7FFFu + ((v.u >> 16) & 1u);  // RNE
  return (unsigned short)(r >> 16);
}
static __device__ __forceinline__ float bf2f(unsigned short u) {
  union { unsigned u; float f; } v;
  v.u = ((unsigned)u) << 16;
  return v.f;
}
static __device__ __forceinline__ float bf2f_lo(unsigned u) {
  union { unsigned u; float f; } v;
  v.u = u << 16;
  return v.f;
}
static __device__ __forceinline__ float bf2f_hi(unsigned u) {
  union { unsigned u; float f; } v;
  v.u = u & 0xFFFF0000u;
  return v.f;
}

// ============================ mega-prep: reorder | x-BN-stats | edge binning ==========
// blocks [0,164): weight reorder (83968 items, 512/block)
// blocks [164,292): input BN stats, 128 blocks, float4 loads, private xpart slots
// blocks [292,548): bin edges by dst>>7 (gpos must be pre-zeroed)
__global__ __launch_bounds__(512) void k_prep(
    const float* __restrict__ projW, const float* __restrict__ skipW,
    const float* __restrict__ c1W, const float* __restrict__ c2W,
    const float* __restrict__ c3W, const float* __restrict__ W1,
    const float* __restrict__ cw, unsigned short* __restrict__ wr,
    const float* __restrict__ x, float* __restrict__ xpart,
    const int* __restrict__ ei, int* __restrict__ gpos,
    unsigned* __restrict__ binned) {
  __shared__ float smf[1024];
  int tx = threadIdx.x;
  int b = blockIdx.x;
  if (b < 164) {
    // ---- weight reorder ----
    int o = b * 512 + tx;
    if (o < 8192) {  // proj: K=64, NT=8
      int off = o;
      int j = off & 7, t = off >> 3;
      int q = t & 3; t >>= 2;
      int c = t & 15; t >>= 4;
      int kb = t & 1, ct = t >> 1;
      int k = kb * 32 + q * 8 + j, col = ct * 16 + c;
      wr[o] = f2bf(projW[(size_t)k * 128 + col]);
    } else if (o < 73728) {  // skip/c1/c2/c3: K=128, NT=8
      int region = (o - 8192) >> 14;
      int off = (o - 8192) & 16383;
      const float* W = region == 0 ? skipW : region == 1 ? c1W : region == 2 ? c2W : c3W;
      int j = off & 7, t = off >> 3;
      int q = t & 3; t >>= 2;
      int c = t & 15; t >>= 4;
      int kb = t & 3, ct = t >> 2;
      int k = kb * 32 + q * 8 + j, col = ct * 16 + c;
      wr[o] = f2bf(W[(size_t)k * 128 + col]);
    } else if (o < 83968) {  // cls: K=128, NT=5
      int off = o - 73728;
      int j = off & 7, t = off >> 3;
      int q = t & 3; t >>= 2;
      int c = t & 15; t >>= 4;
      int kb = t & 3, ct = t >> 2;
      int k = kb * 32 + q * 8 + j, col = ct * 16 + c;
      float v = 0.f;
      if (col < 64) v = W1[(size_t)k * 64 + col];
      else if (col == 64) v = cw[k];
      wr[o] = f2bf(v);
    }
  } else if (b < 292) {
    // ---- input BN stats: 128 blocks, float4 loads, shfl reduce, private slot ----
    int bi = b - 164;
    int lane = tx & 63, wv = tx >> 6;
    int cg = lane & 15;              // col group (4 cols)
    int rsub = wv * 4 + (lane >> 4); // 0..31
    int col4 = cg * 4;
    float s[4] = {0.f, 0.f, 0.f, 0.f}, q[4] = {0.f, 0.f, 0.f, 0.f};
    for (int r = bi * 32 + rsub; r < NN; r += 128 * 32) {
      float4 v = *(const float4*)(x + (size_t)r * 64 + col4);
      s[0] += v.x; q[0] += v.x * v.x;
      s[1] += v.y; q[1] += v.y * v.y;
      s[2] += v.z; q[2] += v.z * v.z;
      s[3] += v.w; q[3] += v.w * v.w;
    }
#pragma unroll
    for (int j = 0; j < 4; ++j) {
      s[j] += __shfl_xor(s[j], 16); s[j] += __shfl_xor(s[j], 32);
      q[j] += __shfl_xor(q[j], 16); q[j] += __shfl_xor(q[j], 32);
    }
    if (lane < 16) {
#pragma unroll
      for (int j = 0; j < 4; ++j) {
        smf[wv * 128 + col4 + j] = s[j];
        smf[wv * 128 + 64 + col4 + j] = q[j];
      }
    }
    __syncthreads();
    if (tx < 64) {
      float ss = 0.f, qq = 0.f;
#pragma unroll
      for (int w = 0; w < 8; ++w) {
        ss += smf[w * 128 + tx];
        qq += smf[w * 128 + 64 + tx];
      }
      xpart[bi * 128 + tx] = ss;
      xpart[bi * 128 + 64 + tx] = qq;
    }
  } else {
    // ---- bin edges ----
    int* cnt = (int*)smf;
    int* base = (int*)smf + 512;
    cnt[tx] = 0;
    __syncthreads();
    int e0 = (b - 292) * 3125;
    int e1 = e0 + 3125;
    if (e1 > EE) e1 = EE;
    for (int i = e0 + tx; i < e1; i += 512) {
      int d = ei[EE + i];
      atomicAdd(&cnt[d >> 7], 1);
    }
    __syncthreads();
    if (tx < NBK) {
      int c = cnt[tx];
      base[tx] = c ? atomicAdd(&gpos[tx], c) : 0;
      cnt[tx] = 0;
    }
    __syncthreads();
    for (int i = e0 + tx; i < e1; i += 512) {
      int s = ei[i];
      int d = ei[EE + i];
      int bk = d >> 7;
      int slot = base[bk] + atomicAdd(&cnt[bk], 1);
      if (slot < BCAP)
        binned[(size_t)bk * BCAP + slot] = (unsigned)s | ((unsigned)(d & 127) << 16);
    }
  }
}

// ============================ bucket: CSR segment build (inline ebase scan) ============
__global__ __launch_bounds__(256) void k_bucket(const unsigned* __restrict__ binned,
                                                const int* __restrict__ gpos,
                                                int* __restrict__ rowp,
                                                int* __restrict__ srcl) {
  __shared__ int cnt[128], offs[128], cur[128];
  __shared__ int red[256], red2[256];
  int b = blockIdx.x, tid = threadIdx.x;
  int accp = 0, acct = 0;
  for (int i = tid; i < NBK; i += 256) {
    int gv = gpos[i];
    if (gv > BCAP) gv = BCAP;
    if (i < b) accp += gv;
    acct += gv;
  }
  red[tid] = accp;
  red2[tid] = acct;
  __syncthreads();
  for (int o = 128; o; o >>= 1) {
    if (tid < o) {
      red[tid] += red[tid + o];
      red2[tid] += red2[tid + o];
    }
    __syncthreads();
  }
  int eb = (b << 7) + red[0];
  if (b == NBK - 1 && tid == 0) rowp[NN] = red2[0] + NN;

  int n0 = b << 7;
  int nodes = NN - n0;
  if (nodes > 128) nodes = 128;
  int ne = gpos[b];
  if (ne > BCAP) ne = BCAP;
  if (tid < 128) cnt[tid] = (tid < nodes) ? 1 : 0;  // 1 = self-loop
  __syncthreads();
  const unsigned* bb = binned + (size_t)b * BCAP;
  for (int i = tid; i < ne; i += 256) atomicAdd(&cnt[bb[i] >> 16], 1);
  __syncthreads();
  if (tid < 128) offs[tid] = cnt[tid];
  __syncthreads();
  for (int o = 1; o < 128; o <<= 1) {
    int t = (tid < 128 && tid >= o) ? offs[tid - o] : 0;
    __syncthreads();
    if (tid < 128) offs[tid] += t;
    __syncthreads();
  }
  if (tid < 128 && tid < nodes) {
    int ex = offs[tid] - cnt[tid];
    rowp[n0 + tid] = eb + ex;
    srcl[eb + ex] = n0 + tid;  // self-loop first
    cur[tid] = ex + 1;
  }
  __syncthreads();
  for (int i = tid; i < ne; i += 256) {
    unsigned e = bb[i];
    int r = atomicAdd(&cur[e >> 16], 1);
    srcl[eb + r] = (int)(e & 0xFFFFu);
  }
}

// ============================ shared device helpers ============================
template <int NH, int NT, int F>
static __device__ __forceinline__ void write_scores(const f32x4 (&acc)[F][NT],
                                                    const float* __restrict__ a_s,
                                                    const float* __restrict__ a_d,
                                                    int r0, int lane, int wv,
                                                    float* __restrict__ scs,
                                                    float* __restrict__ scd) {
  const int lr = lane & 15, lg = lane >> 4;
  float asv[NT], adv[NT];
#pragma unroll
  for (int ct = 0; ct < NT; ++ct) {
    asv[ct] = a_s[ct * 16 + lr];
    adv[ct] = a_d[ct * 16 + lr];
  }
  float ps[F][4][NH], pd[F][4][NH];
#pragma unroll
  for (int f = 0; f < F; ++f)
#pragma unroll
    for (int r = 0; r < 4; ++r)
#pragma unroll
      for (int h = 0; h < NH; ++h) { ps[f][r][h] = 0.f; pd[f][r][h] = 0.f; }
#pragma unroll
  for (int f = 0; f < F; ++f)
#pragma unroll
    for (int ct = 0; ct < NT; ++ct) {
      int h = (NH == 1) ? 0 : (ct >> 1);
#pragma unroll
      for (int r = 0; r < 4; ++r) {
        ps[f][r][h] = fmaf(acc[f][ct][r], asv[ct], ps[f][r][h]);
        pd[f][r][h] = fmaf(acc[f][ct][r], adv[ct], pd[f][r][h]);
      }
    }
#pragma unroll
  for (int off = 1; off < 16; off <<= 1)
#pragma unroll
    for (int f = 0; f < F; ++f)
#pragma unroll
      for (int r = 0; r < 4; ++r)
#pragma unroll
        for (int h = 0; h < NH; ++h) {
          ps[f][r][h] += __shfl_xor(ps[f][r][h], off);
          pd[f][r][h] += __shfl_xor(pd[f][r][h], off);
        }
  if (lr == 0) {
#pragma unroll
    for (int f = 0; f < F; ++f) {
      int rowb = r0 + (wv * F + f) * 16 + lg * 4;
#pragma unroll
      for (int r = 0; r < 4; ++r) {
        int gr = rowb + r;
        if (gr < NN) {
          if (NH == 4) {
            float4 vs = make_float4(ps[f][r][0], ps[f][r][1], ps[f][r][2], ps[f][r][3]);
            float4 vd = make_float4(pd[f][r][0], pd[f][r][1], pd[f][r][2], pd[f][r][3]);
            *(float4*)(scs + (size_t)gr * 4) = vs;
            *(float4*)(scd + (size_t)gr * 4) = vd;
          } else {
            scs[gr] = ps[f][r][0];
            scd[gr] = pd[f][r][0];
          }
        }
      }
    }
  }
}

template <int BIAS, int RELU, int NT, int F>
static __device__ __forceinline__ void write_out_bf(const f32x4 (&acc)[F][NT],
                                                    const float* __restrict__ bias,
                                                    int r0, int lane, int wv,
                                                    unsigned short* __restrict__ out) {
  const int lr = lane & 15, lg = lane >> 4;
#pragma unroll
  for (int f = 0; f < F; ++f) {
    int rowb = r0 + (wv * F + f) * 16 + lg * 4;
#pragma unroll
    for (int ct = 0; ct < NT; ++ct) {
      int col = ct * 16 + lr;
      float bb = BIAS ? bias[col] : 0.f;
#pragma unroll
      for (int r = 0; r < 4; ++r) {
        int gr = rowb + r;
        if (gr < NN) {
          float o = acc[f][ct][r] + bb;
          if (RELU) o = fmaxf(o, 0.f);
          out[(size_t)gr * 128 + col] = f2bf(o);
        }
      }
    }
  }
}

// ============================ MFMA GEMM ============================
// BM rows per block (64/128). BN: 0 none, 1 sc/sh, 2 +relu, 3 +skip+relu.
// BNP: 0 single sums buffer; 1 = 32 agg partials (stride 256); 2 = 128 xpart (stride 128).
// OUTM: 1 bf16 out; 2 classifier tail (BM must be 128). SCH: 0 off, 1/4 GAT scores.
template <int BM, int K, int NT, int ABF, int BN, int BNP, int BIAS, int RELU, int OUTM, int SCH>
__global__ __launch_bounds__(256) void k_mgemm(
    const void* __restrict__ Ain, const unsigned short* __restrict__ Bw,
    const float* __restrict__ bias,
    const float* __restrict__ bnsums, const float* __restrict__ bng,
    const float* __restrict__ bnb,
    const unsigned short* __restrict__ skip,
    const float* __restrict__ a_s, const float* __restrict__ a_d,
    const float* __restrict__ confb,
    void* __restrict__ Cout, float* __restrict__ conf,
    float* __restrict__ scs, float* __restrict__ scd,
    const float* __restrict__ W2, const float* __restrict__ b2,
    const float* __restrict__ W3, const float* __restrict__ b3,
    float* __restrict__ logits) {
  constexpr int KB = K / 32;
  constexpr int RT = BM / 16;       // row tiles
  constexpr int F = BM / 64;        // row tiles per wave
  __shared__ __align__(16) unsigned short sm[(RT + NT) * KB * 512];
  __shared__ float bnsc[128], bnsh[128];
  const int tid = threadIdx.x;
  const int r0 = blockIdx.x * BM;

  if constexpr (BN) {
    if (tid < K) {
      float s, q;
      if constexpr (BNP == 1) {
        s = 0.f; q = 0.f;
#pragma unroll 8
        for (int pp = 0; pp < 32; ++pp) {
          s += bnsums[pp * 256 + tid];
          q += bnsums[pp * 256 + 128 + tid];
        }
      } else if constexpr (BNP == 2) {
        s = 0.f; q = 0.f;
#pragma unroll 8
        for (int pp = 0; pp < 128; ++pp) {
          s += bnsums[pp * 128 + tid];
          q += bnsums[pp * 128 + 64 + tid];
        }
      } else {
        s = bnsums[tid];
        q = bnsums[K + tid];
      }
      float invM = 1.f / (float)NN;
      float mu = s * invM;
      float var = q * invM - mu * mu;
      float sc = bng[tid] * rsqrtf(var + 1e-5f);
      bnsc[tid] = sc;
      bnsh[tid] = bnb[tid] - mu * sc;
    }
    __syncthreads();
  }

  // ---- stage A ----
  if constexpr (ABF) {
    const unsigned short* A = (const unsigned short*)Ain;
    constexpr int IT = BM * (K / 8) / 256;
#pragma unroll
    for (int it = 0; it < IT; ++it) {
      int idx = it * 256 + tid;
      int r = idx / (K / 8);
      int k = (idx % (K / 8)) * 8;
      int gr = r0 + r;
      union { uint4 u4; unsigned short us[8]; } v;
      v.u4 = make_uint4(0, 0, 0, 0);
      if (gr < NN) v.u4 = *(const uint4*)(A + (size_t)gr * K + k);
      if constexpr (BN) {
        union { uint4 u4; unsigned short us[8]; } sv;
        if (BN == 3) {
          sv.u4 = make_uint4(0, 0, 0, 0);
          if (gr < NN) sv.u4 = *(const uint4*)(skip + (size_t)gr * 128 + k);
        }
#pragma unroll
        for (int j = 0; j < 8; ++j) {
          float f = bf2f(v.us[j]) * bnsc[k + j] + bnsh[k + j];
          if (BN == 3) f += bf2f(sv.us[j]);
          if (BN >= 2) f = fmaxf(f, 0.f);
          v.us[j] = f2bf(f);
        }
      }
      *(uint4*)&sm[((r >> 4) * KB + (k >> 5)) * 512 + (r & 15) * 32 + (k & 31)] = v.u4;
    }
  } else {
    const float* A = (const float*)Ain;
    constexpr int IT = BM * (K / 4) / 256;
#pragma unroll
    for (int it = 0; it < IT; ++it) {
      int idx = it * 256 + tid;
      int r = idx / (K / 4);
      int k = (idx % (K / 4)) * 4;
      int gr = r0 + r;
      float4 av = make_float4(0.f, 0.f, 0.f, 0.f);
      if (gr < NN) av = *(const float4*)(A + (size_t)gr * K + k);
      if constexpr (BN) {
        av.x = av.x * bnsc[k + 0] + bnsh[k + 0];
        av.y = av.y * bnsc[k + 1] + bnsh[k + 1];
        av.z = av.z * bnsc[k + 2] + bnsh[k + 2];
        av.w = av.w * bnsc[k + 3] + bnsh[k + 3];
        if (BN >= 2) {
          av.x = fmaxf(av.x, 0.f); av.y = fmaxf(av.y, 0.f);
          av.z = fmaxf(av.z, 0.f); av.w = fmaxf(av.w, 0.f);
        }
      }
      ushort4 o;
      o.x = f2bf(av.x); o.y = f2bf(av.y); o.z = f2bf(av.z); o.w = f2bf(av.w);
      *(ushort4*)&sm[((r >> 4) * KB + (k >> 5)) * 512 + (r & 15) * 32 + (k & 31)] = o;
    }
  }
  // ---- stage B ----
  {
    constexpr int BW = NT * KB * 512;
#pragma unroll
    for (int it = 0; it < BW / 2048; ++it) {
      int idx = it * 256 + tid;
      *(uint4*)&sm[RT * KB * 512 + idx * 8] = *(const uint4*)(Bw + idx * 8);
    }
  }
  __syncthreads();

  // ---- MFMA ----
  const int lane = tid & 63, wv = tid >> 6;
  const int lr = lane & 15, lg = lane >> 4;
  const int fidx = lr * 32 + lg * 8;
  f32x4 acc[F][NT];
#pragma unroll
  for (int f = 0; f < F; ++f)
#pragma unroll
    for (int ct = 0; ct < NT; ++ct) acc[f][ct] = (f32x4){0.f, 0.f, 0.f, 0.f};
#pragma unroll
  for (int kb = 0; kb < KB; ++kb) {
    short8 afr[F];
#pragma unroll
    for (int f = 0; f < F; ++f)
      afr[f] = *(const short8*)&sm[((wv * F + f) * KB + kb) * 512 + fidx];
#pragma unroll
    for (int ct = 0; ct < NT; ++ct) {
      short8 b = *(const short8*)&sm[((RT + ct) * KB + kb) * 512 + fidx];
#pragma unroll
      for (int f = 0; f < F; ++f)
        acc[f][ct] = __builtin_amdgcn_mfma_f32_16x16x32_bf16(afr[f], b, acc[f][ct], 0, 0, 0);
    }
  }

  if constexpr (SCH > 0) {
    write_scores<(SCH == 1) ? 1 : 4>(acc, a_s, a_d, r0, lane, wv, scs, scd);
  }

  if constexpr (OUTM == 2) {
    // -------- classifier tail in-kernel (reuse sm; BM must be 128) --------
    __syncthreads();
    unsigned short* c1s = sm;                 // [128][65] bf16
    float* W2s = (float*)(sm + 8320);         // 64*32
    float* c2s = (float*)(sm + 12416);        // [128][33]
    float* W3s = (float*)(sm + 20864);        // 64
    float* b2s = (float*)(sm + 20992);        // 32
    float* b3s = (float*)(sm + 21056);        // 2
    for (int i = tid; i < 2048; i += 256) W2s[i] = W2[i];
    if (tid < 64) W3s[tid] = W3[tid];
    if (tid < 32) b2s[tid] = b2[tid];
    if (tid < 2) b3s[tid] = b3[tid];
#pragma unroll
    for (int f = 0; f < F; ++f) {
      int lrow = (wv * F + f) * 16 + lg * 4;
#pragma unroll
      for (int ct = 0; ct < NT; ++ct) {
        int col = ct * 16 + lr;
        if (col < 64) {
          float bb = bias[col];
#pragma unroll
          for (int r = 0; r < 4; ++r)
            c1s[(lrow + r) * 65 + col] = f2bf(fmaxf(acc[f][ct][r] + bb, 0.f));
        } else if (col == 64) {
          float cb = confb[0];
#pragma unroll
          for (int r = 0; r < 4; ++r) {
            int gr = r0 + lrow + r;
            if (gr < NN) conf[gr] = 1.f / (1.f + __expf(-(acc[f][ct][r] + cb)));
          }
        }
      }
    }
    __syncthreads();
    {
      int node = tid & 127;
      int cb = (tid >> 7) * 16;
      float a2[16];
#pragma unroll
      for (int i = 0; i < 16; ++i) a2[i] = b2s[cb + i];
      for (int k = 0; k < 64; ++k) {
        float v = bf2f(c1s[node * 65 + k]);
#pragma unroll
        for (int i = 0; i < 16; ++i) a2[i] = fmaf(v, W2s[k * 32 + cb + i], a2[i]);
      }
#pragma unroll
      for (int i = 0; i < 16; ++i) c2s[node * 33 + cb + i] = fmaxf(a2[i], 0.f);
    }
    __syncthreads();
    {
      int node = tid >> 1, j = tid & 1;
      float s3 = b3s[j];
#pragma unroll 8
      for (int k = 0; k < 32; ++k) s3 = fmaf(c2s[node * 33 + k], W3s[k * 2 + j], s3);
      int gr = r0 + node;
      if (gr < NN) logits[(size_t)gr * 2 + j] = s3;
    }
  } else {
    write_out_bf<BIAS, RELU>(acc, bias, r0, lane, wv, (unsigned short*)Cout);
  }
}

// ============================ dual-B MFMA GEMM (skip + conv1) ============================
__global__ __launch_bounds__(256) void k_mgemm_dual(
    const unsigned short* __restrict__ A, const unsigned short* __restrict__ Bw1,
    const float* __restrict__ bias1, const unsigned short* __restrict__ Bw2,
    const float* __restrict__ a_s, const float* __restrict__ a_d,
    unsigned short* __restrict__ Out1, unsigned short* __restrict__ Out2,
    float* __restrict__ scs, float* __restrict__ scd) {
  constexpr int KB = 4;  // K=128
  __shared__ __align__(16) unsigned short sm[16 * KB * 512];
  const int tid = threadIdx.x;
  const int r0 = blockIdx.x * 128;
#pragma unroll
  for (int it = 0; it < 8; ++it) {
    int idx = it * 256 + tid;
    int r = idx >> 4;
    int k = (idx & 15) * 8;
    int gr = r0 + r;
    uint4 v = make_uint4(0, 0, 0, 0);
    if (gr < NN) v = *(const uint4*)(A + (size_t)gr * 128 + k);
    *(uint4*)&sm[((r >> 4) * KB + (k >> 5)) * 512 + (r & 15) * 32 + (k & 31)] = v;
  }
#pragma unroll
  for (int it = 0; it < 8; ++it) {
    int idx = it * 256 + tid;
    *(uint4*)&sm[8 * KB * 512 + idx * 8] = *(const uint4*)(Bw1 + idx * 8);
  }
  __syncthreads();
  const int lane = tid & 63, wv = tid >> 6;
  const int lr = lane & 15, lg = lane >> 4;
  const int fidx = lr * 32 + lg * 8;
  f32x4 acc[2][8];
#pragma unroll
  for (int f = 0; f < 2; ++f)
#pragma unroll
    for (int ct = 0; ct < 8; ++ct) acc[f][ct] = (f32x4){0.f, 0.f, 0.f, 0.f};
#pragma unroll
  for (int kb = 0; kb < KB; ++kb) {
    short8 a0 = *(const short8*)&sm[((wv * 2 + 0) * KB + kb) * 512 + fidx];
    short8 a1 = *(const short8*)&sm[((wv * 2 + 1) * KB + kb) * 512 + fidx];
#pragma unroll
    for (int ct = 0; ct < 8; ++ct) {
      short8 b = *(const short8*)&sm[((8 + ct) * KB + kb) * 512 + fidx];
      acc[0][ct] = __builtin_amdgcn_mfma_f32_16x16x32_bf16(a0, b, acc[0][ct], 0, 0, 0);
      acc[1][ct] = __builtin_amdgcn_mfma_f32_16x16x32_bf16(a1, b, acc[1][ct], 0, 0, 0);
    }
  }
  write_out_bf<1, 0>(acc, bias1, r0, lane, wv, Out1);
  __syncthreads();
#pragma unroll
  for (int it = 0; it < 8; ++it) {
    int idx = it * 256 + tid;
    *(uint4*)&sm[8 * KB * 512 + idx * 8] = *(const uint4*)(Bw2 + idx * 8);
  }
  __syncthreads();
#pragma unroll
  for (int f = 0; f < 2; ++f)
#pragma unroll
    for (int ct = 0; ct < 8; ++ct) acc[f][ct] = (f32x4){0.f, 0.f, 0.f, 0.f};
#pragma unroll
  for (int kb = 0; kb < KB; ++kb) {
    short8 a0 = *(const short8*)&sm[((wv * 2 + 0) * KB + kb) * 512 + fidx];
    short8 a1 = *(const short8*)&sm[((wv * 2 + 1) * KB + kb) * 512 + fidx];
#pragma unroll
    for (int ct = 0; ct < 8; ++ct) {
      short8 b = *(const short8*)&sm[((8 + ct) * KB + kb) * 512 + fidx];
      acc[0][ct] = __builtin_amdgcn_mfma_f32_16x16x32_bf16(a0, b, acc[0][ct], 0, 0, 0);
      acc[1][ct] = __builtin_amdgcn_mfma_f32_16x16x32_bf16(a1, b, acc[1][ct], 0, 0, 0);
    }
  }
  write_scores<4>(acc, a_s, a_d, r0, lane, wv, scs, scd);
  write_out_bf<0, 0>(acc, nullptr, r0, lane, wv, Out2);
}

// ============================ GAT aggregation (+ fused BN stats) ============================
// TWO nodes per wave (32 lanes each). Per node: 2 edge-groups x 16 ch-lanes x 8 bf16 ch,
// 4-edge unroll per group, srcl prefetched one iteration ahead. Single shfl_xor(16) reduce.
// Stats via padded LDS then 32 partial buffers.
template <int H>
__global__ __launch_bounds__(256) void k_agg(const unsigned short* __restrict__ hp,
                                             const float* __restrict__ scs,
                                             const float* __restrict__ scd,
                                             const int* __restrict__ rowp,
                                             const int* __restrict__ srcl,
                                             const float* __restrict__ bias,
                                             unsigned short* __restrict__ out,
                                             float* __restrict__ part) {
  __shared__ float ssum[8][144], ssq[8][144];
  int tid = threadIdx.x;
  int lane = tid & 63, wv = tid >> 6;
  int half = lane >> 5;            // node within wave
  int l32 = lane & 31;
  int g = l32 >> 4;                // edge group 0/1
  int l16 = lane & 15;             // channel lane
  int n = (blockIdx.x * 4 + wv) * 2 + half;  // grid exact: NN/8 blocks
  int c0 = l16 * 8;                // 8 channels per lane
  int hid = (H == 1) ? 0 : (l16 >> 2);
  float sd = scd[(size_t)n * H + hid];
  int beg = rowp[n], end = rowp[n + 1];
  int last = end - 1;
  float a[8];
#pragma unroll
  for (int i = 0; i < 8; ++i) a[i] = 0.f;
  float sw = 0.f;
  int k0 = beg + g * 4;
  int s0 = srcl[(k0 + 0) <= last ? (k0 + 0) : last];
  int s1 = srcl[(k0 + 1) <= last ? (k0 + 1) : last];
  int s2 = srcl[(k0 + 2) <= last ? (k0 + 2) : last];
  int s3 = srcl[(k0 + 3) <= last ? (k0 + 3) : last];
  for (; k0 < end; k0 += 8) {
    int np = k0 + 8;
    int t0 = srcl[(np + 0) <= last ? (np + 0) : last];
    int t1 = srcl[(np + 1) <= last ? (np + 1) : last];
    int t2 = srcl[(np + 2) <= last ? (np + 2) : last];
    int t3 = srcl[(np + 3) <= last ? (np + 3) : last];
    float e0 = scs[(size_t)s0 * H + hid] + sd;
    float e1 = scs[(size_t)s1 * H + hid] + sd;
    float e2 = scs[(size_t)s2 * H + hid] + sd;
    float e3 = scs[(size_t)s3 * H + hid] + sd;
    uint4 u0 = *(const uint4*)(hp + (size_t)s0 * 128 + c0);
    uint4 u1 = *(const uint4*)(hp + (size_t)s1 * 128 + c0);
    uint4 u2 = *(const uint4*)(hp + (size_t)s2 * 128 + c0);
    uint4 u3 = *(const uint4*)(hp + (size_t)s3 * 128 + c0);
    e0 = fmaxf(e0, 0.f) + 0.2f * fminf(e0, 0.f);
    e1 = fmaxf(e1, 0.f) + 0.2f * fminf(e1, 0.f);
    e2 = fmaxf(e2, 0.f) + 0.2f * fminf(e2, 0.f);
    e3 = fmaxf(e3, 0.f) + 0.2f * fminf(e3, 0.f);
    float w0 = __expf(e0);
    float w1 = (k0 + 1 <= last) ? __expf(e1) : 0.f;
    float w2 = (k0 + 2 <= last) ? __expf(e2) : 0.f;
    float w3 = (k0 + 3 <= last) ? __expf(e3) : 0.f;
    a[0] = fmaf(w0, bf2f_lo(u0.x), a[0]); a[1] = fmaf(w0, bf2f_hi(u0.x), a[1]);
    a[2] = fmaf(w0, bf2f_lo(u0.y), a[2]); a[3] = fmaf(w0, bf2f_hi(u0.y), a[3]);
    a[4] = fmaf(w0, bf2f_lo(u0.z), a[4]); a[5] = fmaf(w0, bf2f_hi(u0.z), a[5]);
    a[6] = fmaf(w0, bf2f_lo(u0.w), a[6]); a[7] = fmaf(w0, bf2f_hi(u0.w), a[7]);
    a[0] = fmaf(w1, bf2f_lo(u1.x), a[0]); a[1] = fmaf(w1, bf2f_hi(u1.x), a[1]);
    a[2] = fmaf(w1, bf2f_lo(u1.y), a[2]); a[3] = fmaf(w1, bf2f_hi(u1.y), a[3]);
    a[4] = fmaf(w1, bf2f_lo(u1.z), a[4]); a[5] = fmaf(w1, bf2f_hi(u1.z), a[5]);
    a[6] = fmaf(w1, bf2f_lo(u1.w), a[6]); a[7] = fmaf(w1, bf2f_hi(u1.w), a[7]);
    a[0] = fmaf(w2, bf2f_lo(u2.x), a[0]); a[1] = fmaf(w2, bf2f_hi(u2.x), a[1]);
    a[2] = fmaf(w2, bf2f_lo(u2.y), a[2]); a[3] = fmaf(w2, bf2f_hi(u2.y), a[3]);
    a[4] = fmaf(w2, bf2f_lo(u2.z), a[4]); a[5] = fmaf(w2, bf2f_hi(u2.z), a[5]);
    a[6] = fmaf(w2, bf2f_lo(u2.w), a[6]); a[7] = fmaf(w2, bf2f_hi(u2.w), a[7]);
    a[0] = fmaf(w3, bf2f_lo(u3.x), a[0]); a[1] = fmaf(w3, bf2f_hi(u3.x), a[1]);
    a[2] = fmaf(w3, bf2f_lo(u3.y), a[2]); a[3] = fmaf(w3, bf2f_hi(u3.y), a[3]);
    a[4] = fmaf(w3, bf2f_lo(u3.z), a[4]); a[5] = fmaf(w3, bf2f_hi(u3.z), a[5]);
    a[6] = fmaf(w3, bf2f_lo(u3.w), a[6]); a[7] = fmaf(w3, bf2f_hi(u3.w), a[7]);
    sw += (w0 + w1) + (w2 + w3);
    s0 = t0; s1 = t1; s2 = t2; s3 = t3;
  }
#pragma unroll
  for (int i = 0; i < 8; ++i) a[i] += __shfl_xor(a[i], 16);
  sw += __shfl_xor(sw, 16);
  int slice = wv * 2 + half;
  if (g == 0) {
    float inv = 1.f / (sw + 1e-16f);
    unsigned wb[4];
    int ib = c0 + l16;  // padded: c + (c>>3)
#pragma unroll
    for (int j = 0; j < 4; ++j) {
      float o0 = a[2 * j] * inv + bias[c0 + 2 * j];
      float o1 = a[2 * j + 1] * inv + bias[c0 + 2 * j + 1];
      ssum[slice][ib + 2 * j] = o0;
      ssum[slice][ib + 2 * j + 1] = o1;
      ssq[slice][ib + 2 * j] = o0 * o0;
      ssq[slice][ib + 2 * j + 1] = o1 * o1;
      wb[j] = (unsigned)f2bf(o0) | ((unsigned)f2bf(o1) << 16);
    }
    *(uint4*)(out + (size_t)n * 128 + c0) = make_uint4(wb[0], wb[1], wb[2], wb[3]);
  }
  __syncthreads();
  if (tid < 128) {
    int idx = tid + (tid >> 3);
    float s = 0.f, q = 0.f;
#pragma unroll
    for (int sl = 0; sl < 8; ++sl) {
      s += ssum[sl][idx];
      q += ssq[sl][idx];
    }
    int pb = (blockIdx.x & 31) * 256;
    atomicAdd(&part[pb + tid], s);
    atomicAdd(&part[pb + 128 + tid], q);
  }
}

// ============================ launch ============================
extern "C" void kernel_launch(void* const* d_in, const int* in_sizes, int n_in,
                              void* d_out, int out_size, void* d_ws, size_t ws_size,
                              hipStream_t stream) {
  (void)in_sizes; (void)n_in; (void)out_size; (void)ws_size;
  const float* x       = (const float*)d_in[0];
  const int*   ei      = (const int*)d_in[1];
  const float* in_g    = (const float*)d_in[2];
  const float* in_b    = (const float*)d_in[3];
  const float* projW   = (const float*)d_in[4];
  const float* projb   = (const float*)d_in[5];
  const float* skipW   = (const float*)d_in[6];
  const float* skipb   = (const float*)d_in[7];
  const float* c1W     = (const float*)d_in[8];
  const float* c1as    = (const float*)d_in[9];
  const float* c1ad    = (const float*)d_in[10];
  const float* c1b     = (const float*)d_in[11];
  const float* bn1g    = (const float*)d_in[12];
  const float* bn1b    = (const float*)d_in[13];
  const float* c2W     = (const float*)d_in[14];
  const float* c2as    = (const float*)d_in[15];
  const float* c2ad    = (const float*)d_in[16];
  const float* c2b     = (const float*)d_in[17];
  const float* bn2g    = (const float*)d_in[18];
  const float* bn2b    = (const float*)d_in[19];
  const float* c3W     = (const float*)d_in[20];
  const float* c3as    = (const float*)d_in[21];
  const float* c3ad    = (const float*)d_in[22];
  const float* c3b     = (const float*)d_in[23];
  const float* bn3g    = (const float*)d_in[24];
  const float* bn3b    = (const float*)d_in[25];
  const float* clsW1   = (const float*)d_in[26];
  const float* clsb1   = (const float*)d_in[27];
  const float* clsW2   = (const float*)d_in[28];
  const float* clsb2   = (const float*)d_in[29];
  const float* clsW3   = (const float*)d_in[30];
  const float* clsb3   = (const float*)d_in[31];
  const float* confW   = (const float*)d_in[32];
  const float* confb   = (const float*)d_in[33];

  float* out_logits = (float*)d_out;
  float* out_conf   = (float*)d_out + (size_t)NN * 2;

  char* p = (char*)d_ws;
  auto alloc = [&](size_t bytes) -> char* {
    char* r = p;
    p += (bytes + 255) & ~(size_t)255;
    return r;
  };
  unsigned short* hr  = (unsigned short*)alloc((size_t)NN * 128 * 2);  // relu(proj)
  unsigned short* hsk = (unsigned short*)alloc((size_t)NN * 128 * 2);  // h_skip
  unsigned short* hb  = (unsigned short*)alloc((size_t)NN * 128 * 2);  // conv h
  unsigned short* agA = (unsigned short*)alloc((size_t)NN * 128 * 2);  // agg out (L1, L3)
  unsigned short* agB = (unsigned short*)alloc((size_t)NN * 128 * 2);  // agg out (L2)
  float* scs   = (float*)alloc((size_t)NN * 4 * 4);
  float* scd   = (float*)alloc((size_t)NN * 4 * 4);
  // zero region: gpos | part1 | part2 | part3 (32 slots x 256 floats each)
  char*  zr    = alloc(2048 + 3 * 32768);
  int*   gpos  = (int*)zr;
  float* part1 = (float*)(zr + 2048);
  float* part2 = part1 + 8192;
  float* part3 = part2 + 8192;
  float* xpart = (float*)alloc(128 * 128 * 4);  // input BN partials (no zeroing needed)
  int*   rowp  = (int*)alloc((size_t)(NN + 1) * 4);
  unsigned* binned = (unsigned*)alloc((size_t)NBK * BCAP * 4);
  int*   srcl  = (int*)alloc((size_t)TOT_E * 4);
  unsigned short* wr = (unsigned short*)alloc(83968 * 2);
  unsigned short* wr_proj = wr;
  unsigned short* wr_skip = wr + 8192;
  unsigned short* wr_c1   = wr + 24576;
  unsigned short* wr_c2   = wr + 40960;
  unsigned short* wr_c3   = wr + 57344;
  unsigned short* wr_cls  = wr + 73728;

  const int GB64  = (NN + 63) / 64;    // 782
  const int GB128 = (NN + 127) / 128;  // 391
  const int AB    = NN / 8;            // 6250 agg blocks (exact, 8 nodes/block)

  hipMemsetAsync(zr, 0, 2048 + 3 * 32768, stream);

  // ---- mega-prep: reorder | x-stats | bin ----
  k_prep<<<548, 512, 0, stream>>>(projW, skipW, c1W, c2W, c3W, clsW1, confW, wr,
                                  x, xpart, ei, gpos, binned);
  // ---- CSR segments ----
  k_bucket<<<NBK, 256, 0, stream>>>(binned, gpos, rowp, srcl);

  // ---- proj: hr = relu(bn(x) @ projW + b) ----
  k_mgemm<64, 64, 8, 0, 1, 2, 1, 1, 1, 0><<<GB64, 256, 0, stream>>>(
      x, wr_proj, projb, xpart, in_g, in_b, nullptr, nullptr, nullptr, nullptr,
      hr, nullptr, nullptr, nullptr, nullptr, nullptr, nullptr, nullptr, nullptr);

  // ---- dual: hsk = hr@skipW+b ; h1 = hr@c1W (+scores) ----
  k_mgemm_dual<<<GB128, 256, 0, stream>>>(hr, wr_skip, skipb, wr_c1, c1as, c1ad,
                                          hsk, hb, scs, scd);
  k_agg<4><<<AB, 256, 0, stream>>>(hb, scs, scd, rowp, srcl, c1b, agA, part1);

  // ---- GAT layer 2 (bn1+relu fused into A staging) ----
  k_mgemm<64, 128, 8, 1, 2, 1, 0, 0, 1, 4><<<GB64, 256, 0, stream>>>(
      agA, wr_c2, nullptr, part1, bn1g, bn1b, nullptr, c2as, c2ad, nullptr,
      hb, nullptr, scs, scd, nullptr, nullptr, nullptr, nullptr, nullptr);
  k_agg<4><<<AB, 256, 0, stream>>>(hb, scs, scd, rowp, srcl, c2b, agB, part2);

  // ---- GAT layer 3 (H=1; bn2+relu fused) ----
  k_mgemm<64, 128, 8, 1, 2, 1, 0, 0, 1, 1><<<GB64, 256, 0, stream>>>(
      agB, wr_c3, nullptr, part2, bn2g, bn2b, nullptr, c3as, c3ad, nullptr,
      hb, nullptr, scs, scd, nullptr, nullptr, nullptr, nullptr, nullptr);
  k_agg<1><<<AB, 256, 0, stream>>>(hb, scs, scd, rowp, srcl, c3b, agA, part3);

  // ---- classifier: relu(bn3(agA)+hsk) @ [W1|confW] -> C1(LDS) -> c2 -> logits/conf ----
  k_mgemm<128, 128, 5, 1, 3, 1, 1, 0, 2, 0><<<GB128, 256, 0, stream>>>(
      agA, wr_cls, clsb1, part3, bn3g, bn3b, hsk, nullptr, nullptr, confb,
      nullptr, out_conf, nullptr, nullptr, clsW2, clsb2, clsW3, clsb3, out_logits);
}

// Round 12
// 223.191 us; speedup vs baseline: 1.3301x; 1.0360x over previous
//
#include <hip/hip_runtime.h>
#include <cstdint>
#include <cstddef>

#define NN 50000
#define EE 800000
#define TOT_E (NN + EE)
#define NBK 391      // buckets of 128 dst nodes
#define BCAP 2560    // bucket capacity (mean 2048 -> 11 sigma headroom)

typedef __attribute__((ext_vector_type(8))) short short8;
typedef __attribute__((ext_vector_type(4))) float f32x4;

static __device__ __forceinline__ unsigned short f2bf(float f) {
  union { float f; unsigned u; } v;
  v.f = f;
  unsigned r = v.u + 0x7FFFu + ((v.u >> 16) & 1u);  // RNE
  return (unsigned short)(r >> 16);
}
static __device__ __forceinline__ float bf2f(unsigned short u) {
  union { unsigned u; float f; } v;
  v.u = ((unsigned)u) << 16;
  return v.f;
}
static __device__ __forceinline__ float bf2f_lo(unsigned u) {
  union { unsigned u; float f; } v;
  v.u = u << 16;
  return v.f;
}
static __device__ __forceinline__ float bf2f_hi(unsigned u) {
  union { unsigned u; float f; } v;
  v.u = u & 0xFFFF0000u;
  return v.f;
}

// ============================ mega-prep: reorder | x-BN-stats | edge binning ==========
__global__ __launch_bounds__(512) void k_prep(
    const float* __restrict__ projW, const float* __restrict__ skipW,
    const float* __restrict__ c1W, const float* __restrict__ c2W,
    const float* __restrict__ c3W, const float* __restrict__ W1,
    const float* __restrict__ cw, unsigned short* __restrict__ wr,
    const float* __restrict__ x, float* __restrict__ xpart,
    const int* __restrict__ ei, int* __restrict__ gpos,
    unsigned* __restrict__ binned) {
  __shared__ float smf[1024];
  int tx = threadIdx.x;
  int b = blockIdx.x;
  if (b < 164) {
    int o = b * 512 + tx;
    if (o < 8192) {  // proj: K=64, NT=8
      int off = o;
      int j = off & 7, t = off >> 3;
      int q = t & 3; t >>= 2;
      int c = t & 15; t >>= 4;
      int kb = t & 1, ct = t >> 1;
      int k = kb * 32 + q * 8 + j, col = ct * 16 + c;
      wr[o] = f2bf(projW[(size_t)k * 128 + col]);
    } else if (o < 73728) {  // skip/c1/c2/c3: K=128, NT=8
      int region = (o - 8192) >> 14;
      int off = (o - 8192) & 16383;
      const float* W = region == 0 ? skipW : region == 1 ? c1W : region == 2 ? c2W : c3W;
      int j = off & 7, t = off >> 3;
      int q = t & 3; t >>= 2;
      int c = t & 15; t >>= 4;
      int kb = t & 3, ct = t >> 2;
      int k = kb * 32 + q * 8 + j, col = ct * 16 + c;
      wr[o] = f2bf(W[(size_t)k * 128 + col]);
    } else if (o < 83968) {  // cls: K=128, NT=5
      int off = o - 73728;
      int j = off & 7, t = off >> 3;
      int q = t & 3; t >>= 2;
      int c = t & 15; t >>= 4;
      int kb = t & 3, ct = t >> 2;
      int k = kb * 32 + q * 8 + j, col = ct * 16 + c;
      float v = 0.f;
      if (col < 64) v = W1[(size_t)k * 64 + col];
      else if (col == 64) v = cw[k];
      wr[o] = f2bf(v);
    }
  } else if (b < 292) {
    // ---- input BN stats: 128 blocks, float4 loads, shfl reduce, private slot ----
    int bi = b - 164;
    int lane = tx & 63, wv = tx >> 6;
    int cg = lane & 15;
    int rsub = wv * 4 + (lane >> 4);
    int col4 = cg * 4;
    float s[4] = {0.f, 0.f, 0.f, 0.f}, q[4] = {0.f, 0.f, 0.f, 0.f};
    for (int r = bi * 32 + rsub; r < NN; r += 128 * 32) {
      float4 v = *(const float4*)(x + (size_t)r * 64 + col4);
      s[0] += v.x; q[0] += v.x * v.x;
      s[1] += v.y; q[1] += v.y * v.y;
      s[2] += v.z; q[2] += v.z * v.z;
      s[3] += v.w; q[3] += v.w * v.w;
    }
#pragma unroll
    for (int j = 0; j < 4; ++j) {
      s[j] += __shfl_xor(s[j], 16); s[j] += __shfl_xor(s[j], 32);
      q[j] += __shfl_xor(q[j], 16); q[j] += __shfl_xor(q[j], 32);
    }
    if (lane < 16) {
#pragma unroll
      for (int j = 0; j < 4; ++j) {
        smf[wv * 128 + col4 + j] = s[j];
        smf[wv * 128 + 64 + col4 + j] = q[j];
      }
    }
    __syncthreads();
    if (tx < 64) {
      float ss = 0.f, qq = 0.f;
#pragma unroll
      for (int w = 0; w < 8; ++w) {
        ss += smf[w * 128 + tx];
        qq += smf[w * 128 + 64 + tx];
      }
      xpart[bi * 128 + tx] = ss;
      xpart[bi * 128 + 64 + tx] = qq;
    }
  } else {
    // ---- bin edges ----
    int* cnt = (int*)smf;
    int* base = (int*)smf + 512;
    cnt[tx] = 0;
    __syncthreads();
    int e0 = (b - 292) * 3125;
    int e1 = e0 + 3125;
    if (e1 > EE) e1 = EE;
    for (int i = e0 + tx; i < e1; i += 512) {
      int d = ei[EE + i];
      atomicAdd(&cnt[d >> 7], 1);
    }
    __syncthreads();
    if (tx < NBK) {
      int c = cnt[tx];
      base[tx] = c ? atomicAdd(&gpos[tx], c) : 0;
      cnt[tx] = 0;
    }
    __syncthreads();
    for (int i = e0 + tx; i < e1; i += 512) {
      int s = ei[i];
      int d = ei[EE + i];
      int bk = d >> 7;
      int slot = base[bk] + atomicAdd(&cnt[bk], 1);
      if (slot < BCAP)
        binned[(size_t)bk * BCAP + slot] = (unsigned)s | ((unsigned)(d & 127) << 16);
    }
  }
}

// ============================ bucket: CSR segment build (inline ebase scan) ============
__global__ __launch_bounds__(256) void k_bucket(const unsigned* __restrict__ binned,
                                                const int* __restrict__ gpos,
                                                int* __restrict__ rowp,
                                                int* __restrict__ srcl) {
  __shared__ int cnt[128], offs[128], cur[128];
  __shared__ int red[256], red2[256];
  int b = blockIdx.x, tid = threadIdx.x;
  int accp = 0, acct = 0;
  for (int i = tid; i < NBK; i += 256) {
    int gv = gpos[i];
    if (gv > BCAP) gv = BCAP;
    if (i < b) accp += gv;
    acct += gv;
  }
  red[tid] = accp;
  red2[tid] = acct;
  __syncthreads();
  for (int o = 128; o; o >>= 1) {
    if (tid < o) {
      red[tid] += red[tid + o];
      red2[tid] += red2[tid + o];
    }
    __syncthreads();
  }
  int eb = (b << 7) + red[0];
  if (b == NBK - 1 && tid == 0) rowp[NN] = red2[0] + NN;

  int n0 = b << 7;
  int nodes = NN - n0;
  if (nodes > 128) nodes = 128;
  int ne = gpos[b];
  if (ne > BCAP) ne = BCAP;
  if (tid < 128) cnt[tid] = (tid < nodes) ? 1 : 0;  // 1 = self-loop
  __syncthreads();
  const unsigned* bb = binned + (size_t)b * BCAP;
  for (int i = tid; i < ne; i += 256) atomicAdd(&cnt[bb[i] >> 16], 1);
  __syncthreads();
  if (tid < 128) offs[tid] = cnt[tid];
  __syncthreads();
  for (int o = 1; o < 128; o <<= 1) {
    int t = (tid < 128 && tid >= o) ? offs[tid - o] : 0;
    __syncthreads();
    if (tid < 128) offs[tid] += t;
    __syncthreads();
  }
  if (tid < 128 && tid < nodes) {
    int ex = offs[tid] - cnt[tid];
    rowp[n0 + tid] = eb + ex;
    srcl[eb + ex] = n0 + tid;  // self-loop first
    cur[tid] = ex + 1;
  }
  __syncthreads();
  for (int i = tid; i < ne; i += 256) {
    unsigned e = bb[i];
    int r = atomicAdd(&cur[e >> 16], 1);
    srcl[eb + r] = (int)(e & 0xFFFFu);
  }
}

// ============================ shared device helpers ============================
template <int NH, int NT, int F>
static __device__ __forceinline__ void write_scores(const f32x4 (&acc)[F][NT],
                                                    const float* __restrict__ a_s,
                                                    const float* __restrict__ a_d,
                                                    int r0, int lane, int wv,
                                                    float* __restrict__ scs,
                                                    float* __restrict__ scd) {
  const int lr = lane & 15, lg = lane >> 4;
  float asv[NT], adv[NT];
#pragma unroll
  for (int ct = 0; ct < NT; ++ct) {
    asv[ct] = a_s[ct * 16 + lr];
    adv[ct] = a_d[ct * 16 + lr];
  }
  float ps[F][4][NH], pd[F][4][NH];
#pragma unroll
  for (int f = 0; f < F; ++f)
#pragma unroll
    for (int r = 0; r < 4; ++r)
#pragma unroll
      for (int h = 0; h < NH; ++h) { ps[f][r][h] = 0.f; pd[f][r][h] = 0.f; }
#pragma unroll
  for (int f = 0; f < F; ++f)
#pragma unroll
    for (int ct = 0; ct < NT; ++ct) {
      int h = (NH == 1) ? 0 : (ct >> 1);
#pragma unroll
      for (int r = 0; r < 4; ++r) {
        ps[f][r][h] = fmaf(acc[f][ct][r], asv[ct], ps[f][r][h]);
        pd[f][r][h] = fmaf(acc[f][ct][r], adv[ct], pd[f][r][h]);
      }
    }
#pragma unroll
  for (int off = 1; off < 16; off <<= 1)
#pragma unroll
    for (int f = 0; f < F; ++f)
#pragma unroll
      for (int r = 0; r < 4; ++r)
#pragma unroll
        for (int h = 0; h < NH; ++h) {
          ps[f][r][h] += __shfl_xor(ps[f][r][h], off);
          pd[f][r][h] += __shfl_xor(pd[f][r][h], off);
        }
  if (lr == 0) {
#pragma unroll
    for (int f = 0; f < F; ++f) {
      int rowb = r0 + (wv * F + f) * 16 + lg * 4;
#pragma unroll
      for (int r = 0; r < 4; ++r) {
        int gr = rowb + r;
        if (gr < NN) {
          if (NH == 4) {
            float4 vs = make_float4(ps[f][r][0], ps[f][r][1], ps[f][r][2], ps[f][r][3]);
            float4 vd = make_float4(pd[f][r][0], pd[f][r][1], pd[f][r][2], pd[f][r][3]);
            *(float4*)(scs + (size_t)gr * 4) = vs;
            *(float4*)(scd + (size_t)gr * 4) = vd;
          } else {
            scs[gr] = ps[f][r][0];
            scd[gr] = pd[f][r][0];
          }
        }
      }
    }
  }
}

template <int BIAS, int RELU, int NT, int F>
static __device__ __forceinline__ void write_out_bf(const f32x4 (&acc)[F][NT],
                                                    const float* __restrict__ bias,
                                                    int r0, int lane, int wv,
                                                    unsigned short* __restrict__ out) {
  const int lr = lane & 15, lg = lane >> 4;
#pragma unroll
  for (int f = 0; f < F; ++f) {
    int rowb = r0 + (wv * F + f) * 16 + lg * 4;
#pragma unroll
    for (int ct = 0; ct < NT; ++ct) {
      int col = ct * 16 + lr;
      float bb = BIAS ? bias[col] : 0.f;
#pragma unroll
      for (int r = 0; r < 4; ++r) {
        int gr = rowb + r;
        if (gr < NN) {
          float o = acc[f][ct][r] + bb;
          if (RELU) o = fmaxf(o, 0.f);
          out[(size_t)gr * 128 + col] = f2bf(o);
        }
      }
    }
  }
}

// ============================ fused front: proj -> skip + conv1(+scores) ============
// One kernel, BM=128. Phase 1: A1 = bn(x) bf16 fragments (K=64) + B=projW -> proj acc.
// Proj result (relu,+bias) written straight back to LDS as the K=128 A-fragment; then
// B=skipW -> hsk, restage B=c1W -> hb + fused attention scores. hr never hits global.
__global__ __launch_bounds__(256) void k_front(
    const float* __restrict__ x, const float* __restrict__ xpart,
    const float* __restrict__ in_g, const float* __restrict__ in_b,
    const unsigned short* __restrict__ BwP, const float* __restrict__ projb,
    const unsigned short* __restrict__ BwS, const float* __restrict__ skipb,
    const unsigned short* __restrict__ BwC, const float* __restrict__ a_s,
    const float* __restrict__ a_d,
    unsigned short* __restrict__ hsk, unsigned short* __restrict__ hb,
    float* __restrict__ scs, float* __restrict__ scd) {
  __shared__ __align__(16) unsigned short sm[32768];  // 64 KB
  __shared__ float bnsc[64], bnsh[64];
  const int tid = threadIdx.x;
  const int r0 = blockIdx.x * 128;

  if (tid < 64) {
    float s = 0.f, q = 0.f;
#pragma unroll 8
    for (int pp = 0; pp < 128; ++pp) {
      s += xpart[pp * 128 + tid];
      q += xpart[pp * 128 + 64 + tid];
    }
    float invM = 1.f / (float)NN;
    float mu = s * invM;
    float var = q * invM - mu * mu;
    float sc = in_g[tid] * rsqrtf(var + 1e-5f);
    bnsc[tid] = sc;
    bnsh[tid] = in_b[tid] - mu * sc;
  }
  __syncthreads();

  // ---- stage A1: bn(x) as bf16 fragments, K=64 (KB=2), at offset 0 ----
#pragma unroll
  for (int it = 0; it < 8; ++it) {
    int idx = it * 256 + tid;
    int r = idx >> 4;
    int k = (idx & 15) * 4;
    int gr = r0 + r;
    float4 av = make_float4(0.f, 0.f, 0.f, 0.f);
    if (gr < NN) av = *(const float4*)(x + (size_t)gr * 64 + k);
    av.x = av.x * bnsc[k + 0] + bnsh[k + 0];
    av.y = av.y * bnsc[k + 1] + bnsh[k + 1];
    av.z = av.z * bnsc[k + 2] + bnsh[k + 2];
    av.w = av.w * bnsc[k + 3] + bnsh[k + 3];
    ushort4 o;
    o.x = f2bf(av.x); o.y = f2bf(av.y); o.z = f2bf(av.z); o.w = f2bf(av.w);
    *(ushort4*)&sm[((r >> 4) * 2 + (k >> 5)) * 512 + (r & 15) * 32 + (k & 31)] = o;
  }
  // ---- stage B1 = projW fragments at offset 8192 ----
#pragma unroll
  for (int it = 0; it < 4; ++it) {
    int idx = it * 256 + tid;
    *(uint4*)&sm[8192 + idx * 8] = *(const uint4*)(BwP + idx * 8);
  }
  __syncthreads();

  const int lane = tid & 63, wv = tid >> 6;
  const int lr = lane & 15, lg = lane >> 4;
  const int fidx = lr * 32 + lg * 8;
  f32x4 acc[2][8];
#pragma unroll
  for (int f = 0; f < 2; ++f)
#pragma unroll
    for (int ct = 0; ct < 8; ++ct) acc[f][ct] = (f32x4){0.f, 0.f, 0.f, 0.f};
#pragma unroll
  for (int kb = 0; kb < 2; ++kb) {
    short8 a0 = *(const short8*)&sm[((wv * 2 + 0) * 2 + kb) * 512 + fidx];
    short8 a1 = *(const short8*)&sm[((wv * 2 + 1) * 2 + kb) * 512 + fidx];
#pragma unroll
    for (int ct = 0; ct < 8; ++ct) {
      short8 b = *(const short8*)&sm[8192 + (ct * 2 + kb) * 512 + fidx];
      acc[0][ct] = __builtin_amdgcn_mfma_f32_16x16x32_bf16(a0, b, acc[0][ct], 0, 0, 0);
      acc[1][ct] = __builtin_amdgcn_mfma_f32_16x16x32_bf16(a1, b, acc[1][ct], 0, 0, 0);
    }
  }
  __syncthreads();  // all waves done reading A1/B1

  // ---- write proj result (relu, +bias) as K=128 A-fragment at offset 0 ----
  {
    float pbv[8];
#pragma unroll
    for (int ct = 0; ct < 8; ++ct) pbv[ct] = projb[ct * 16 + lr];
#pragma unroll
    for (int f = 0; f < 2; ++f) {
      int rowb = (wv * 2 + f) * 16 + lg * 4;
#pragma unroll
      for (int ct = 0; ct < 8; ++ct) {
        int col = ct * 16 + lr;
#pragma unroll
        for (int r = 0; r < 4; ++r) {
          int row = rowb + r;
          float o = fmaxf(acc[f][ct][r] + pbv[ct], 0.f);
          sm[((row >> 4) * 4 + (col >> 5)) * 512 + (row & 15) * 32 + (col & 31)] = f2bf(o);
        }
      }
    }
  }
  // ---- stage B2 = skipW at offset 16384 ----
#pragma unroll
  for (int it = 0; it < 8; ++it) {
    int idx = it * 256 + tid;
    *(uint4*)&sm[16384 + idx * 8] = *(const uint4*)(BwS + idx * 8);
  }
  __syncthreads();

#pragma unroll
  for (int f = 0; f < 2; ++f)
#pragma unroll
    for (int ct = 0; ct < 8; ++ct) acc[f][ct] = (f32x4){0.f, 0.f, 0.f, 0.f};
#pragma unroll
  for (int kb = 0; kb < 4; ++kb) {
    short8 a0 = *(const short8*)&sm[((wv * 2 + 0) * 4 + kb) * 512 + fidx];
    short8 a1 = *(const short8*)&sm[((wv * 2 + 1) * 4 + kb) * 512 + fidx];
#pragma unroll
    for (int ct = 0; ct < 8; ++ct) {
      short8 b = *(const short8*)&sm[16384 + (ct * 4 + kb) * 512 + fidx];
      acc[0][ct] = __builtin_amdgcn_mfma_f32_16x16x32_bf16(a0, b, acc[0][ct], 0, 0, 0);
      acc[1][ct] = __builtin_amdgcn_mfma_f32_16x16x32_bf16(a1, b, acc[1][ct], 0, 0, 0);
    }
  }
  write_out_bf<1, 0>(acc, skipb, r0, lane, wv, hsk);
  __syncthreads();  // done reading B2

  // ---- stage B3 = c1W at offset 16384 ----
#pragma unroll
  for (int it = 0; it < 8; ++it) {
    int idx = it * 256 + tid;
    *(uint4*)&sm[16384 + idx * 8] = *(const uint4*)(BwC + idx * 8);
  }
  __syncthreads();

#pragma unroll
  for (int f = 0; f < 2; ++f)
#pragma unroll
    for (int ct = 0; ct < 8; ++ct) acc[f][ct] = (f32x4){0.f, 0.f, 0.f, 0.f};
#pragma unroll
  for (int kb = 0; kb < 4; ++kb) {
    short8 a0 = *(const short8*)&sm[((wv * 2 + 0) * 4 + kb) * 512 + fidx];
    short8 a1 = *(const short8*)&sm[((wv * 2 + 1) * 4 + kb) * 512 + fidx];
#pragma unroll
    for (int ct = 0; ct < 8; ++ct) {
      short8 b = *(const short8*)&sm[16384 + (ct * 4 + kb) * 512 + fidx];
      acc[0][ct] = __builtin_amdgcn_mfma_f32_16x16x32_bf16(a0, b, acc[0][ct], 0, 0, 0);
      acc[1][ct] = __builtin_amdgcn_mfma_f32_16x16x32_bf16(a1, b, acc[1][ct], 0, 0, 0);
    }
  }
  write_scores<4>(acc, a_s, a_d, r0, lane, wv, scs, scd);
  write_out_bf<0, 0>(acc, nullptr, r0, lane, wv, hb);
}

// ============================ MFMA GEMM ============================
// BM rows per block (64/128). BN: 0 none, 1 sc/sh, 2 +relu, 3 +skip+relu.
// BNP: 1 = 32 agg partials (stride 256). OUTM: 1 bf16 out; 2 classifier tail (BM=128).
// SCH: 0 off, 1/4 GAT scores.
template <int BM, int K, int NT, int ABF, int BN, int BNP, int BIAS, int RELU, int OUTM, int SCH>
__global__ __launch_bounds__(256) void k_mgemm(
    const void* __restrict__ Ain, const unsigned short* __restrict__ Bw,
    const float* __restrict__ bias,
    const float* __restrict__ bnsums, const float* __restrict__ bng,
    const float* __restrict__ bnb,
    const unsigned short* __restrict__ skip,
    const float* __restrict__ a_s, const float* __restrict__ a_d,
    const float* __restrict__ confb,
    void* __restrict__ Cout, float* __restrict__ conf,
    float* __restrict__ scs, float* __restrict__ scd,
    const float* __restrict__ W2, const float* __restrict__ b2,
    const float* __restrict__ W3, const float* __restrict__ b3,
    float* __restrict__ logits) {
  constexpr int KB = K / 32;
  constexpr int RT = BM / 16;
  constexpr int F = BM / 64;
  __shared__ __align__(16) unsigned short sm[(RT + NT) * KB * 512];
  __shared__ float bnsc[128], bnsh[128];
  const int tid = threadIdx.x;
  const int r0 = blockIdx.x * BM;

  if constexpr (BN) {
    if (tid < K) {
      float s = 0.f, q = 0.f;
#pragma unroll 8
      for (int pp = 0; pp < 32; ++pp) {
        s += bnsums[pp * 256 + tid];
        q += bnsums[pp * 256 + 128 + tid];
      }
      float invM = 1.f / (float)NN;
      float mu = s * invM;
      float var = q * invM - mu * mu;
      float sc = bng[tid] * rsqrtf(var + 1e-5f);
      bnsc[tid] = sc;
      bnsh[tid] = bnb[tid] - mu * sc;
    }
    __syncthreads();
  }

  // ---- stage A (bf16 input) ----
  {
    const unsigned short* A = (const unsigned short*)Ain;
    constexpr int IT = BM * (K / 8) / 256;
#pragma unroll
    for (int it = 0; it < IT; ++it) {
      int idx = it * 256 + tid;
      int r = idx / (K / 8);
      int k = (idx % (K / 8)) * 8;
      int gr = r0 + r;
      union { uint4 u4; unsigned short us[8]; } v;
      v.u4 = make_uint4(0, 0, 0, 0);
      if (gr < NN) v.u4 = *(const uint4*)(A + (size_t)gr * K + k);
      if constexpr (BN) {
        union { uint4 u4; unsigned short us[8]; } sv;
        if (BN == 3) {
          sv.u4 = make_uint4(0, 0, 0, 0);
          if (gr < NN) sv.u4 = *(const uint4*)(skip + (size_t)gr * 128 + k);
        }
#pragma unroll
        for (int j = 0; j < 8; ++j) {
          float f = bf2f(v.us[j]) * bnsc[k + j] + bnsh[k + j];
          if (BN == 3) f += bf2f(sv.us[j]);
          if (BN >= 2) f = fmaxf(f, 0.f);
          v.us[j] = f2bf(f);
        }
      }
      *(uint4*)&sm[((r >> 4) * KB + (k >> 5)) * 512 + (r & 15) * 32 + (k & 31)] = v.u4;
    }
  }
  // ---- stage B ----
  {
    constexpr int BW = NT * KB * 512;
#pragma unroll
    for (int it = 0; it < BW / 2048; ++it) {
      int idx = it * 256 + tid;
      *(uint4*)&sm[RT * KB * 512 + idx * 8] = *(const uint4*)(Bw + idx * 8);
    }
  }
  __syncthreads();

  // ---- MFMA ----
  const int lane = tid & 63, wv = tid >> 6;
  const int lr = lane & 15, lg = lane >> 4;
  const int fidx = lr * 32 + lg * 8;
  f32x4 acc[F][NT];
#pragma unroll
  for (int f = 0; f < F; ++f)
#pragma unroll
    for (int ct = 0; ct < NT; ++ct) acc[f][ct] = (f32x4){0.f, 0.f, 0.f, 0.f};
#pragma unroll
  for (int kb = 0; kb < KB; ++kb) {
    short8 afr[F];
#pragma unroll
    for (int f = 0; f < F; ++f)
      afr[f] = *(const short8*)&sm[((wv * F + f) * KB + kb) * 512 + fidx];
#pragma unroll
    for (int ct = 0; ct < NT; ++ct) {
      short8 b = *(const short8*)&sm[((RT + ct) * KB + kb) * 512 + fidx];
#pragma unroll
      for (int f = 0; f < F; ++f)
        acc[f][ct] = __builtin_amdgcn_mfma_f32_16x16x32_bf16(afr[f], b, acc[f][ct], 0, 0, 0);
    }
  }

  if constexpr (SCH > 0) {
    write_scores<(SCH == 1) ? 1 : 4>(acc, a_s, a_d, r0, lane, wv, scs, scd);
  }

  if constexpr (OUTM == 2) {
    // -------- classifier tail in-kernel (reuse sm; BM must be 128) --------
    __syncthreads();
    unsigned short* c1s = sm;                 // [128][65] bf16
    float* W2s = (float*)(sm + 8320);         // 64*32
    float* c2s = (float*)(sm + 12416);        // [128][33]
    float* W3s = (float*)(sm + 20864);        // 64
    float* b2s = (float*)(sm + 20992);        // 32
    float* b3s = (float*)(sm + 21056);        // 2
    for (int i = tid; i < 2048; i += 256) W2s[i] = W2[i];
    if (tid < 64) W3s[tid] = W3[tid];
    if (tid < 32) b2s[tid] = b2[tid];
    if (tid < 2) b3s[tid] = b3[tid];
#pragma unroll
    for (int f = 0; f < F; ++f) {
      int lrow = (wv * F + f) * 16 + lg * 4;
#pragma unroll
      for (int ct = 0; ct < NT; ++ct) {
        int col = ct * 16 + lr;
        if (col < 64) {
          float bb = bias[col];
#pragma unroll
          for (int r = 0; r < 4; ++r)
            c1s[(lrow + r) * 65 + col] = f2bf(fmaxf(acc[f][ct][r] + bb, 0.f));
        } else if (col == 64) {
          float cb = confb[0];
#pragma unroll
          for (int r = 0; r < 4; ++r) {
            int gr = r0 + lrow + r;
            if (gr < NN) conf[gr] = 1.f / (1.f + __expf(-(acc[f][ct][r] + cb)));
          }
        }
      }
    }
    __syncthreads();
    {
      int node = tid & 127;
      int cb = (tid >> 7) * 16;
      float a2[16];
#pragma unroll
      for (int i = 0; i < 16; ++i) a2[i] = b2s[cb + i];
      for (int k = 0; k < 64; ++k) {
        float v = bf2f(c1s[node * 65 + k]);
#pragma unroll
        for (int i = 0; i < 16; ++i) a2[i] = fmaf(v, W2s[k * 32 + cb + i], a2[i]);
      }
#pragma unroll
      for (int i = 0; i < 16; ++i) c2s[node * 33 + cb + i] = fmaxf(a2[i], 0.f);
    }
    __syncthreads();
    {
      int node = tid >> 1, j = tid & 1;
      float s3 = b3s[j];
#pragma unroll 8
      for (int k = 0; k < 32; ++k) s3 = fmaf(c2s[node * 33 + k], W3s[k * 2 + j], s3);
      int gr = r0 + node;
      if (gr < NN) logits[(size_t)gr * 2 + j] = s3;
    }
  } else {
    write_out_bf<BIAS, RELU>(acc, bias, r0, lane, wv, (unsigned short*)Cout);
  }
}

// ============================ GAT aggregation (+ fused BN stats) ============================
template <int H>
__global__ __launch_bounds__(256) void k_agg(const unsigned short* __restrict__ hp,
                                             const float* __restrict__ scs,
                                             const float* __restrict__ scd,
                                             const int* __restrict__ rowp,
                                             const int* __restrict__ srcl,
                                             const float* __restrict__ bias,
                                             unsigned short* __restrict__ out,
                                             float* __restrict__ part) {
  __shared__ float ssum[8][144], ssq[8][144];
  int tid = threadIdx.x;
  int lane = tid & 63, wv = tid >> 6;
  int half = lane >> 5;
  int l32 = lane & 31;
  int g = l32 >> 4;
  int l16 = lane & 15;
  int n = (blockIdx.x * 4 + wv) * 2 + half;
  int c0 = l16 * 8;
  int hid = (H == 1) ? 0 : (l16 >> 2);
  float sd = scd[(size_t)n * H + hid];
  int beg = rowp[n], end = rowp[n + 1];
  int last = end - 1;
  float a[8];
#pragma unroll
  for (int i = 0; i < 8; ++i) a[i] = 0.f;
  float sw = 0.f;
  int k0 = beg + g * 4;
  int s0 = srcl[(k0 + 0) <= last ? (k0 + 0) : last];
  int s1 = srcl[(k0 + 1) <= last ? (k0 + 1) : last];
  int s2 = srcl[(k0 + 2) <= last ? (k0 + 2) : last];
  int s3 = srcl[(k0 + 3) <= last ? (k0 + 3) : last];
  for (; k0 < end; k0 += 8) {
    int np = k0 + 8;
    int t0 = srcl[(np + 0) <= last ? (np + 0) : last];
    int t1 = srcl[(np + 1) <= last ? (np + 1) : last];
    int t2 = srcl[(np + 2) <= last ? (np + 2) : last];
    int t3 = srcl[(np + 3) <= last ? (np + 3) : last];
    float e0 = scs[(size_t)s0 * H + hid] + sd;
    float e1 = scs[(size_t)s1 * H + hid] + sd;
    float e2 = scs[(size_t)s2 * H + hid] + sd;
    float e3 = scs[(size_t)s3 * H + hid] + sd;
    uint4 u0 = *(const uint4*)(hp + (size_t)s0 * 128 + c0);
    uint4 u1 = *(const uint4*)(hp + (size_t)s1 * 128 + c0);
    uint4 u2 = *(const uint4*)(hp + (size_t)s2 * 128 + c0);
    uint4 u3 = *(const uint4*)(hp + (size_t)s3 * 128 + c0);
    e0 = fmaxf(e0, 0.f) + 0.2f * fminf(e0, 0.f);
    e1 = fmaxf(e1, 0.f) + 0.2f * fminf(e1, 0.f);
    e2 = fmaxf(e2, 0.f) + 0.2f * fminf(e2, 0.f);
    e3 = fmaxf(e3, 0.f) + 0.2f * fminf(e3, 0.f);
    float w0 = __expf(e0);
    float w1 = (k0 + 1 <= last) ? __expf(e1) : 0.f;
    float w2 = (k0 + 2 <= last) ? __expf(e2) : 0.f;
    float w3 = (k0 + 3 <= last) ? __expf(e3) : 0.f;
    a[0] = fmaf(w0, bf2f_lo(u0.x), a[0]); a[1] = fmaf(w0, bf2f_hi(u0.x), a[1]);
    a[2] = fmaf(w0, bf2f_lo(u0.y), a[2]); a[3] = fmaf(w0, bf2f_hi(u0.y), a[3]);
    a[4] = fmaf(w0, bf2f_lo(u0.z), a[4]); a[5] = fmaf(w0, bf2f_hi(u0.z), a[5]);
    a[6] = fmaf(w0, bf2f_lo(u0.w), a[6]); a[7] = fmaf(w0, bf2f_hi(u0.w), a[7]);
    a[0] = fmaf(w1, bf2f_lo(u1.x), a[0]); a[1] = fmaf(w1, bf2f_hi(u1.x), a[1]);
    a[2] = fmaf(w1, bf2f_lo(u1.y), a[2]); a[3] = fmaf(w1, bf2f_hi(u1.y), a[3]);
    a[4] = fmaf(w1, bf2f_lo(u1.z), a[4]); a[5] = fmaf(w1, bf2f_hi(u1.z), a[5]);
    a[6] = fmaf(w1, bf2f_lo(u1.w), a[6]); a[7] = fmaf(w1, bf2f_hi(u1.w), a[7]);
    a[0] = fmaf(w2, bf2f_lo(u2.x), a[0]); a[1] = fmaf(w2, bf2f_hi(u2.x), a[1]);
    a[2] = fmaf(w2, bf2f_lo(u2.y), a[2]); a[3] = fmaf(w2, bf2f_hi(u2.y), a[3]);
    a[4] = fmaf(w2, bf2f_lo(u2.z), a[4]); a[5] = fmaf(w2, bf2f_hi(u2.z), a[5]);
    a[6] = fmaf(w2, bf2f_lo(u2.w), a[6]); a[7] = fmaf(w2, bf2f_hi(u2.w), a[7]);
    a[0] = fmaf(w3, bf2f_lo(u3.x), a[0]); a[1] = fmaf(w3, bf2f_hi(u3.x), a[1]);
    a[2] = fmaf(w3, bf2f_lo(u3.y), a[2]); a[3] = fmaf(w3, bf2f_hi(u3.y), a[3]);
    a[4] = fmaf(w3, bf2f_lo(u3.z), a[4]); a[5] = fmaf(w3, bf2f_hi(u3.z), a[5]);
    a[6] = fmaf(w3, bf2f_lo(u3.w), a[6]); a[7] = fmaf(w3, bf2f_hi(u3.w), a[7]);
    sw += (w0 + w1) + (w2 + w3);
    s0 = t0; s1 = t1; s2 = t2; s3 = t3;
  }
#pragma unroll
  for (int i = 0; i < 8; ++i) a[i] += __shfl_xor(a[i], 16);
  sw += __shfl_xor(sw, 16);
  int slice = wv * 2 + half;
  if (g == 0) {
    float inv = 1.f / (sw + 1e-16f);
    unsigned wb[4];
    int ib = c0 + l16;  // padded: c + (c>>3)
#pragma unroll
    for (int j = 0; j < 4; ++j) {
      float o0 = a[2 * j] * inv + bias[c0 + 2 * j];
      float o1 = a[2 * j + 1] * inv + bias[c0 + 2 * j + 1];
      ssum[slice][ib + 2 * j] = o0;
      ssum[slice][ib + 2 * j + 1] = o1;
      ssq[slice][ib + 2 * j] = o0 * o0;
      ssq[slice][ib + 2 * j + 1] = o1 * o1;
      wb[j] = (unsigned)f2bf(o0) | ((unsigned)f2bf(o1) << 16);
    }
    *(uint4*)(out + (size_t)n * 128 + c0) = make_uint4(wb[0], wb[1], wb[2], wb[3]);
  }
  __syncthreads();
  if (tid < 128) {
    int idx = tid + (tid >> 3);
    float s = 0.f, q = 0.f;
#pragma unroll
    for (int sl = 0; sl < 8; ++sl) {
      s += ssum[sl][idx];
      q += ssq[sl][idx];
    }
    int pb = (blockIdx.x & 31) * 256;
    atomicAdd(&part[pb + tid], s);
    atomicAdd(&part[pb + 128 + tid], q);
  }
}

// ============================ launch ============================
extern "C" void kernel_launch(void* const* d_in, const int* in_sizes, int n_in,
                              void* d_out, int out_size, void* d_ws, size_t ws_size,
                              hipStream_t stream) {
  (void)in_sizes; (void)n_in; (void)out_size; (void)ws_size;
  const float* x       = (const float*)d_in[0];
  const int*   ei      = (const int*)d_in[1];
  const float* in_g    = (const float*)d_in[2];
  const float* in_b    = (const float*)d_in[3];
  const float* projW   = (const float*)d_in[4];
  const float* projb   = (const float*)d_in[5];
  const float* skipW   = (const float*)d_in[6];
  const float* skipb   = (const float*)d_in[7];
  const float* c1W     = (const float*)d_in[8];
  const float* c1as    = (const float*)d_in[9];
  const float* c1ad    = (const float*)d_in[10];
  const float* c1b     = (const float*)d_in[11];
  const float* bn1g    = (const float*)d_in[12];
  const float* bn1b    = (const float*)d_in[13];
  const float* c2W     = (const float*)d_in[14];
  const float* c2as    = (const float*)d_in[15];
  const float* c2ad    = (const float*)d_in[16];
  const float* c2b     = (const float*)d_in[17];
  const float* bn2g    = (const float*)d_in[18];
  const float* bn2b    = (const float*)d_in[19];
  const float* c3W     = (const float*)d_in[20];
  const float* c3as    = (const float*)d_in[21];
  const float* c3ad    = (const float*)d_in[22];
  const float* c3b     = (const float*)d_in[23];
  const float* bn3g    = (const float*)d_in[24];
  const float* bn3b    = (const float*)d_in[25];
  const float* clsW1   = (const float*)d_in[26];
  const float* clsb1   = (const float*)d_in[27];
  const float* clsW2   = (const float*)d_in[28];
  const float* clsb2   = (const float*)d_in[29];
  const float* clsW3   = (const float*)d_in[30];
  const float* clsb3   = (const float*)d_in[31];
  const float* confW   = (const float*)d_in[32];
  const float* confb   = (const float*)d_in[33];

  float* out_logits = (float*)d_out;
  float* out_conf   = (float*)d_out + (size_t)NN * 2;

  char* p = (char*)d_ws;
  auto alloc = [&](size_t bytes) -> char* {
    char* r = p;
    p += (bytes + 255) & ~(size_t)255;
    return r;
  };
  unsigned short* hsk = (unsigned short*)alloc((size_t)NN * 128 * 2);  // h_skip
  unsigned short* hb  = (unsigned short*)alloc((size_t)NN * 128 * 2);  // conv h
  unsigned short* agA = (unsigned short*)alloc((size_t)NN * 128 * 2);  // agg out (L1, L3)
  unsigned short* agB = (unsigned short*)alloc((size_t)NN * 128 * 2);  // agg out (L2)
  float* scs   = (float*)alloc((size_t)NN * 4 * 4);
  float* scd   = (float*)alloc((size_t)NN * 4 * 4);
  // zero region: gpos | part1 | part2 | part3 (32 slots x 256 floats each)
  char*  zr    = alloc(2048 + 3 * 32768);
  int*   gpos  = (int*)zr;
  float* part1 = (float*)(zr + 2048);
  float* part2 = part1 + 8192;
  float* part3 = part2 + 8192;
  float* xpart = (float*)alloc(128 * 128 * 4);  // input BN partials (no zeroing needed)
  int*   rowp  = (int*)alloc((size_t)(NN + 1) * 4);
  unsigned* binned = (unsigned*)alloc((size_t)NBK * BCAP * 4);
  int*   srcl  = (int*)alloc((size_t)TOT_E * 4);
  unsigned short* wr = (unsigned short*)alloc(83968 * 2);
  unsigned short* wr_proj = wr;
  unsigned short* wr_skip = wr + 8192;
  unsigned short* wr_c1   = wr + 24576;
  unsigned short* wr_c2   = wr + 40960;
  unsigned short* wr_c3   = wr + 57344;
  unsigned short* wr_cls  = wr + 73728;

  const int GB64  = (NN + 63) / 64;    // 782
  const int GB128 = (NN + 127) / 128;  // 391
  const int AB    = NN / 8;            // 6250 agg blocks

  hipMemsetAsync(zr, 0, 2048 + 3 * 32768, stream);

  // ---- mega-prep: reorder | x-stats | bin ----
  k_prep<<<548, 512, 0, stream>>>(projW, skipW, c1W, c2W, c3W, clsW1, confW, wr,
                                  x, xpart, ei, gpos, binned);
  // ---- CSR segments ----
  k_bucket<<<NBK, 256, 0, stream>>>(binned, gpos, rowp, srcl);

  // ---- fused front: proj -> skip + conv1 (+scores) ----
  k_front<<<GB128, 256, 0, stream>>>(x, xpart, in_g, in_b, wr_proj, projb,
                                     wr_skip, skipb, wr_c1, c1as, c1ad,
                                     hsk, hb, scs, scd);
  k_agg<4><<<AB, 256, 0, stream>>>(hb, scs, scd, rowp, srcl, c1b, agA, part1);

  // ---- GAT layer 2 (bn1+relu fused into A staging) ----
  k_mgemm<64, 128, 8, 1, 2, 1, 0, 0, 1, 4><<<GB64, 256, 0, stream>>>(
      agA, wr_c2, nullptr, part1, bn1g, bn1b, nullptr, c2as, c2ad, nullptr,
      hb, nullptr, scs, scd, nullptr, nullptr, nullptr, nullptr, nullptr);
  k_agg<4><<<AB, 256, 0, stream>>>(hb, scs, scd, rowp, srcl, c2b, agB, part2);

  // ---- GAT layer 3 (H=1; bn2+relu fused) ----
  k_mgemm<64, 128, 8, 1, 2, 1, 0, 0, 1, 1><<<GB64, 256, 0, stream>>>(
      agB, wr_c3, nullptr, part2, bn2g, bn2b, nullptr, c3as, c3ad, nullptr,
      hb, nullptr, scs, scd, nullptr, nullptr, nullptr, nullptr, nullptr);
  k_agg<1><<<AB, 256, 0, stream>>>(hb, scs, scd, rowp, srcl, c3b, agA, part3);

  // ---- classifier: relu(bn3(agA)+hsk) @ [W1|confW] -> C1(LDS) -> c2 -> logits/conf ----
  k_mgemm<128, 128, 5, 1, 3, 1, 1, 0, 2, 0><<<GB128, 256, 0, stream>>>(
      agA, wr_cls, clsb1, part3, bn3g, bn3b, hsk, nullptr, nullptr, confb,
      nullptr, out_conf, nullptr, nullptr, clsW2, clsb2, clsW3, clsb3, out_logits);
}

// Round 13
// 216.363 us; speedup vs baseline: 1.3721x; 1.0316x over previous
//
#include <hip/hip_runtime.h>
#include <cstdint>
#include <cstddef>

#define NN 50000
#define EE 800000
#define TOT_E (NN + EE)
#define NBK 391      // buckets of 128 dst nodes
#define BCAP 2560    // bucket capacity (mean 2048 -> 11 sigma headroom)

typedef __attribute__((ext_vector_type(8))) short short8;
typedef __attribute__((ext_vector_type(4))) float f32x4;

static __device__ __forceinline__ unsigned short f2bf(float f) {
  union { float f; unsigned u; } v;
  v.f = f;
  unsigned r = v.u + 0x7FFFu + ((v.u >> 16) & 1u);  // RNE
  return (unsigned short)(r >> 16);
}
static __device__ __forceinline__ float bf2f(unsigned short u) {
  union { unsigned u; float f; } v;
  v.u = ((unsigned)u) << 16;
  return v.f;
}
static __device__ __forceinline__ float bf2f_lo(unsigned u) {
  union { unsigned u; float f; } v;
  v.u = u << 16;
  return v.f;
}
static __device__ __forceinline__ float bf2f_hi(unsigned u) {
  union { unsigned u; float f; } v;
  v.u = u & 0xFFFF0000u;
  return v.f;
}

// ============================ mega-prep: reorder | x-stats | zero | bin ==========
// blocks [0,164): weight reorder; [164,292): input BN stats -> atomicAdd xsum;
// [292,340): zero part1-3; [340,852): bin edges by dst>>7 (gpos pre-zeroed).
__global__ __launch_bounds__(512) void k_prep(
    const float* __restrict__ projW, const float* __restrict__ skipW,
    const float* __restrict__ c1W, const float* __restrict__ c2W,
    const float* __restrict__ c3W, const float* __restrict__ W1,
    const float* __restrict__ cw, unsigned short* __restrict__ wr,
    const float* __restrict__ x, float* __restrict__ xsum,
    float* __restrict__ partz,
    const int* __restrict__ ei, int* __restrict__ gpos,
    unsigned* __restrict__ binned) {
  __shared__ float smf[1024];
  int tx = threadIdx.x;
  int b = blockIdx.x;
  if (b < 164) {
    int o = b * 512 + tx;
    if (o < 8192) {  // proj: K=64, NT=8
      int off = o;
      int j = off & 7, t = off >> 3;
      int q = t & 3; t >>= 2;
      int c = t & 15; t >>= 4;
      int kb = t & 1, ct = t >> 1;
      int k = kb * 32 + q * 8 + j, col = ct * 16 + c;
      wr[o] = f2bf(projW[(size_t)k * 128 + col]);
    } else if (o < 73728) {  // skip/c1/c2/c3: K=128, NT=8
      int region = (o - 8192) >> 14;
      int off = (o - 8192) & 16383;
      const float* W = region == 0 ? skipW : region == 1 ? c1W : region == 2 ? c2W : c3W;
      int j = off & 7, t = off >> 3;
      int q = t & 3; t >>= 2;
      int c = t & 15; t >>= 4;
      int kb = t & 3, ct = t >> 2;
      int k = kb * 32 + q * 8 + j, col = ct * 16 + c;
      wr[o] = f2bf(W[(size_t)k * 128 + col]);
    } else if (o < 83968) {  // cls: K=128, NT=5
      int off = o - 73728;
      int j = off & 7, t = off >> 3;
      int q = t & 3; t >>= 2;
      int c = t & 15; t >>= 4;
      int kb = t & 3, ct = t >> 2;
      int k = kb * 32 + q * 8 + j, col = ct * 16 + c;
      float v = 0.f;
      if (col < 64) v = W1[(size_t)k * 64 + col];
      else if (col == 64) v = cw[k];
      wr[o] = f2bf(v);
    }
  } else if (b < 292) {
    // ---- input BN stats: 128 blocks, float4 loads, shfl reduce, atomicAdd xsum ----
    int bi = b - 164;
    int lane = tx & 63, wv = tx >> 6;
    int cg = lane & 15;
    int rsub = wv * 4 + (lane >> 4);
    int col4 = cg * 4;
    float s[4] = {0.f, 0.f, 0.f, 0.f}, q[4] = {0.f, 0.f, 0.f, 0.f};
    for (int r = bi * 32 + rsub; r < NN; r += 128 * 32) {
      float4 v = *(const float4*)(x + (size_t)r * 64 + col4);
      s[0] += v.x; q[0] += v.x * v.x;
      s[1] += v.y; q[1] += v.y * v.y;
      s[2] += v.z; q[2] += v.z * v.z;
      s[3] += v.w; q[3] += v.w * v.w;
    }
#pragma unroll
    for (int j = 0; j < 4; ++j) {
      s[j] += __shfl_xor(s[j], 16); s[j] += __shfl_xor(s[j], 32);
      q[j] += __shfl_xor(q[j], 16); q[j] += __shfl_xor(q[j], 32);
    }
    if (lane < 16) {
#pragma unroll
      for (int j = 0; j < 4; ++j) {
        smf[wv * 128 + col4 + j] = s[j];
        smf[wv * 128 + 64 + col4 + j] = q[j];
      }
    }
    __syncthreads();
    if (tx < 64) {
      float ss = 0.f, qq = 0.f;
#pragma unroll
      for (int w = 0; w < 8; ++w) {
        ss += smf[w * 128 + tx];
        qq += smf[w * 128 + 64 + tx];
      }
      atomicAdd(&xsum[tx], ss);
      atomicAdd(&xsum[64 + tx], qq);
    }
  } else if (b < 340) {
    // ---- zero part1-3 (24576 floats) ----
    partz[(b - 292) * 512 + tx] = 0.f;
  } else {
    // ---- bin edges: 512 blocks x 1563 edges ----
    int* cnt = (int*)smf;
    int* base = (int*)smf + 512;
    cnt[tx] = 0;
    __syncthreads();
    int e0 = (b - 340) * 1563;
    int e1 = e0 + 1563;
    if (e1 > EE) e1 = EE;
    for (int i = e0 + tx; i < e1; i += 512) {
      int d = ei[EE + i];
      atomicAdd(&cnt[d >> 7], 1);
    }
    __syncthreads();
    if (tx < NBK) {
      int c = cnt[tx];
      base[tx] = c ? atomicAdd(&gpos[tx], c) : 0;
      cnt[tx] = 0;
    }
    __syncthreads();
    for (int i = e0 + tx; i < e1; i += 512) {
      int s = ei[i];
      int d = ei[EE + i];
      int bk = d >> 7;
      int slot = base[bk] + atomicAdd(&cnt[bk], 1);
      if (slot < BCAP)
        binned[(size_t)bk * BCAP + slot] = (unsigned)s | ((unsigned)(d & 127) << 16);
    }
  }
}

// ============================ shared device helpers ============================
template <int NH, int NT, int F>
static __device__ __forceinline__ void write_scores(const f32x4 (&acc)[F][NT],
                                                    const float* __restrict__ a_s,
                                                    const float* __restrict__ a_d,
                                                    int r0, int lane, int wv,
                                                    float* __restrict__ scs,
                                                    float* __restrict__ scd) {
  const int lr = lane & 15, lg = lane >> 4;
  float asv[NT], adv[NT];
#pragma unroll
  for (int ct = 0; ct < NT; ++ct) {
    asv[ct] = a_s[ct * 16 + lr];
    adv[ct] = a_d[ct * 16 + lr];
  }
  float ps[F][4][NH], pd[F][4][NH];
#pragma unroll
  for (int f = 0; f < F; ++f)
#pragma unroll
    for (int r = 0; r < 4; ++r)
#pragma unroll
      for (int h = 0; h < NH; ++h) { ps[f][r][h] = 0.f; pd[f][r][h] = 0.f; }
#pragma unroll
  for (int f = 0; f < F; ++f)
#pragma unroll
    for (int ct = 0; ct < NT; ++ct) {
      int h = (NH == 1) ? 0 : (ct >> 1);
#pragma unroll
      for (int r = 0; r < 4; ++r) {
        ps[f][r][h] = fmaf(acc[f][ct][r], asv[ct], ps[f][r][h]);
        pd[f][r][h] = fmaf(acc[f][ct][r], adv[ct], pd[f][r][h]);
      }
    }
#pragma unroll
  for (int off = 1; off < 16; off <<= 1)
#pragma unroll
    for (int f = 0; f < F; ++f)
#pragma unroll
      for (int r = 0; r < 4; ++r)
#pragma unroll
        for (int h = 0; h < NH; ++h) {
          ps[f][r][h] += __shfl_xor(ps[f][r][h], off);
          pd[f][r][h] += __shfl_xor(pd[f][r][h], off);
        }
  if (lr == 0) {
#pragma unroll
    for (int f = 0; f < F; ++f) {
      int rowb = r0 + (wv * F + f) * 16 + lg * 4;
#pragma unroll
      for (int r = 0; r < 4; ++r) {
        int gr = rowb + r;
        if (gr < NN) {
          if (NH == 4) {
            float4 vs = make_float4(ps[f][r][0], ps[f][r][1], ps[f][r][2], ps[f][r][3]);
            float4 vd = make_float4(pd[f][r][0], pd[f][r][1], pd[f][r][2], pd[f][r][3]);
            *(float4*)(scs + (size_t)gr * 4) = vs;
            *(float4*)(scd + (size_t)gr * 4) = vd;
          } else {
            scs[gr] = ps[f][r][0];
            scd[gr] = pd[f][r][0];
          }
        }
      }
    }
  }
}

template <int BIAS, int RELU, int NT, int F>
static __device__ __forceinline__ void write_out_bf(const f32x4 (&acc)[F][NT],
                                                    const float* __restrict__ bias,
                                                    int r0, int lane, int wv,
                                                    unsigned short* __restrict__ out) {
  const int lr = lane & 15, lg = lane >> 4;
#pragma unroll
  for (int f = 0; f < F; ++f) {
    int rowb = r0 + (wv * F + f) * 16 + lg * 4;
#pragma unroll
    for (int ct = 0; ct < NT; ++ct) {
      int col = ct * 16 + lr;
      float bb = BIAS ? bias[col] : 0.f;
#pragma unroll
      for (int r = 0; r < 4; ++r) {
        int gr = rowb + r;
        if (gr < NN) {
          float o = acc[f][ct][r] + bb;
          if (RELU) o = fmaxf(o, 0.f);
          out[(size_t)gr * 128 + col] = f2bf(o);
        }
      }
    }
  }
}

// ============================ fused front: {proj->skip+conv1} | bucket ============
// blocks [0,391): GEMM chain (BM=128): A1 = bn(x) (K=64) @ projW -> relu -> LDS A
// (K=128) -> skipW -> hsk; -> c1W -> hb + scores. hr never hits global.
// blocks [391,782): CSR bucket build (independent of GEMM family; both need only prep).
__global__ __launch_bounds__(256) void k_front(
    const float* __restrict__ x, const float* __restrict__ xsum,
    const float* __restrict__ in_g, const float* __restrict__ in_b,
    const unsigned short* __restrict__ BwP, const float* __restrict__ projb,
    const unsigned short* __restrict__ BwS, const float* __restrict__ skipb,
    const unsigned short* __restrict__ BwC, const float* __restrict__ a_s,
    const float* __restrict__ a_d,
    unsigned short* __restrict__ hsk, unsigned short* __restrict__ hb,
    float* __restrict__ scs, float* __restrict__ scd,
    const unsigned* __restrict__ binned, const int* __restrict__ gpos,
    int* __restrict__ rowp, int* __restrict__ srcl) {
  __shared__ __align__(16) unsigned short sm[32768];  // 64 KB
  __shared__ float bnsc[64], bnsh[64];
  const int tid = threadIdx.x;

  if (blockIdx.x >= 391) {
    // ================= bucket family =================
    int* cnt  = (int*)sm;          // 128
    int* offs = (int*)sm + 128;    // 128
    int* cur  = (int*)sm + 256;    // 128
    int* red  = (int*)sm + 384;    // 256
    int* red2 = (int*)sm + 640;    // 256
    int b = blockIdx.x - 391;
    int accp = 0, acct = 0;
    for (int i = tid; i < NBK; i += 256) {
      int gv = gpos[i];
      if (gv > BCAP) gv = BCAP;
      if (i < b) accp += gv;
      acct += gv;
    }
    red[tid] = accp;
    red2[tid] = acct;
    __syncthreads();
    for (int o = 128; o; o >>= 1) {
      if (tid < o) {
        red[tid] += red[tid + o];
        red2[tid] += red2[tid + o];
      }
      __syncthreads();
    }
    int eb = (b << 7) + red[0];
    if (b == NBK - 1 && tid == 0) rowp[NN] = red2[0] + NN;

    int n0 = b << 7;
    int nodes = NN - n0;
    if (nodes > 128) nodes = 128;
    int ne = gpos[b];
    if (ne > BCAP) ne = BCAP;
    if (tid < 128) cnt[tid] = (tid < nodes) ? 1 : 0;  // 1 = self-loop
    __syncthreads();
    const unsigned* bb = binned + (size_t)b * BCAP;
    for (int i = tid; i < ne; i += 256) atomicAdd(&cnt[bb[i] >> 16], 1);
    __syncthreads();
    if (tid < 128) offs[tid] = cnt[tid];
    __syncthreads();
    for (int o = 1; o < 128; o <<= 1) {
      int t = (tid < 128 && tid >= o) ? offs[tid - o] : 0;
      __syncthreads();
      if (tid < 128) offs[tid] += t;
      __syncthreads();
    }
    if (tid < 128 && tid < nodes) {
      int ex = offs[tid] - cnt[tid];
      rowp[n0 + tid] = eb + ex;
      srcl[eb + ex] = n0 + tid;  // self-loop first
      cur[tid] = ex + 1;
    }
    __syncthreads();
    for (int i = tid; i < ne; i += 256) {
      unsigned e = bb[i];
      int r = atomicAdd(&cur[e >> 16], 1);
      srcl[eb + r] = (int)(e & 0xFFFFu);
    }
    return;
  }

  // ================= GEMM family =================
  const int r0 = blockIdx.x * 128;
  if (tid < 64) {
    float invM = 1.f / (float)NN;
    float mu = xsum[tid] * invM;
    float var = xsum[64 + tid] * invM - mu * mu;
    float sc = in_g[tid] * rsqrtf(var + 1e-5f);
    bnsc[tid] = sc;
    bnsh[tid] = in_b[tid] - mu * sc;
  }
  __syncthreads();

  // ---- stage A1: bn(x) as bf16 fragments, K=64 (KB=2), at offset 0 ----
#pragma unroll
  for (int it = 0; it < 8; ++it) {
    int idx = it * 256 + tid;
    int r = idx >> 4;
    int k = (idx & 15) * 4;
    int gr = r0 + r;
    float4 av = make_float4(0.f, 0.f, 0.f, 0.f);
    if (gr < NN) av = *(const float4*)(x + (size_t)gr * 64 + k);
    av.x = av.x * bnsc[k + 0] + bnsh[k + 0];
    av.y = av.y * bnsc[k + 1] + bnsh[k + 1];
    av.z = av.z * bnsc[k + 2] + bnsh[k + 2];
    av.w = av.w * bnsc[k + 3] + bnsh[k + 3];
    ushort4 o;
    o.x = f2bf(av.x); o.y = f2bf(av.y); o.z = f2bf(av.z); o.w = f2bf(av.w);
    *(ushort4*)&sm[((r >> 4) * 2 + (k >> 5)) * 512 + (r & 15) * 32 + (k & 31)] = o;
  }
  // ---- stage B1 = projW fragments at offset 8192 ----
#pragma unroll
  for (int it = 0; it < 4; ++it) {
    int idx = it * 256 + tid;
    *(uint4*)&sm[8192 + idx * 8] = *(const uint4*)(BwP + idx * 8);
  }
  __syncthreads();

  const int lane = tid & 63, wv = tid >> 6;
  const int lr = lane & 15, lg = lane >> 4;
  const int fidx = lr * 32 + lg * 8;
  f32x4 acc[2][8];
#pragma unroll
  for (int f = 0; f < 2; ++f)
#pragma unroll
    for (int ct = 0; ct < 8; ++ct) acc[f][ct] = (f32x4){0.f, 0.f, 0.f, 0.f};
#pragma unroll
  for (int kb = 0; kb < 2; ++kb) {
    short8 a0 = *(const short8*)&sm[((wv * 2 + 0) * 2 + kb) * 512 + fidx];
    short8 a1 = *(const short8*)&sm[((wv * 2 + 1) * 2 + kb) * 512 + fidx];
#pragma unroll
    for (int ct = 0; ct < 8; ++ct) {
      short8 b = *(const short8*)&sm[8192 + (ct * 2 + kb) * 512 + fidx];
      acc[0][ct] = __builtin_amdgcn_mfma_f32_16x16x32_bf16(a0, b, acc[0][ct], 0, 0, 0);
      acc[1][ct] = __builtin_amdgcn_mfma_f32_16x16x32_bf16(a1, b, acc[1][ct], 0, 0, 0);
    }
  }
  __syncthreads();  // all waves done reading A1/B1

  // ---- write proj result (relu, +bias) as K=128 A-fragment at offset 0 ----
  {
    float pbv[8];
#pragma unroll
    for (int ct = 0; ct < 8; ++ct) pbv[ct] = projb[ct * 16 + lr];
#pragma unroll
    for (int f = 0; f < 2; ++f) {
      int rowb = (wv * 2 + f) * 16 + lg * 4;
#pragma unroll
      for (int ct = 0; ct < 8; ++ct) {
        int col = ct * 16 + lr;
#pragma unroll
        for (int r = 0; r < 4; ++r) {
          int row = rowb + r;
          float o = fmaxf(acc[f][ct][r] + pbv[ct], 0.f);
          sm[((row >> 4) * 4 + (col >> 5)) * 512 + (row & 15) * 32 + (col & 31)] = f2bf(o);
        }
      }
    }
  }
  // ---- stage B2 = skipW at offset 16384 ----
#pragma unroll
  for (int it = 0; it < 8; ++it) {
    int idx = it * 256 + tid;
    *(uint4*)&sm[16384 + idx * 8] = *(const uint4*)(BwS + idx * 8);
  }
  __syncthreads();

#pragma unroll
  for (int f = 0; f < 2; ++f)
#pragma unroll
    for (int ct = 0; ct < 8; ++ct) acc[f][ct] = (f32x4){0.f, 0.f, 0.f, 0.f};
#pragma unroll
  for (int kb = 0; kb < 4; ++kb) {
    short8 a0 = *(const short8*)&sm[((wv * 2 + 0) * 4 + kb) * 512 + fidx];
    short8 a1 = *(const short8*)&sm[((wv * 2 + 1) * 4 + kb) * 512 + fidx];
#pragma unroll
    for (int ct = 0; ct < 8; ++ct) {
      short8 b = *(const short8*)&sm[16384 + (ct * 4 + kb) * 512 + fidx];
      acc[0][ct] = __builtin_amdgcn_mfma_f32_16x16x32_bf16(a0, b, acc[0][ct], 0, 0, 0);
      acc[1][ct] = __builtin_amdgcn_mfma_f32_16x16x32_bf16(a1, b, acc[1][ct], 0, 0, 0);
    }
  }
  write_out_bf<1, 0>(acc, skipb, r0, lane, wv, hsk);
  __syncthreads();  // done reading B2

  // ---- stage B3 = c1W at offset 16384 ----
#pragma unroll
  for (int it = 0; it < 8; ++it) {
    int idx = it * 256 + tid;
    *(uint4*)&sm[16384 + idx * 8] = *(const uint4*)(BwC + idx * 8);
  }
  __syncthreads();

#pragma unroll
  for (int f = 0; f < 2; ++f)
#pragma unroll
    for (int ct = 0; ct < 8; ++ct) acc[f][ct] = (f32x4){0.f, 0.f, 0.f, 0.f};
#pragma unroll
  for (int kb = 0; kb < 4; ++kb) {
    short8 a0 = *(const short8*)&sm[((wv * 2 + 0) * 4 + kb) * 512 + fidx];
    short8 a1 = *(const short8*)&sm[((wv * 2 + 1) * 4 + kb) * 512 + fidx];
#pragma unroll
    for (int ct = 0; ct < 8; ++ct) {
      short8 b = *(const short8*)&sm[16384 + (ct * 4 + kb) * 512 + fidx];
      acc[0][ct] = __builtin_amdgcn_mfma_f32_16x16x32_bf16(a0, b, acc[0][ct], 0, 0, 0);
      acc[1][ct] = __builtin_amdgcn_mfma_f32_16x16x32_bf16(a1, b, acc[1][ct], 0, 0, 0);
    }
  }
  write_scores<4>(acc, a_s, a_d, r0, lane, wv, scs, scd);
  write_out_bf<0, 0>(acc, nullptr, r0, lane, wv, hb);
}

// ============================ MFMA GEMM ============================
template <int BM, int K, int NT, int ABF, int BN, int BNP, int BIAS, int RELU, int OUTM, int SCH>
__global__ __launch_bounds__(256) void k_mgemm(
    const void* __restrict__ Ain, const unsigned short* __restrict__ Bw,
    const float* __restrict__ bias,
    const float* __restrict__ bnsums, const float* __restrict__ bng,
    const float* __restrict__ bnb,
    const unsigned short* __restrict__ skip,
    const float* __restrict__ a_s, const float* __restrict__ a_d,
    const float* __restrict__ confb,
    void* __restrict__ Cout, float* __restrict__ conf,
    float* __restrict__ scs, float* __restrict__ scd,
    const float* __restrict__ W2, const float* __restrict__ b2,
    const float* __restrict__ W3, const float* __restrict__ b3,
    float* __restrict__ logits) {
  constexpr int KB = K / 32;
  constexpr int RT = BM / 16;
  constexpr int F = BM / 64;
  __shared__ __align__(16) unsigned short sm[(RT + NT) * KB * 512];
  __shared__ float bnsc[128], bnsh[128];
  const int tid = threadIdx.x;
  const int r0 = blockIdx.x * BM;

  if constexpr (BN) {
    if (tid < K) {
      float s = 0.f, q = 0.f;
#pragma unroll 8
      for (int pp = 0; pp < 32; ++pp) {
        s += bnsums[pp * 256 + tid];
        q += bnsums[pp * 256 + 128 + tid];
      }
      float invM = 1.f / (float)NN;
      float mu = s * invM;
      float var = q * invM - mu * mu;
      float sc = bng[tid] * rsqrtf(var + 1e-5f);
      bnsc[tid] = sc;
      bnsh[tid] = bnb[tid] - mu * sc;
    }
    __syncthreads();
  }

  // ---- stage A (bf16 input) ----
  {
    const unsigned short* A = (const unsigned short*)Ain;
    constexpr int IT = BM * (K / 8) / 256;
#pragma unroll
    for (int it = 0; it < IT; ++it) {
      int idx = it * 256 + tid;
      int r = idx / (K / 8);
      int k = (idx % (K / 8)) * 8;
      int gr = r0 + r;
      union { uint4 u4; unsigned short us[8]; } v;
      v.u4 = make_uint4(0, 0, 0, 0);
      if (gr < NN) v.u4 = *(const uint4*)(A + (size_t)gr * K + k);
      if constexpr (BN) {
        union { uint4 u4; unsigned short us[8]; } sv;
        if (BN == 3) {
          sv.u4 = make_uint4(0, 0, 0, 0);
          if (gr < NN) sv.u4 = *(const uint4*)(skip + (size_t)gr * 128 + k);
        }
#pragma unroll
        for (int j = 0; j < 8; ++j) {
          float f = bf2f(v.us[j]) * bnsc[k + j] + bnsh[k + j];
          if (BN == 3) f += bf2f(sv.us[j]);
          if (BN >= 2) f = fmaxf(f, 0.f);
          v.us[j] = f2bf(f);
        }
      }
      *(uint4*)&sm[((r >> 4) * KB + (k >> 5)) * 512 + (r & 15) * 32 + (k & 31)] = v.u4;
    }
  }
  // ---- stage B ----
  {
    constexpr int BW = NT * KB * 512;
#pragma unroll
    for (int it = 0; it < BW / 2048; ++it) {
      int idx = it * 256 + tid;
      *(uint4*)&sm[RT * KB * 512 + idx * 8] = *(const uint4*)(Bw + idx * 8);
    }
  }
  __syncthreads();

  // ---- MFMA ----
  const int lane = tid & 63, wv = tid >> 6;
  const int lr = lane & 15, lg = lane >> 4;
  const int fidx = lr * 32 + lg * 8;
  f32x4 acc[F][NT];
#pragma unroll
  for (int f = 0; f < F; ++f)
#pragma unroll
    for (int ct = 0; ct < NT; ++ct) acc[f][ct] = (f32x4){0.f, 0.f, 0.f, 0.f};
#pragma unroll
  for (int kb = 0; kb < KB; ++kb) {
    short8 afr[F];
#pragma unroll
    for (int f = 0; f < F; ++f)
      afr[f] = *(const short8*)&sm[((wv * F + f) * KB + kb) * 512 + fidx];
#pragma unroll
    for (int ct = 0; ct < NT; ++ct) {
      short8 b = *(const short8*)&sm[((RT + ct) * KB + kb) * 512 + fidx];
#pragma unroll
      for (int f = 0; f < F; ++f)
        acc[f][ct] = __builtin_amdgcn_mfma_f32_16x16x32_bf16(afr[f], b, acc[f][ct], 0, 0, 0);
    }
  }

  if constexpr (SCH > 0) {
    write_scores<(SCH == 1) ? 1 : 4>(acc, a_s, a_d, r0, lane, wv, scs, scd);
  }

  if constexpr (OUTM == 2) {
    // -------- classifier tail in-kernel (reuse sm; BM must be 128) --------
    __syncthreads();
    unsigned short* c1s = sm;                 // [128][65] bf16
    float* W2s = (float*)(sm + 8320);         // 64*32
    float* c2s = (float*)(sm + 12416);        // [128][33]
    float* W3s = (float*)(sm + 20864);        // 64
    float* b2s = (float*)(sm + 20992);        // 32
    float* b3s = (float*)(sm + 21056);        // 2
    for (int i = tid; i < 2048; i += 256) W2s[i] = W2[i];
    if (tid < 64) W3s[tid] = W3[tid];
    if (tid < 32) b2s[tid] = b2[tid];
    if (tid < 2) b3s[tid] = b3[tid];
#pragma unroll
    for (int f = 0; f < F; ++f) {
      int lrow = (wv * F + f) * 16 + lg * 4;
#pragma unroll
      for (int ct = 0; ct < NT; ++ct) {
        int col = ct * 16 + lr;
        if (col < 64) {
          float bb = bias[col];
#pragma unroll
          for (int r = 0; r < 4; ++r)
            c1s[(lrow + r) * 65 + col] = f2bf(fmaxf(acc[f][ct][r] + bb, 0.f));
        } else if (col == 64) {
          float cb = confb[0];
#pragma unroll
          for (int r = 0; r < 4; ++r) {
            int gr = r0 + lrow + r;
            if (gr < NN) conf[gr] = 1.f / (1.f + __expf(-(acc[f][ct][r] + cb)));
          }
        }
      }
    }
    __syncthreads();
    {
      int node = tid & 127;
      int cb = (tid >> 7) * 16;
      float a2[16];
#pragma unroll
      for (int i = 0; i < 16; ++i) a2[i] = b2s[cb + i];
      for (int k = 0; k < 64; ++k) {
        float v = bf2f(c1s[node * 65 + k]);
#pragma unroll
        for (int i = 0; i < 16; ++i) a2[i] = fmaf(v, W2s[k * 32 + cb + i], a2[i]);
      }
#pragma unroll
      for (int i = 0; i < 16; ++i) c2s[node * 33 + cb + i] = fmaxf(a2[i], 0.f);
    }
    __syncthreads();
    {
      int node = tid >> 1, j = tid & 1;
      float s3 = b3s[j];
#pragma unroll 8
      for (int k = 0; k < 32; ++k) s3 = fmaf(c2s[node * 33 + k], W3s[k * 2 + j], s3);
      int gr = r0 + node;
      if (gr < NN) logits[(size_t)gr * 2 + j] = s3;
    }
  } else {
    write_out_bf<BIAS, RELU>(acc, bias, r0, lane, wv, (unsigned short*)Cout);
  }
}

// ============================ GAT aggregation (+ fused BN stats) ============================
template <int H>
__global__ __launch_bounds__(256) void k_agg(const unsigned short* __restrict__ hp,
                                             const float* __restrict__ scs,
                                             const float* __restrict__ scd,
                                             const int* __restrict__ rowp,
                                             const int* __restrict__ srcl,
                                             const float* __restrict__ bias,
                                             unsigned short* __restrict__ out,
                                             float* __restrict__ part) {
  __shared__ float ssum[8][144], ssq[8][144];
  int tid = threadIdx.x;
  int lane = tid & 63, wv = tid >> 6;
  int half = lane >> 5;
  int l32 = lane & 31;
  int g = l32 >> 4;
  int l16 = lane & 15;
  int n = (blockIdx.x * 4 + wv) * 2 + half;
  int c0 = l16 * 8;
  int hid = (H == 1) ? 0 : (l16 >> 2);
  float sd = scd[(size_t)n * H + hid];
  int beg = rowp[n], end = rowp[n + 1];
  int last = end - 1;
  float a[8];
#pragma unroll
  for (int i = 0; i < 8; ++i) a[i] = 0.f;
  float sw = 0.f;
  int k0 = beg + g * 4;
  int s0 = srcl[(k0 + 0) <= last ? (k0 + 0) : last];
  int s1 = srcl[(k0 + 1) <= last ? (k0 + 1) : last];
  int s2 = srcl[(k0 + 2) <= last ? (k0 + 2) : last];
  int s3 = srcl[(k0 + 3) <= last ? (k0 + 3) : last];
  for (; k0 < end; k0 += 8) {
    int np = k0 + 8;
    int t0 = srcl[(np + 0) <= last ? (np + 0) : last];
    int t1 = srcl[(np + 1) <= last ? (np + 1) : last];
    int t2 = srcl[(np + 2) <= last ? (np + 2) : last];
    int t3 = srcl[(np + 3) <= last ? (np + 3) : last];
    float e0 = scs[(size_t)s0 * H + hid] + sd;
    float e1 = scs[(size_t)s1 * H + hid] + sd;
    float e2 = scs[(size_t)s2 * H + hid] + sd;
    float e3 = scs[(size_t)s3 * H + hid] + sd;
    uint4 u0 = *(const uint4*)(hp + (size_t)s0 * 128 + c0);
    uint4 u1 = *(const uint4*)(hp + (size_t)s1 * 128 + c0);
    uint4 u2 = *(const uint4*)(hp + (size_t)s2 * 128 + c0);
    uint4 u3 = *(const uint4*)(hp + (size_t)s3 * 128 + c0);
    e0 = fmaxf(e0, 0.f) + 0.2f * fminf(e0, 0.f);
    e1 = fmaxf(e1, 0.f) + 0.2f * fminf(e1, 0.f);
    e2 = fmaxf(e2, 0.f) + 0.2f * fminf(e2, 0.f);
    e3 = fmaxf(e3, 0.f) + 0.2f * fminf(e3, 0.f);
    float w0 = __expf(e0);
    float w1 = (k0 + 1 <= last) ? __expf(e1) : 0.f;
    float w2 = (k0 + 2 <= last) ? __expf(e2) : 0.f;
    float w3 = (k0 + 3 <= last) ? __expf(e3) : 0.f;
    a[0] = fmaf(w0, bf2f_lo(u0.x), a[0]); a[1] = fmaf(w0, bf2f_hi(u0.x), a[1]);
    a[2] = fmaf(w0, bf2f_lo(u0.y), a[2]); a[3] = fmaf(w0, bf2f_hi(u0.y), a[3]);
    a[4] = fmaf(w0, bf2f_lo(u0.z), a[4]); a[5] = fmaf(w0, bf2f_hi(u0.z), a[5]);
    a[6] = fmaf(w0, bf2f_lo(u0.w), a[6]); a[7] = fmaf(w0, bf2f_hi(u0.w), a[7]);
    a[0] = fmaf(w1, bf2f_lo(u1.x), a[0]); a[1] = fmaf(w1, bf2f_hi(u1.x), a[1]);
    a[2] = fmaf(w1, bf2f_lo(u1.y), a[2]); a[3] = fmaf(w1, bf2f_hi(u1.y), a[3]);
    a[4] = fmaf(w1, bf2f_lo(u1.z), a[4]); a[5] = fmaf(w1, bf2f_hi(u1.z), a[5]);
    a[6] = fmaf(w1, bf2f_lo(u1.w), a[6]); a[7] = fmaf(w1, bf2f_hi(u1.w), a[7]);
    a[0] = fmaf(w2, bf2f_lo(u2.x), a[0]); a[1] = fmaf(w2, bf2f_hi(u2.x), a[1]);
    a[2] = fmaf(w2, bf2f_lo(u2.y), a[2]); a[3] = fmaf(w2, bf2f_hi(u2.y), a[3]);
    a[4] = fmaf(w2, bf2f_lo(u2.z), a[4]); a[5] = fmaf(w2, bf2f_hi(u2.z), a[5]);
    a[6] = fmaf(w2, bf2f_lo(u2.w), a[6]); a[7] = fmaf(w2, bf2f_hi(u2.w), a[7]);
    a[0] = fmaf(w3, bf2f_lo(u3.x), a[0]); a[1] = fmaf(w3, bf2f_hi(u3.x), a[1]);
    a[2] = fmaf(w3, bf2f_lo(u3.y), a[2]); a[3] = fmaf(w3, bf2f_hi(u3.y), a[3]);
    a[4] = fmaf(w3, bf2f_lo(u3.z), a[4]); a[5] = fmaf(w3, bf2f_hi(u3.z), a[5]);
    a[6] = fmaf(w3, bf2f_lo(u3.w), a[6]); a[7] = fmaf(w3, bf2f_hi(u3.w), a[7]);
    sw += (w0 + w1) + (w2 + w3);
    s0 = t0; s1 = t1; s2 = t2; s3 = t3;
  }
#pragma unroll
  for (int i = 0; i < 8; ++i) a[i] += __shfl_xor(a[i], 16);
  sw += __shfl_xor(sw, 16);
  int slice = wv * 2 + half;
  if (g == 0) {
    float inv = 1.f / (sw + 1e-16f);
    unsigned wb[4];
    int ib = c0 + l16;  // padded: c + (c>>3)
#pragma unroll
    for (int j = 0; j < 4; ++j) {
      float o0 = a[2 * j] * inv + bias[c0 + 2 * j];
      float o1 = a[2 * j + 1] * inv + bias[c0 + 2 * j + 1];
      ssum[slice][ib + 2 * j] = o0;
      ssum[slice][ib + 2 * j + 1] = o1;
      ssq[slice][ib + 2 * j] = o0 * o0;
      ssq[slice][ib + 2 * j + 1] = o1 * o1;
      wb[j] = (unsigned)f2bf(o0) | ((unsigned)f2bf(o1) << 16);
    }
    *(uint4*)(out + (size_t)n * 128 + c0) = make_uint4(wb[0], wb[1], wb[2], wb[3]);
  }
  __syncthreads();
  if (tid < 128) {
    int idx = tid + (tid >> 3);
    float s = 0.f, q = 0.f;
#pragma unroll
    for (int sl = 0; sl < 8; ++sl) {
      s += ssum[sl][idx];
      q += ssq[sl][idx];
    }
    int pb = (blockIdx.x & 31) * 256;
    atomicAdd(&part[pb + tid], s);
    atomicAdd(&part[pb + 128 + tid], q);
  }
}

// ============================ launch ============================
extern "C" void kernel_launch(void* const* d_in, const int* in_sizes, int n_in,
                              void* d_out, int out_size, void* d_ws, size_t ws_size,
                              hipStream_t stream) {
  (void)in_sizes; (void)n_in; (void)out_size; (void)ws_size;
  const float* x       = (const float*)d_in[0];
  const int*   ei      = (const int*)d_in[1];
  const float* in_g    = (const float*)d_in[2];
  const float* in_b    = (const float*)d_in[3];
  const float* projW   = (const float*)d_in[4];
  const float* projb   = (const float*)d_in[5];
  const float* skipW   = (const float*)d_in[6];
  const float* skipb   = (const float*)d_in[7];
  const float* c1W     = (const float*)d_in[8];
  const float* c1as    = (const float*)d_in[9];
  const float* c1ad    = (const float*)d_in[10];
  const float* c1b     = (const float*)d_in[11];
  const float* bn1g    = (const float*)d_in[12];
  const float* bn1b    = (const float*)d_in[13];
  const float* c2W     = (const float*)d_in[14];
  const float* c2as    = (const float*)d_in[15];
  const float* c2ad    = (const float*)d_in[16];
  const float* c2b     = (const float*)d_in[17];
  const float* bn2g    = (const float*)d_in[18];
  const float* bn2b    = (const float*)d_in[19];
  const float* c3W     = (const float*)d_in[20];
  const float* c3as    = (const float*)d_in[21];
  const float* c3ad    = (const float*)d_in[22];
  const float* c3b     = (const float*)d_in[23];
  const float* bn3g    = (const float*)d_in[24];
  const float* bn3b    = (const float*)d_in[25];
  const float* clsW1   = (const float*)d_in[26];
  const float* clsb1   = (const float*)d_in[27];
  const float* clsW2   = (const float*)d_in[28];
  const float* clsb2   = (const float*)d_in[29];
  const float* clsW3   = (const float*)d_in[30];
  const float* clsb3   = (const float*)d_in[31];
  const float* confW   = (const float*)d_in[32];
  const float* confb   = (const float*)d_in[33];

  float* out_logits = (float*)d_out;
  float* out_conf   = (float*)d_out + (size_t)NN * 2;

  char* p = (char*)d_ws;
  auto alloc = [&](size_t bytes) -> char* {
    char* r = p;
    p += (bytes + 255) & ~(size_t)255;
    return r;
  };
  unsigned short* hsk = (unsigned short*)alloc((size_t)NN * 128 * 2);  // h_skip
  unsigned short* hb  = (unsigned short*)alloc((size_t)NN * 128 * 2);  // conv h
  unsigned short* agA = (unsigned short*)alloc((size_t)NN * 128 * 2);  // agg out (L1, L3)
  unsigned short* agB = (unsigned short*)alloc((size_t)NN * 128 * 2);  // agg out (L2)
  float* scs   = (float*)alloc((size_t)NN * 4 * 4);
  float* scd   = (float*)alloc((size_t)NN * 4 * 4);
  // zero region (memset): gpos | xsum
  char*  zr    = alloc(2048 + 512);
  int*   gpos  = (int*)zr;
  float* xsum  = (float*)(zr + 2048);
  // parts zeroed by k_prep family
  float* part1 = (float*)alloc(3 * 32768);
  float* part2 = part1 + 8192;
  float* part3 = part2 + 8192;
  int*   rowp  = (int*)alloc((size_t)(NN + 1) * 4);
  unsigned* binned = (unsigned*)alloc((size_t)NBK * BCAP * 4);
  int*   srcl  = (int*)alloc((size_t)TOT_E * 4);
  unsigned short* wr = (unsigned short*)alloc(83968 * 2);
  unsigned short* wr_proj = wr;
  unsigned short* wr_skip = wr + 8192;
  unsigned short* wr_c1   = wr + 24576;
  unsigned short* wr_c2   = wr + 40960;
  unsigned short* wr_c3   = wr + 57344;
  unsigned short* wr_cls  = wr + 73728;

  const int GB64  = (NN + 63) / 64;    // 782
  const int GB128 = (NN + 127) / 128;  // 391
  const int AB    = NN / 8;            // 6250 agg blocks

  hipMemsetAsync(zr, 0, 2048 + 512, stream);

  // ---- mega-prep: reorder | x-stats | zero parts | bin ----
  k_prep<<<852, 512, 0, stream>>>(projW, skipW, c1W, c2W, c3W, clsW1, confW, wr,
                                  x, xsum, part1, ei, gpos, binned);

  // ---- fused front: {proj -> skip + conv1 (+scores)} | bucket CSR ----
  k_front<<<782, 256, 0, stream>>>(x, xsum, in_g, in_b, wr_proj, projb,
                                   wr_skip, skipb, wr_c1, c1as, c1ad,
                                   hsk, hb, scs, scd,
                                   binned, gpos, rowp, srcl);
  k_agg<4><<<AB, 256, 0, stream>>>(hb, scs, scd, rowp, srcl, c1b, agA, part1);

  // ---- GAT layer 2 (bn1+relu fused into A staging) ----
  k_mgemm<64, 128, 8, 1, 2, 1, 0, 0, 1, 4><<<GB64, 256, 0, stream>>>(
      agA, wr_c2, nullptr, part1, bn1g, bn1b, nullptr, c2as, c2ad, nullptr,
      hb, nullptr, scs, scd, nullptr, nullptr, nullptr, nullptr, nullptr);
  k_agg<4><<<AB, 256, 0, stream>>>(hb, scs, scd, rowp, srcl, c2b, agB, part2);

  // ---- GAT layer 3 (H=1; bn2+relu fused) ----
  k_mgemm<64, 128, 8, 1, 2, 1, 0, 0, 1, 1><<<GB64, 256, 0, stream>>>(
      agB, wr_c3, nullptr, part2, bn2g, bn2b, nullptr, c3as, c3ad, nullptr,
      hb, nullptr, scs, scd, nullptr, nullptr, nullptr, nullptr, nullptr);
  k_agg<1><<<AB, 256, 0, stream>>>(hb, scs, scd, rowp, srcl, c3b, agA, part3);

  // ---- classifier: relu(bn3(agA)+hsk) @ [W1|confW] -> C1(LDS) -> c2 -> logits/conf ----
  k_mgemm<128, 128, 5, 1, 3, 1, 1, 0, 2, 0><<<GB128, 256, 0, stream>>>(
      agA, wr_cls, clsb1, part3, bn3g, bn3b, hsk, nullptr, nullptr, confb,
      nullptr, out_conf, nullptr, nullptr, clsW2, clsb2, clsW3, clsb3, out_logits);
}